// Round 13
// baseline (224.689 us; speedup 1.0000x reference)
//
#include <hip/hip_runtime.h>
#include <math.h>

typedef float  f32x4  __attribute__((ext_vector_type(4)));
typedef short  bf16x8 __attribute__((ext_vector_type(8)));
typedef unsigned short u16;

__device__ __forceinline__ u16 f2b(float f) {
  union { float f; unsigned u; } v; v.f = f;
  unsigned r = v.u + 0x7FFFu + ((v.u >> 16) & 1u);
  return (u16)(r >> 16);
}
__device__ __forceinline__ float b2f(u16 h) {
  union { unsigned u; float f; } v; v.u = ((unsigned)h) << 16;
  return v.f;
}

// async global->LDS, 16B per lane; dest = wave-uniform base + lane*16
__device__ __forceinline__ void gl_lds16(const u16* g, u16* l) {
  __builtin_amdgcn_global_load_lds(
      (const __attribute__((address_space(1))) unsigned*)g,
      (__attribute__((address_space(3))) unsigned*)l, 16, 0, 0);
}

// ---------------- fp32 -> bf16 conversion / packing ----------------
__global__ __launch_bounds__(256) void convert_kernel(
    const float* __restrict__ x,  const float* __restrict__ Wq,
    const float* __restrict__ Wk, const float* __restrict__ Wv,
    const float* __restrict__ Wo, const float* __restrict__ bq,
    const float* __restrict__ bk, const float* __restrict__ bv,
    u16* __restrict__ xb, u16* __restrict__ Wcat, u16* __restrict__ Wob,
    float* __restrict__ bcat)
{
  long i = ((long)blockIdx.x * 256 + threadIdx.x) * 4;
  if (i < 10485760L) {
    const float* src; u16* dst; long o;
    if (i < 4194304L)      { src = x;  dst = xb;             o = i; }
    else if (i < 6291456L) { src = Wq; dst = Wcat;           o = i - 4194304L; }
    else if (i < 8388608L) { src = Wk; dst = Wcat + 2097152; o = i - 6291456L; }
    else if (i < 9437184L) { src = Wv; dst = Wcat + 4194304; o = i - 8388608L; }
    else                   { src = Wo; dst = Wob;            o = i - 9437184L; }
    float4 v = *(const float4*)(src + o);
    union { u16 h[4]; uint2 u2; } p;
    p.h[0] = f2b(v.x); p.h[1] = f2b(v.y); p.h[2] = f2b(v.z); p.h[3] = f2b(v.w);
    *(uint2*)(dst + o) = p.u2;
  } else if (i < 10490880L) {
    long j = i - 10485760L;
    const float* src; long o;
    if (j < 2048)      { src = bq; o = j; }
    else if (j < 4096) { src = bk; o = j - 2048; }
    else               { src = bv; o = j - 4096; }
    *(float4*)(bcat + j) = *(const float4*)(src + o);
  }
}

// ---------------- prep: logL scan (blocks 0-3) + RoPE table (blocks 4-35) ----------------
__global__ __launch_bounds__(1024) void prep_kernel(
    const float* __restrict__ a, float* __restrict__ logL,
    float* __restrict__ ctab, float* __restrict__ stab)
{
  if (blockIdx.x < 4) {
    __shared__ float sh[1024];
    int b = blockIdx.x, t = threadIdx.x;
    float v = (t == 0) ? 0.f : log2f(a[b * 1023 + t - 1]);
    sh[t] = v;
    __syncthreads();
    for (int off = 1; off < 1024; off <<= 1) {
      float add = (t >= off) ? sh[t - off] : 0.f;
      __syncthreads();
      sh[t] += add;
      __syncthreads();
    }
    logL[b * 1024 + t] = sh[t];
  } else {
    int idx = (blockIdx.x - 4) * 1024 + threadIdx.x;   // 0..32767
    int s = idx >> 5, i = idx & 31;
    float freq = expf(-(float)i * (9.210340371976184f / 32.f));  // 10000^(-i/32)
    float ang = (float)s * freq;
    ctab[idx] = cosf(ang);
    stab[idx] = sinf(ang);
  }
}

// ---------------- MFMA NT GEMM, m97 structure (unchanged) ----------------
template<int EPI>
__global__ __launch_bounds__(256) void gemm_nt(
    const u16* __restrict__ A, const u16* __restrict__ Bw,
    const float* __restrict__ bias, float* __restrict__ outF,
    u16* __restrict__ q1t, u16* __restrict__ q2t,
    u16* __restrict__ k1t, u16* __restrict__ k2t, u16* __restrict__ vtT,
    const float* __restrict__ ctab, const float* __restrict__ stab,
    int N)
{
  const int K = 1024;
  __shared__ u16 As[128 * 32];
  __shared__ u16 Bs[128 * 32];
  int tid  = threadIdx.x;
  int lane = tid & 63, wave = tid >> 6;
  int wm = wave >> 1, wn = wave & 1;
  int m0 = blockIdx.y * 128, n0 = blockIdx.x * 128;
  int fr = lane & 15, hi = lane >> 4;

  int c0 = wave * 128 + lane;
  int c1 = c0 + 64;
  int r0 = c0 >> 2, q0_ = c0 & 3;
  int r1 = c1 >> 2, q1_ = c1 & 3;
  u16* asb0 = &As[wave * 1024];
  u16* asb1 = &As[wave * 1024 + 512];
  u16* bsb0 = &Bs[wave * 1024];
  u16* bsb1 = &Bs[wave * 1024 + 512];
  const u16* ag0 = A  + (size_t)(m0 + r0) * K + q0_ * 8;
  const u16* ag1 = A  + (size_t)(m0 + r1) * K + q1_ * 8;
  const u16* bg0 = Bw + (size_t)(n0 + r0) * K + q0_ * 8;
  const u16* bg1 = Bw + (size_t)(n0 + r1) * K + q1_ * 8;

  f32x4 acc[4][4];
#pragma unroll
  for (int i = 0; i < 4; ++i)
#pragma unroll
    for (int j = 0; j < 4; ++j) acc[i][j] = 0.0f;

  for (int kk0 = 0; kk0 < K; kk0 += 32) {
    __syncthreads();
    gl_lds16(ag0 + kk0, asb0);
    gl_lds16(ag1 + kk0, asb1);
    gl_lds16(bg0 + kk0, bsb0);
    gl_lds16(bg1 + kk0, bsb1);
    __syncthreads();
    bf16x8 af[4], bfv[4];
#pragma unroll
    for (int f = 0; f < 4; ++f) {
      af[f]  = *(const bf16x8*)&As[(wm * 64 + f * 16 + fr) * 32 + hi * 8];
      bfv[f] = *(const bf16x8*)&Bs[(wn * 64 + f * 16 + fr) * 32 + hi * 8];
    }
#pragma unroll
    for (int i = 0; i < 4; ++i)
#pragma unroll
      for (int j = 0; j < 4; ++j)
        acc[i][j] = __builtin_amdgcn_mfma_f32_16x16x32_bf16(af[i], bfv[j], acc[i][j], 0, 0, 0);
  }

  int rg = lane >> 4;
  if (EPI == 0) {
    if (n0 < 4096) {
      u16* dst; int base;
      if (n0 < 1024)      { dst = q1t; base = 0; }
      else if (n0 < 2048) { dst = q2t; base = 1024; }
      else if (n0 < 3072) { dst = k1t; base = 2048; }
      else                { dst = k2t; base = 3072; }
      float qs = (n0 < 2048) ? 0.18033688011112042f : 1.0f;   // 0.125*log2e
#pragma unroll
      for (int i = 0; i < 4; ++i) {
#pragma unroll
        for (int e = 0; e < 4; ++e) {
          int m = m0 + wm * 64 + i * 16 + rg * 4 + e;
          int b = m >> 10, s = m & 1023;
#pragma unroll
          for (int j = 0; j < 2; ++j) {
            int n_lo = n0 + wn * 64 + j * 16 + fr;
            int feat = n_lo - base;
            int h = feat >> 6, dh = feat & 63;   // dh < 32
            float a1 = acc[i][j][e]     + bias[n_lo];
            float a2 = acc[i][j + 2][e] + bias[n_lo + 32];
            float cs = ctab[s * 32 + dh], sn = stab[s * 32 + dh];
            size_t rowb = ((size_t)(b * 16 + h) * 1024 + s) * 64;
            dst[rowb + dh]      = f2b((a1 * cs - a2 * sn) * qs);
            dst[rowb + dh + 32] = f2b((a1 * sn + a2 * cs) * qs);
          }
        }
      }
    } else {
      // v tensor: TRANSPOSED store [bh][dh][s]
#pragma unroll
      for (int i = 0; i < 4; ++i) {
        int mbase = m0 + wm * 64 + i * 16 + rg * 4;
        int b = mbase >> 10, s0 = mbase & 1023;
#pragma unroll
        for (int j = 0; j < 4; ++j) {
          int n = n0 + wn * 64 + j * 16 + fr;
          int feat = n - 4096;
          int h = feat >> 6, dh = feat & 63;
          float bv = bias[n];
          union { u16 hh[4]; uint2 u2; } p;
#pragma unroll
          for (int e = 0; e < 4; ++e) p.hh[e] = f2b(acc[i][j][e] + bv);
          *(uint2*)&vtT[((size_t)(b * 16 + h) * 64 + dh) * 1024 + s0] = p.u2;
        }
      }
    }
  } else {
#pragma unroll
    for (int i = 0; i < 4; ++i)
#pragma unroll
      for (int j = 0; j < 4; ++j)
#pragma unroll
        for (int e = 0; e < 4; ++e) {
          int m = m0 + wm * 64 + i * 16 + rg * 4 + e;
          int n = n0 + wn * 64 + j * 16 + fr;
          outF[(size_t)m * N + n] = acc[i][j][e] + bias[n];
        }
  }
}

// ---------------- fused MFMA attention v8 ----------------
// = r12 structure (2 barriers/tile, reg prefetch, XCD swizzle) + fused GN-stats:
// per-block Sum/SumSq of the ctx chunk computed in-epilogue (deterministic
// shfl tree) -> partials[blockIdx]; eliminates gn_stats' 64MB single-gen read.
__global__ __launch_bounds__(256) void attn_fused(
    const u16* __restrict__ q1t, const u16* __restrict__ q2t,
    const u16* __restrict__ k1t, const u16* __restrict__ k2t,
    const u16* __restrict__ vtT,
    const float* __restrict__ logL, const float* __restrict__ lamp,
    float* __restrict__ ctx, float2* __restrict__ partials)
{
  __shared__ u16 K1s[64][68];
  __shared__ u16 K2s[64][68];
  __shared__ u16 P1s[64][68];
  __shared__ u16 P2s[64][68];
  __shared__ u16 Vts[2][64][68];   // V^T [dh][k], k-blocks XOR-swizzled by (dh>>3)&7
  __shared__ float lred1[2][2][32];
  __shared__ float lred2[2][2][32];
  __shared__ float pred[4][2];

  int tid  = threadIdx.x;
  int lane = tid & 63, wave = tid >> 6;
  int wm = wave >> 1, wn = wave & 1;
  int id = blockIdx.x;
  int bh = (id & 7) * 8 + (id >> 7);        // XCD-grouped: 8 bh per XCD (L2-fit)
  int q0 = ((id >> 3) & 15) * 64;
  int b = bh >> 4;
  int fr = lane & 15, hi = lane >> 4;

  bf16x8 qf1[2][2], qf2[2][2];
#pragma unroll
  for (int i = 0; i < 2; ++i)
#pragma unroll
    for (int ks = 0; ks < 2; ++ks) {
      size_t off = ((size_t)bh * 1024 + q0 + wm * 32 + i * 16 + fr) * 64 + ks * 32 + hi * 8;
      qf1[i][ks] = *(const bf16x8*)(q1t + off);
      qf2[i][ks] = *(const bf16x8*)(q2t + off);
    }
  float Lq[2][4];
#pragma unroll
  for (int i = 0; i < 2; ++i)
#pragma unroll
    for (int r = 0; r < 4; ++r)
      Lq[i][r] = logL[b * 1024 + q0 + wm * 32 + i * 16 + hi * 4 + r];

  float lacc1[2][4], lacc2[2][4];
  f32x4 U1[2][2], U2[2][2];
#pragma unroll
  for (int i = 0; i < 2; ++i)
#pragma unroll
    for (int r = 0; r < 4; ++r) { lacc1[i][r] = 0.f; lacc2[i][r] = 0.f; }
#pragma unroll
  for (int i = 0; i < 2; ++i)
#pragma unroll
    for (int j = 0; j < 2; ++j) { U1[i][j] = 0.f; U2[i][j] = 0.f; }

  int sr = tid >> 2, sc0 = (tid & 3) * 16;
  int swz = (sr >> 3) & 7;
  int blk0 = ((sc0 >> 3) ^ swz) << 3;
  int blk1 = (((sc0 >> 3) + 1) ^ swz) << 3;

  // LDS byte addresses for packed P writes (row wm*32+hi*4, col wn*32+fr)
  unsigned a1base = (unsigned)(size_t)&P1s[wm * 32 + hi * 4][wn * 32 + fr];
  unsigned a2base = (unsigned)(size_t)&P2s[wm * 32 + hi * 4][wn * 32 + fr];

  // staging global bases (per-lane)
  const u16* kg1 = k1t + ((size_t)bh * 1024 + sr) * 64 + sc0;   // + kt*4096
  const u16* kg2 = k2t + ((size_t)bh * 1024 + sr) * 64 + sc0;
  const u16* vgT = vtT + (size_t)bh * 65536 + (size_t)sr * 1024 + sc0;  // + kt*64

  // prologue: prefetch tile 0
  bf16x8 ra0 = *(const bf16x8*)(kg1),  ra1 = *(const bf16x8*)(kg1 + 8);
  bf16x8 rb0 = *(const bf16x8*)(kg2),  rb1 = *(const bf16x8*)(kg2 + 8);
  bf16x8 rv0 = *(const bf16x8*)(vgT),  rv1 = *(const bf16x8*)(vgT + 8);

  for (int kt = 0; kt < 16; ++kt) {
    // ---- LDS write of tile kt (regs already hold it) ----
    *(bf16x8*)&K1s[sr][sc0]          = ra0;  *(bf16x8*)&K1s[sr][sc0 + 8] = ra1;
    *(bf16x8*)&K2s[sr][sc0]          = rb0;  *(bf16x8*)&K2s[sr][sc0 + 8] = rb1;
    *(bf16x8*)&Vts[kt & 1][sr][blk0] = rv0;  *(bf16x8*)&Vts[kt & 1][sr][blk1] = rv1;
    float Ltl[2];
#pragma unroll
    for (int j = 0; j < 2; ++j) Ltl[j] = logL[b * 1024 + kt * 64 + wn * 32 + j * 16 + fr];
    __syncthreads();   // barA: stage visible; also fences all waves' prev PV

    // ---- prefetch tile kt+1 (latency hides under QK^T + exp) ----
    if (kt < 15) {
      size_t ko = (size_t)(kt + 1) * 4096;
      size_t vo = (size_t)(kt + 1) * 64;
      ra0 = *(const bf16x8*)(kg1 + ko);  ra1 = *(const bf16x8*)(kg1 + ko + 8);
      rb0 = *(const bf16x8*)(kg2 + ko);  rb1 = *(const bf16x8*)(kg2 + ko + 8);
      rv0 = *(const bf16x8*)(vgT + vo);  rv1 = *(const bf16x8*)(vgT + vo + 8);
    }

    // ---- QK^T ----
    f32x4 S1[2][2], S2[2][2];
#pragma unroll
    for (int i = 0; i < 2; ++i)
#pragma unroll
      for (int j = 0; j < 2; ++j) { S1[i][j] = 0.f; S2[i][j] = 0.f; }
    __builtin_amdgcn_s_setprio(1);
#pragma unroll
    for (int ks = 0; ks < 2; ++ks) {
      bf16x8 kf1[2], kf2[2];
#pragma unroll
      for (int j = 0; j < 2; ++j) {
        kf1[j] = *(const bf16x8*)&K1s[wn * 32 + j * 16 + fr][ks * 32 + hi * 8];
        kf2[j] = *(const bf16x8*)&K2s[wn * 32 + j * 16 + fr][ks * 32 + hi * 8];
      }
#pragma unroll
      for (int i = 0; i < 2; ++i)
#pragma unroll
        for (int j = 0; j < 2; ++j) {
          S1[i][j] = __builtin_amdgcn_mfma_f32_16x16x32_bf16(qf1[i][ks], kf1[j], S1[i][j], 0, 0, 0);
          S2[i][j] = __builtin_amdgcn_mfma_f32_16x16x32_bf16(qf2[i][ks], kf2[j], S2[i][j], 0, 0, 0);
        }
    }
    __builtin_amdgcn_s_setprio(0);

    // ---- exponentials (log2 domain) + packed P write ----
#pragma unroll
    for (int i = 0; i < 2; ++i) {
#pragma unroll
      for (int r = 0; r < 4; ++r) {
        float lq = Lq[i][r];
        float e1j[2], e2j[2], p1j[2], p2j[2];
#pragma unroll
        for (int j = 0; j < 2; ++j) {
          float nd = -fabsf(Ltl[j] - lq);
          float t1, t2, ec;
          asm("v_exp_f32 %0, %1" : "=v"(t1) : "v"(S1[i][j][r]));
          asm("v_exp_f32 %0, %1" : "=v"(t2) : "v"(S2[i][j][r]));
          asm("v_exp_f32 %0, %1" : "=v"(ec) : "v"(nd));
          e1j[j] = t1; e2j[j] = t2;
          p1j[j] = t1 * ec; p2j[j] = t2 * ec;
        }
        lacc1[i][r] += e1j[0] + e1j[1];
        lacc2[i][r] += e2j[0] + e2j[1];
        unsigned off = (unsigned)((i * 16 + r) * 136);
        unsigned ad1 = a1base + off, ad2 = a2base + off;
        unsigned pk1, pk2;
        asm("v_cvt_pk_bf16_f32 %0, %1, %2" : "=v"(pk1) : "v"(p1j[0]), "v"(p1j[1]));
        asm("v_cvt_pk_bf16_f32 %0, %1, %2" : "=v"(pk2) : "v"(p2j[0]), "v"(p2j[1]));
        asm volatile("ds_write_b16 %0, %1\n\tds_write_b16_d16_hi %0, %1 offset:32"
                     :: "v"(ad1), "v"(pk1) : "memory");
        asm volatile("ds_write_b16 %0, %1\n\tds_write_b16_d16_hi %0, %1 offset:32"
                     :: "v"(ad2), "v"(pk2) : "memory");
      }
    }
    __syncthreads();   // barB: P visible; also fences all waves' QK^T reads of K

    // ---- PV: U += P * V (P in P1s/P2s, V^T in Vts[kt&1]) ----
    __builtin_amdgcn_s_setprio(1);
#pragma unroll
    for (int ks = 0; ks < 2; ++ks) {
      bf16x8 pa1[2], pa2[2], vb[2];
#pragma unroll
      for (int i = 0; i < 2; ++i) {
        pa1[i] = *(const bf16x8*)&P1s[wm * 32 + i * 16 + fr][ks * 32 + hi * 8];
        pa2[i] = *(const bf16x8*)&P2s[wm * 32 + i * 16 + fr][ks * 32 + hi * 8];
      }
#pragma unroll
      for (int j = 0; j < 2; ++j) {
        int row = wn * 32 + j * 16 + fr;
        int kbb = (ks * 4 + hi) ^ ((row >> 3) & 7);
        vb[j] = *(const bf16x8*)&Vts[kt & 1][row][kbb << 3];
      }
#pragma unroll
      for (int i = 0; i < 2; ++i)
#pragma unroll
        for (int j = 0; j < 2; ++j) {
          U1[i][j] = __builtin_amdgcn_mfma_f32_16x16x32_bf16(pa1[i], vb[j], U1[i][j], 0, 0, 0);
          U2[i][j] = __builtin_amdgcn_mfma_f32_16x16x32_bf16(pa2[i], vb[j], U2[i][j], 0, 0, 0);
        }
    }
    __builtin_amdgcn_s_setprio(0);
  }

  // ---- denominator: intra-wave reduce over fr, then cross-wave over wn ----
#pragma unroll
  for (int i = 0; i < 2; ++i)
#pragma unroll
    for (int r = 0; r < 4; ++r) {
#pragma unroll
      for (int m = 1; m < 16; m <<= 1) {
        lacc1[i][r] += __shfl_xor(lacc1[i][r], m);
        lacc2[i][r] += __shfl_xor(lacc2[i][r], m);
      }
    }
  if (fr == 0) {
#pragma unroll
    for (int i = 0; i < 2; ++i)
#pragma unroll
      for (int r = 0; r < 4; ++r) {
        int rl = i * 16 + hi * 4 + r;
        lred1[wn][wm][rl] = lacc1[i][r];
        lred2[wn][wm][rl] = lacc2[i][r];
      }
  }
  __syncthreads();
  float lam = lamp[0];

  // ---- epilogue: ctx = U1/l1 - lam*U2/l2, plus block partial Sum/SumSq ----
  float psum = 0.f, psq = 0.f;
#pragma unroll
  for (int i = 0; i < 2; ++i) {
#pragma unroll
    for (int r = 0; r < 4; ++r) {
      int rl = i * 16 + hi * 4 + r;
      float l1 = lred1[0][wm][rl] + lred1[1][wm][rl];
      float l2 = lred2[0][wm][rl] + lred2[1][wm][rl];
      float inv1 = 1.f / l1;
      float inv2 = lam / l2;
      int qg = q0 + wm * 32 + i * 16 + hi * 4 + r;
#pragma unroll
      for (int j = 0; j < 2; ++j) {
        int dh = wn * 32 + j * 16 + fr;
        float o = U1[i][j][r] * inv1 - U2[i][j][r] * inv2;
        ctx[((size_t)bh * 1024 + qg) * 64 + dh] = o;
        psum += o; psq += o * o;
      }
    }
  }
#pragma unroll
  for (int m = 1; m < 64; m <<= 1) {
    psum += __shfl_xor(psum, m);
    psq  += __shfl_xor(psq, m);
  }
  if (lane == 0) { pred[wave][0] = psum; pred[wave][1] = psq; }
  __syncthreads();
  if (tid == 0)
    partials[id] = make_float2(pred[0][0] + pred[1][0] + pred[2][0] + pred[3][0],
                               pred[0][1] + pred[1][1] + pred[2][1] + pred[3][1]);
}

// ---------------- combine partials -> mean/rsqrt per (b,h) ----------------
__global__ __launch_bounds__(64) void gn_combine(
    const float2* __restrict__ partials, float2* __restrict__ mv)
{
  int bh = blockIdx.x;
  int m = threadIdx.x;
  float s = 0.f, ss = 0.f;
  if (m < 16) {
    float2 p = partials[(bh & 7) * 128 + m * 8 + (bh >> 3)];
    s = p.x; ss = p.y;
  }
#pragma unroll
  for (int o = 1; o < 16; o <<= 1) { s += __shfl_xor(s, o); ss += __shfl_xor(ss, o); }
  if (m == 0) {
    float mean = s / 65536.f;
    float var = ss / 65536.f - mean * mean;
    mv[bh] = make_float2(mean, rsqrtf(var + 1e-5f));
  }
}

__global__ __launch_bounds__(256) void gn_apply(
    const float* __restrict__ ctx, const float2* __restrict__ mv,
    const float* __restrict__ gw, const float* __restrict__ gb,
    u16* __restrict__ normed)
{
  unsigned idx = blockIdx.x * 256u + threadIdx.x;
  unsigned i = idx * 4;
  unsigned d = i & 1023u;
  unsigned srow = i >> 10;
  unsigned b = srow >> 10;
  unsigned h = d >> 6, dh = d & 63u;
  float2 m = mv[b * 16 + h];
  float4 x = *(const float4*)&ctx[(((size_t)(b * 16 + h)) * 1024 + (srow & 1023u)) * 64 + dh];
  float4 g = *(const float4*)&gw[d];
  float4 be = *(const float4*)&gb[d];
  union { u16 hh[4]; uint2 u2; } p;
  p.hh[0] = f2b(((x.x - m.x) * m.y * g.x + be.x) * 0.8f);
  p.hh[1] = f2b(((x.y - m.x) * m.y * g.y + be.y) * 0.8f);
  p.hh[2] = f2b(((x.z - m.x) * m.y * g.z + be.z) * 0.8f);
  p.hh[3] = f2b(((x.w - m.x) * m.y * g.w + be.w) * 0.8f);
  *(uint2*)(normed + i) = p.u2;
}

// ---------------- launch ----------------
extern "C" void kernel_launch(void* const* d_in, const int* in_sizes, int n_in,
                              void* d_out, int out_size, void* d_ws, size_t ws_size,
                              hipStream_t stream) {
  (void)in_sizes; (void)n_in; (void)out_size; (void)ws_size;
  const float* x   = (const float*)d_in[0];
  const float* aff = (const float*)d_in[1];
  const float* Wq  = (const float*)d_in[2];
  const float* bq  = (const float*)d_in[3];
  const float* Wk  = (const float*)d_in[4];
  const float* bk  = (const float*)d_in[5];
  const float* Wv  = (const float*)d_in[6];
  const float* bv  = (const float*)d_in[7];
  const float* Wo  = (const float*)d_in[8];
  const float* bo  = (const float*)d_in[9];
  const float* gw  = (const float*)d_in[10];
  const float* gb  = (const float*)d_in[11];
  const float* lam = (const float*)d_in[12];
  float* out = (float*)d_out;

  char* w = (char*)d_ws;
  u16*    xb    = (u16*)(w);
  u16*    Wcat  = (u16*)(w + 8388608);
  u16*    Wob   = (u16*)(w + 18874368);
  float*  bcat  = (float*)(w + 20971520);
  u16*    q1t   = (u16*)(w + 20992000);
  u16*    q2t   = (u16*)(w + 29380608);
  u16*    k1t   = (u16*)(w + 37769216);
  u16*    k2t   = (u16*)(w + 46157824);
  u16*    vtT   = (u16*)(w + 54546432);   // [bh][dh][s] transposed
  float*  logL  = (float*)(w + 62935040);
  float*  ctab  = (float*)(w + 62951424);
  float*  stab  = (float*)(w + 63082496);
  float2* parts = (float2*)(w + 63213568); // 1024 float2 (gap before ctx)
  float*  ctx   = (float*)(w + 63475712);
  float2* mv    = (float2*)(w + 80252928);
  u16*    normed= (u16*)(w + 80253440);

  convert_kernel<<<10245, 256, 0, stream>>>(x, Wq, Wk, Wv, Wo, bq, bk, bv, xb, Wcat, Wob, bcat);
  prep_kernel<<<36, 1024, 0, stream>>>(aff, logL, ctab, stab);
  gemm_nt<0><<<dim3(40, 32), 256, 0, stream>>>(xb, Wcat, bcat, nullptr, q1t, q2t, k1t, k2t, vtT, ctab, stab, 5120);
  attn_fused<<<1024, 256, 0, stream>>>(q1t, q2t, k1t, k2t, vtT, logL, lam, ctx, parts);
  gn_combine<<<64, 64, 0, stream>>>(parts, mv);
  gn_apply<<<4096, 256, 0, stream>>>(ctx, mv, gw, gb, normed);
  gemm_nt<1><<<dim3(8, 32), 256, 0, stream>>>(normed, Wob, bo, out, nullptr, nullptr, nullptr, nullptr, nullptr, ctab, stab, 1024);
}

// Round 14
// 198.801 us; speedup vs baseline: 1.1302x; 1.1302x over previous
//
#include <hip/hip_runtime.h>
#include <math.h>

typedef float  f32x4  __attribute__((ext_vector_type(4)));
typedef short  bf16x8 __attribute__((ext_vector_type(8)));
typedef unsigned short u16;

__device__ __forceinline__ u16 f2b(float f) {
  union { float f; unsigned u; } v; v.f = f;
  unsigned r = v.u + 0x7FFFu + ((v.u >> 16) & 1u);
  return (u16)(r >> 16);
}
__device__ __forceinline__ float b2f(u16 h) {
  union { unsigned u; float f; } v; v.u = ((unsigned)h) << 16;
  return v.f;
}

// async global->LDS, 16B per lane; dest = wave-uniform base + lane*16
__device__ __forceinline__ void gl_lds16(const u16* g, u16* l) {
  __builtin_amdgcn_global_load_lds(
      (const __attribute__((address_space(1))) unsigned*)g,
      (__attribute__((address_space(3))) unsigned*)l, 16, 0, 0);
}

// ---------------- fp32 -> bf16 conversion / packing ----------------
__global__ __launch_bounds__(256) void convert_kernel(
    const float* __restrict__ x,  const float* __restrict__ Wq,
    const float* __restrict__ Wk, const float* __restrict__ Wv,
    const float* __restrict__ Wo, const float* __restrict__ bq,
    const float* __restrict__ bk, const float* __restrict__ bv,
    u16* __restrict__ xb, u16* __restrict__ Wcat, u16* __restrict__ Wob,
    float* __restrict__ bcat)
{
  long i = ((long)blockIdx.x * 256 + threadIdx.x) * 4;
  if (i < 10485760L) {
    const float* src; u16* dst; long o;
    if (i < 4194304L)      { src = x;  dst = xb;             o = i; }
    else if (i < 6291456L) { src = Wq; dst = Wcat;           o = i - 4194304L; }
    else if (i < 8388608L) { src = Wk; dst = Wcat + 2097152; o = i - 6291456L; }
    else if (i < 9437184L) { src = Wv; dst = Wcat + 4194304; o = i - 8388608L; }
    else                   { src = Wo; dst = Wob;            o = i - 9437184L; }
    float4 v = *(const float4*)(src + o);
    union { u16 h[4]; uint2 u2; } p;
    p.h[0] = f2b(v.x); p.h[1] = f2b(v.y); p.h[2] = f2b(v.z); p.h[3] = f2b(v.w);
    *(uint2*)(dst + o) = p.u2;
  } else if (i < 10490880L) {
    long j = i - 10485760L;
    const float* src; long o;
    if (j < 2048)      { src = bq; o = j; }
    else if (j < 4096) { src = bk; o = j - 2048; }
    else               { src = bv; o = j - 4096; }
    *(float4*)(bcat + j) = *(const float4*)(src + o);
  }
}

// ---------------- prep: logL scan (blocks 0-3) + RoPE table (blocks 4-35) ----------------
__global__ __launch_bounds__(1024) void prep_kernel(
    const float* __restrict__ a, float* __restrict__ logL,
    float* __restrict__ ctab, float* __restrict__ stab)
{
  if (blockIdx.x < 4) {
    __shared__ float sh[1024];
    int b = blockIdx.x, t = threadIdx.x;
    float v = (t == 0) ? 0.f : log2f(a[b * 1023 + t - 1]);
    sh[t] = v;
    __syncthreads();
    for (int off = 1; off < 1024; off <<= 1) {
      float add = (t >= off) ? sh[t - off] : 0.f;
      __syncthreads();
      sh[t] += add;
      __syncthreads();
    }
    logL[b * 1024 + t] = sh[t];
  } else {
    int idx = (blockIdx.x - 4) * 1024 + threadIdx.x;   // 0..32767
    int s = idx >> 5, i = idx & 31;
    float freq = expf(-(float)i * (9.210340371976184f / 32.f));  // 10000^(-i/32)
    float ang = (float)s * freq;
    ctab[idx] = cosf(ang);
    stab[idx] = sinf(ang);
  }
}

// ---------------- MFMA NT GEMM, m97 structure (unchanged) ----------------
template<int EPI>
__global__ __launch_bounds__(256) void gemm_nt(
    const u16* __restrict__ A, const u16* __restrict__ Bw,
    const float* __restrict__ bias, float* __restrict__ outF,
    u16* __restrict__ q1t, u16* __restrict__ q2t,
    u16* __restrict__ k1t, u16* __restrict__ k2t, u16* __restrict__ vtT,
    const float* __restrict__ ctab, const float* __restrict__ stab,
    int N)
{
  const int K = 1024;
  __shared__ u16 As[128 * 32];
  __shared__ u16 Bs[128 * 32];
  int tid  = threadIdx.x;
  int lane = tid & 63, wave = tid >> 6;
  int wm = wave >> 1, wn = wave & 1;
  int m0 = blockIdx.y * 128, n0 = blockIdx.x * 128;
  int fr = lane & 15, hi = lane >> 4;

  int c0 = wave * 128 + lane;
  int c1 = c0 + 64;
  int r0 = c0 >> 2, q0_ = c0 & 3;
  int r1 = c1 >> 2, q1_ = c1 & 3;
  u16* asb0 = &As[wave * 1024];
  u16* asb1 = &As[wave * 1024 + 512];
  u16* bsb0 = &Bs[wave * 1024];
  u16* bsb1 = &Bs[wave * 1024 + 512];
  const u16* ag0 = A  + (size_t)(m0 + r0) * K + q0_ * 8;
  const u16* ag1 = A  + (size_t)(m0 + r1) * K + q1_ * 8;
  const u16* bg0 = Bw + (size_t)(n0 + r0) * K + q0_ * 8;
  const u16* bg1 = Bw + (size_t)(n0 + r1) * K + q1_ * 8;

  f32x4 acc[4][4];
#pragma unroll
  for (int i = 0; i < 4; ++i)
#pragma unroll
    for (int j = 0; j < 4; ++j) acc[i][j] = 0.0f;

  for (int kk0 = 0; kk0 < K; kk0 += 32) {
    __syncthreads();
    gl_lds16(ag0 + kk0, asb0);
    gl_lds16(ag1 + kk0, asb1);
    gl_lds16(bg0 + kk0, bsb0);
    gl_lds16(bg1 + kk0, bsb1);
    __syncthreads();
    bf16x8 af[4], bfv[4];
#pragma unroll
    for (int f = 0; f < 4; ++f) {
      af[f]  = *(const bf16x8*)&As[(wm * 64 + f * 16 + fr) * 32 + hi * 8];
      bfv[f] = *(const bf16x8*)&Bs[(wn * 64 + f * 16 + fr) * 32 + hi * 8];
    }
#pragma unroll
    for (int i = 0; i < 4; ++i)
#pragma unroll
      for (int j = 0; j < 4; ++j)
        acc[i][j] = __builtin_amdgcn_mfma_f32_16x16x32_bf16(af[i], bfv[j], acc[i][j], 0, 0, 0);
  }

  int rg = lane >> 4;
  if (EPI == 0) {
    if (n0 < 4096) {
      u16* dst; int base;
      if (n0 < 1024)      { dst = q1t; base = 0; }
      else if (n0 < 2048) { dst = q2t; base = 1024; }
      else if (n0 < 3072) { dst = k1t; base = 2048; }
      else                { dst = k2t; base = 3072; }
      float qs = (n0 < 2048) ? 0.18033688011112042f : 1.0f;   // 0.125*log2e
#pragma unroll
      for (int i = 0; i < 4; ++i) {
#pragma unroll
        for (int e = 0; e < 4; ++e) {
          int m = m0 + wm * 64 + i * 16 + rg * 4 + e;
          int b = m >> 10, s = m & 1023;
#pragma unroll
          for (int j = 0; j < 2; ++j) {
            int n_lo = n0 + wn * 64 + j * 16 + fr;
            int feat = n_lo - base;
            int h = feat >> 6, dh = feat & 63;   // dh < 32
            float a1 = acc[i][j][e]     + bias[n_lo];
            float a2 = acc[i][j + 2][e] + bias[n_lo + 32];
            float cs = ctab[s * 32 + dh], sn = stab[s * 32 + dh];
            size_t rowb = ((size_t)(b * 16 + h) * 1024 + s) * 64;
            dst[rowb + dh]      = f2b((a1 * cs - a2 * sn) * qs);
            dst[rowb + dh + 32] = f2b((a1 * sn + a2 * cs) * qs);
          }
        }
      }
    } else {
      // v tensor: TRANSPOSED store [bh][dh][s]
#pragma unroll
      for (int i = 0; i < 4; ++i) {
        int mbase = m0 + wm * 64 + i * 16 + rg * 4;
        int b = mbase >> 10, s0 = mbase & 1023;
#pragma unroll
        for (int j = 0; j < 4; ++j) {
          int n = n0 + wn * 64 + j * 16 + fr;
          int feat = n - 4096;
          int h = feat >> 6, dh = feat & 63;
          float bv = bias[n];
          union { u16 hh[4]; uint2 u2; } p;
#pragma unroll
          for (int e = 0; e < 4; ++e) p.hh[e] = f2b(acc[i][j][e] + bv);
          *(uint2*)&vtT[((size_t)(b * 16 + h) * 64 + dh) * 1024 + s0] = p.u2;
        }
      }
    }
  } else {
#pragma unroll
    for (int i = 0; i < 4; ++i)
#pragma unroll
      for (int j = 0; j < 4; ++j)
#pragma unroll
        for (int e = 0; e < 4; ++e) {
          int m = m0 + wm * 64 + i * 16 + rg * 4 + e;
          int n = n0 + wn * 64 + j * 16 + fr;
          outF[(size_t)m * N + n] = acc[i][j][e] + bias[n];
        }
  }
}

// ---------------- fused MFMA attention v9 ----------------
// = r11 structure (4-barrier, direct-staged, P aliased into K-space, VGPR 104
// -- measured 88.0us) + GN-stats fusion epilogue. r13's regression was the
// 128-VGPR occupancy cliff (m69): r12's 128 + 2 fusion regs = 132 -> waves
// halved. r11's 104 leaves ~24 regs of headroom for the fusion.
__global__ __launch_bounds__(256) void attn_fused(
    const u16* __restrict__ q1t, const u16* __restrict__ q2t,
    const u16* __restrict__ k1t, const u16* __restrict__ k2t,
    const u16* __restrict__ vtT,
    const float* __restrict__ logL, const float* __restrict__ lamp,
    float* __restrict__ ctx, float2* __restrict__ partials)
{
  __shared__ u16 K1s[64][72];   // K1 during QK^T, P1 during PV
  __shared__ u16 K2s[64][72];   // K2 during QK^T, P2 during PV
  __shared__ u16 Vts[64][72];   // V^T [dh][k], k-blocks XOR-swizzled by (dh>>3)&7
  __shared__ float lred1[2][2][32];
  __shared__ float lred2[2][2][32];
  __shared__ float pred[4][2];

  int tid  = threadIdx.x;
  int lane = tid & 63, wave = tid >> 6;
  int wm = wave >> 1, wn = wave & 1;
  int id = blockIdx.x;
  int bh = (id & 7) * 8 + (id >> 7);        // XCD-grouped: 8 bh per XCD (L2-fit)
  int q0 = ((id >> 3) & 15) * 64;
  int b = bh >> 4;
  int fr = lane & 15, hi = lane >> 4;

  bf16x8 qf1[2][2], qf2[2][2];
#pragma unroll
  for (int i = 0; i < 2; ++i)
#pragma unroll
    for (int ks = 0; ks < 2; ++ks) {
      size_t off = ((size_t)bh * 1024 + q0 + wm * 32 + i * 16 + fr) * 64 + ks * 32 + hi * 8;
      qf1[i][ks] = *(const bf16x8*)(q1t + off);
      qf2[i][ks] = *(const bf16x8*)(q2t + off);
    }
  float Lq[2][4];
#pragma unroll
  for (int i = 0; i < 2; ++i)
#pragma unroll
    for (int r = 0; r < 4; ++r)
      Lq[i][r] = logL[b * 1024 + q0 + wm * 32 + i * 16 + hi * 4 + r];

  float lacc1[2][4], lacc2[2][4];
  f32x4 U1[2][2], U2[2][2];
#pragma unroll
  for (int i = 0; i < 2; ++i)
#pragma unroll
    for (int r = 0; r < 4; ++r) { lacc1[i][r] = 0.f; lacc2[i][r] = 0.f; }
#pragma unroll
  for (int i = 0; i < 2; ++i)
#pragma unroll
    for (int j = 0; j < 2; ++j) { U1[i][j] = 0.f; U2[i][j] = 0.f; }

  int sr = tid >> 2, sc0 = (tid & 3) * 16;
  int swz = (sr >> 3) & 7;
  int blk0 = ((sc0 >> 3) ^ swz) << 3;
  int blk1 = (((sc0 >> 3) + 1) ^ swz) << 3;

  // LDS byte addresses for packed P writes (row wm*32+hi*4, col wn*32+fr)
  unsigned a1base = (unsigned)(size_t)&K1s[wm * 32 + hi * 4][wn * 32 + fr];
  unsigned a2base = (unsigned)(size_t)&K2s[wm * 32 + hi * 4][wn * 32 + fr];

  for (int kt = 0; kt < 16; ++kt) {
    __syncthreads();   // (1) prev PV reads done
    size_t gb = ((size_t)bh * 1024 + kt * 64 + sr) * 64 + sc0;
    size_t gv = (size_t)bh * 65536 + (size_t)sr * 1024 + kt * 64 + sc0;
    bf16x8 a0 = *(const bf16x8*)(k1t + gb), a1 = *(const bf16x8*)(k1t + gb + 8);
    bf16x8 b0 = *(const bf16x8*)(k2t + gb), b1 = *(const bf16x8*)(k2t + gb + 8);
    bf16x8 v0 = *(const bf16x8*)(vtT + gv), v1 = *(const bf16x8*)(vtT + gv + 8);
    *(bf16x8*)&K1s[sr][sc0]     = a0;  *(bf16x8*)&K1s[sr][sc0 + 8] = a1;
    *(bf16x8*)&K2s[sr][sc0]     = b0;  *(bf16x8*)&K2s[sr][sc0 + 8] = b1;
    *(bf16x8*)&Vts[sr][blk0]    = v0;  *(bf16x8*)&Vts[sr][blk1]    = v1;
    float Ltl[2];
#pragma unroll
    for (int j = 0; j < 2; ++j) Ltl[j] = logL[b * 1024 + kt * 64 + wn * 32 + j * 16 + fr];
    __syncthreads();   // (2) stage complete

    // ---- QK^T ----
    f32x4 S1[2][2], S2[2][2];
#pragma unroll
    for (int i = 0; i < 2; ++i)
#pragma unroll
      for (int j = 0; j < 2; ++j) { S1[i][j] = 0.f; S2[i][j] = 0.f; }
    __builtin_amdgcn_s_setprio(1);
#pragma unroll
    for (int ks = 0; ks < 2; ++ks) {
      bf16x8 kf1[2], kf2[2];
#pragma unroll
      for (int j = 0; j < 2; ++j) {
        kf1[j] = *(const bf16x8*)&K1s[wn * 32 + j * 16 + fr][ks * 32 + hi * 8];
        kf2[j] = *(const bf16x8*)&K2s[wn * 32 + j * 16 + fr][ks * 32 + hi * 8];
      }
#pragma unroll
      for (int i = 0; i < 2; ++i)
#pragma unroll
        for (int j = 0; j < 2; ++j) {
          S1[i][j] = __builtin_amdgcn_mfma_f32_16x16x32_bf16(qf1[i][ks], kf1[j], S1[i][j], 0, 0, 0);
          S2[i][j] = __builtin_amdgcn_mfma_f32_16x16x32_bf16(qf2[i][ks], kf2[j], S2[i][j], 0, 0, 0);
        }
    }
    __builtin_amdgcn_s_setprio(0);
    __syncthreads();   // (3) all K reads done -> K-space reusable as P

    // ---- exponentials (log2 domain) + packed P write ----
#pragma unroll
    for (int i = 0; i < 2; ++i) {
#pragma unroll
      for (int r = 0; r < 4; ++r) {
        float lq = Lq[i][r];
        float e1j[2], e2j[2], p1j[2], p2j[2];
#pragma unroll
        for (int j = 0; j < 2; ++j) {
          float nd = -fabsf(Ltl[j] - lq);
          float t1, t2, ec;
          asm("v_exp_f32 %0, %1" : "=v"(t1) : "v"(S1[i][j][r]));
          asm("v_exp_f32 %0, %1" : "=v"(t2) : "v"(S2[i][j][r]));
          asm("v_exp_f32 %0, %1" : "=v"(ec) : "v"(nd));
          e1j[j] = t1; e2j[j] = t2;
          p1j[j] = t1 * ec; p2j[j] = t2 * ec;
        }
        lacc1[i][r] += e1j[0] + e1j[1];
        lacc2[i][r] += e2j[0] + e2j[1];
        unsigned off = (unsigned)((i * 16 + r) * 144);
        unsigned ad1 = a1base + off, ad2 = a2base + off;
        unsigned pk1, pk2;
        asm("v_cvt_pk_bf16_f32 %0, %1, %2" : "=v"(pk1) : "v"(p1j[0]), "v"(p1j[1]));
        asm("v_cvt_pk_bf16_f32 %0, %1, %2" : "=v"(pk2) : "v"(p2j[0]), "v"(p2j[1]));
        asm volatile("ds_write_b16 %0, %1\n\tds_write_b16_d16_hi %0, %1 offset:32"
                     :: "v"(ad1), "v"(pk1) : "memory");
        asm volatile("ds_write_b16 %0, %1\n\tds_write_b16_d16_hi %0, %1 offset:32"
                     :: "v"(ad2), "v"(pk2) : "memory");
      }
    }
    __syncthreads();   // (4) P complete

    // ---- PV: U += P * V (P in K1s/K2s, V^T in Vts) ----
    __builtin_amdgcn_s_setprio(1);
#pragma unroll
    for (int ks = 0; ks < 2; ++ks) {
      bf16x8 pa1[2], pa2[2], vb[2];
#pragma unroll
      for (int i = 0; i < 2; ++i) {
        pa1[i] = *(const bf16x8*)&K1s[wm * 32 + i * 16 + fr][ks * 32 + hi * 8];
        pa2[i] = *(const bf16x8*)&K2s[wm * 32 + i * 16 + fr][ks * 32 + hi * 8];
      }
#pragma unroll
      for (int j = 0; j < 2; ++j) {
        int row = wn * 32 + j * 16 + fr;
        int kbb = (ks * 4 + hi) ^ ((row >> 3) & 7);
        vb[j] = *(const bf16x8*)&Vts[row][kbb << 3];
      }
#pragma unroll
      for (int i = 0; i < 2; ++i)
#pragma unroll
        for (int j = 0; j < 2; ++j) {
          U1[i][j] = __builtin_amdgcn_mfma_f32_16x16x32_bf16(pa1[i], vb[j], U1[i][j], 0, 0, 0);
          U2[i][j] = __builtin_amdgcn_mfma_f32_16x16x32_bf16(pa2[i], vb[j], U2[i][j], 0, 0, 0);
        }
    }
    __builtin_amdgcn_s_setprio(0);
  }

  // ---- denominator: intra-wave reduce over fr, then cross-wave over wn ----
#pragma unroll
  for (int i = 0; i < 2; ++i)
#pragma unroll
    for (int r = 0; r < 4; ++r) {
#pragma unroll
      for (int m = 1; m < 16; m <<= 1) {
        lacc1[i][r] += __shfl_xor(lacc1[i][r], m);
        lacc2[i][r] += __shfl_xor(lacc2[i][r], m);
      }
    }
  if (fr == 0) {
#pragma unroll
    for (int i = 0; i < 2; ++i)
#pragma unroll
      for (int r = 0; r < 4; ++r) {
        int rl = i * 16 + hi * 4 + r;
        lred1[wn][wm][rl] = lacc1[i][r];
        lred2[wn][wm][rl] = lacc2[i][r];
      }
  }
  __syncthreads();
  float lam = lamp[0];

  // ---- epilogue: ctx = U1/l1 - lam*U2/l2, plus block partial Sum/SumSq ----
  float psum = 0.f, psq = 0.f;
#pragma unroll
  for (int i = 0; i < 2; ++i) {
#pragma unroll
    for (int r = 0; r < 4; ++r) {
      int rl = i * 16 + hi * 4 + r;
      float l1 = lred1[0][wm][rl] + lred1[1][wm][rl];
      float l2 = lred2[0][wm][rl] + lred2[1][wm][rl];
      float inv1 = 1.f / l1;
      float inv2 = lam / l2;
      int qg = q0 + wm * 32 + i * 16 + hi * 4 + r;
#pragma unroll
      for (int j = 0; j < 2; ++j) {
        int dh = wn * 32 + j * 16 + fr;
        float o = U1[i][j][r] * inv1 - U2[i][j][r] * inv2;
        ctx[((size_t)bh * 1024 + qg) * 64 + dh] = o;
        psum += o; psq += o * o;
      }
    }
  }
#pragma unroll
  for (int m = 1; m < 64; m <<= 1) {
    psum += __shfl_xor(psum, m);
    psq  += __shfl_xor(psq, m);
  }
  if (lane == 0) { pred[wave][0] = psum; pred[wave][1] = psq; }
  __syncthreads();
  if (tid == 0)
    partials[id] = make_float2(pred[0][0] + pred[1][0] + pred[2][0] + pred[3][0],
                               pred[0][1] + pred[1][1] + pred[2][1] + pred[3][1]);
}

// ---------------- combine partials -> mean/rsqrt per (b,h) ----------------
__global__ __launch_bounds__(64) void gn_combine(
    const float2* __restrict__ partials, float2* __restrict__ mv)
{
  int bh = blockIdx.x;
  int m = threadIdx.x;
  float s = 0.f, ss = 0.f;
  if (m < 16) {
    float2 p = partials[(bh & 7) * 128 + m * 8 + (bh >> 3)];
    s = p.x; ss = p.y;
  }
#pragma unroll
  for (int o = 1; o < 16; o <<= 1) { s += __shfl_xor(s, o); ss += __shfl_xor(ss, o); }
  if (m == 0) {
    float mean = s / 65536.f;
    float var = ss / 65536.f - mean * mean;
    mv[bh] = make_float2(mean, rsqrtf(var + 1e-5f));
  }
}

__global__ __launch_bounds__(256) void gn_apply(
    const float* __restrict__ ctx, const float2* __restrict__ mv,
    const float* __restrict__ gw, const float* __restrict__ gb,
    u16* __restrict__ normed)
{
  unsigned idx = blockIdx.x * 256u + threadIdx.x;
  unsigned i = idx * 4;
  unsigned d = i & 1023u;
  unsigned srow = i >> 10;
  unsigned b = srow >> 10;
  unsigned h = d >> 6, dh = d & 63u;
  float2 m = mv[b * 16 + h];
  float4 x = *(const float4*)&ctx[(((size_t)(b * 16 + h)) * 1024 + (srow & 1023u)) * 64 + dh];
  float4 g = *(const float4*)&gw[d];
  float4 be = *(const float4*)&gb[d];
  union { u16 hh[4]; uint2 u2; } p;
  p.hh[0] = f2b(((x.x - m.x) * m.y * g.x + be.x) * 0.8f);
  p.hh[1] = f2b(((x.y - m.x) * m.y * g.y + be.y) * 0.8f);
  p.hh[2] = f2b(((x.z - m.x) * m.y * g.z + be.z) * 0.8f);
  p.hh[3] = f2b(((x.w - m.x) * m.y * g.w + be.w) * 0.8f);
  *(uint2*)(normed + i) = p.u2;
}

// ---------------- launch ----------------
extern "C" void kernel_launch(void* const* d_in, const int* in_sizes, int n_in,
                              void* d_out, int out_size, void* d_ws, size_t ws_size,
                              hipStream_t stream) {
  (void)in_sizes; (void)n_in; (void)out_size; (void)ws_size;
  const float* x   = (const float*)d_in[0];
  const float* aff = (const float*)d_in[1];
  const float* Wq  = (const float*)d_in[2];
  const float* bq  = (const float*)d_in[3];
  const float* Wk  = (const float*)d_in[4];
  const float* bk  = (const float*)d_in[5];
  const float* Wv  = (const float*)d_in[6];
  const float* bv  = (const float*)d_in[7];
  const float* Wo  = (const float*)d_in[8];
  const float* bo  = (const float*)d_in[9];
  const float* gw  = (const float*)d_in[10];
  const float* gb  = (const float*)d_in[11];
  const float* lam = (const float*)d_in[12];
  float* out = (float*)d_out;

  char* w = (char*)d_ws;
  u16*    xb    = (u16*)(w);
  u16*    Wcat  = (u16*)(w + 8388608);
  u16*    Wob   = (u16*)(w + 18874368);
  float*  bcat  = (float*)(w + 20971520);
  u16*    q1t   = (u16*)(w + 20992000);
  u16*    q2t   = (u16*)(w + 29380608);
  u16*    k1t   = (u16*)(w + 37769216);
  u16*    k2t   = (u16*)(w + 46157824);
  u16*    vtT   = (u16*)(w + 54546432);   // [bh][dh][s] transposed
  float*  logL  = (float*)(w + 62935040);
  float*  ctab  = (float*)(w + 62951424);
  float*  stab  = (float*)(w + 63082496);
  float2* parts = (float2*)(w + 63213568); // 1024 float2 (gap before ctx)
  float*  ctx   = (float*)(w + 63475712);
  float2* mv    = (float2*)(w + 80252928);
  u16*    normed= (u16*)(w + 80253440);

  convert_kernel<<<10245, 256, 0, stream>>>(x, Wq, Wk, Wv, Wo, bq, bk, bv, xb, Wcat, Wob, bcat);
  prep_kernel<<<36, 1024, 0, stream>>>(aff, logL, ctab, stab);
  gemm_nt<0><<<dim3(40, 32), 256, 0, stream>>>(xb, Wcat, bcat, nullptr, q1t, q2t, k1t, k2t, vtT, ctab, stab, 5120);
  attn_fused<<<1024, 256, 0, stream>>>(q1t, q2t, k1t, k2t, vtT, logL, lam, ctx, parts);
  gn_combine<<<64, 64, 0, stream>>>(parts, mv);
  gn_apply<<<4096, 256, 0, stream>>>(ctx, mv, gw, gb, normed);
  gemm_nt<1><<<dim3(8, 32), 256, 0, stream>>>(normed, Wob, bo, out, nullptr, nullptr, nullptr, nullptr, nullptr, ctab, stab, 1024);
}

// Round 15
// 189.616 us; speedup vs baseline: 1.1850x; 1.0484x over previous
//
#include <hip/hip_runtime.h>
#include <math.h>

typedef float  f32x4  __attribute__((ext_vector_type(4)));
typedef short  bf16x8 __attribute__((ext_vector_type(8)));
typedef unsigned short u16;

__device__ __forceinline__ u16 f2b(float f) {
  union { float f; unsigned u; } v; v.f = f;
  unsigned r = v.u + 0x7FFFu + ((v.u >> 16) & 1u);
  return (u16)(r >> 16);
}
__device__ __forceinline__ float b2f(u16 h) {
  union { unsigned u; float f; } v; v.u = ((unsigned)h) << 16;
  return v.f;
}

// async global->LDS, 16B per lane; dest = wave-uniform base + lane*16
__device__ __forceinline__ void gl_lds16(const u16* g, u16* l) {
  __builtin_amdgcn_global_load_lds(
      (const __attribute__((address_space(1))) unsigned*)g,
      (__attribute__((address_space(3))) unsigned*)l, 16, 0, 0);
}

// ---------------- fp32 -> bf16 conversion / packing ----------------
__global__ __launch_bounds__(256) void convert_kernel(
    const float* __restrict__ x,  const float* __restrict__ Wq,
    const float* __restrict__ Wk, const float* __restrict__ Wv,
    const float* __restrict__ Wo, const float* __restrict__ bq,
    const float* __restrict__ bk, const float* __restrict__ bv,
    u16* __restrict__ xb, u16* __restrict__ Wcat, u16* __restrict__ Wob,
    float* __restrict__ bcat)
{
  long i = ((long)blockIdx.x * 256 + threadIdx.x) * 4;
  if (i < 10485760L) {
    const float* src; u16* dst; long o;
    if (i < 4194304L)      { src = x;  dst = xb;             o = i; }
    else if (i < 6291456L) { src = Wq; dst = Wcat;           o = i - 4194304L; }
    else if (i < 8388608L) { src = Wk; dst = Wcat + 2097152; o = i - 6291456L; }
    else if (i < 9437184L) { src = Wv; dst = Wcat + 4194304; o = i - 8388608L; }
    else                   { src = Wo; dst = Wob;            o = i - 9437184L; }
    float4 v = *(const float4*)(src + o);
    union { u16 h[4]; uint2 u2; } p;
    p.h[0] = f2b(v.x); p.h[1] = f2b(v.y); p.h[2] = f2b(v.z); p.h[3] = f2b(v.w);
    *(uint2*)(dst + o) = p.u2;
  } else if (i < 10490880L) {
    long j = i - 10485760L;
    const float* src; long o;
    if (j < 2048)      { src = bq; o = j; }
    else if (j < 4096) { src = bk; o = j - 2048; }
    else               { src = bv; o = j - 4096; }
    *(float4*)(bcat + j) = *(const float4*)(src + o);
  }
}

// ---------------- prep: logL scan (blocks 0-3) + RoPE table (blocks 4-35) ----------------
__global__ __launch_bounds__(1024) void prep_kernel(
    const float* __restrict__ a, float* __restrict__ logL,
    float* __restrict__ ctab, float* __restrict__ stab)
{
  if (blockIdx.x < 4) {
    __shared__ float sh[1024];
    int b = blockIdx.x, t = threadIdx.x;
    float v = (t == 0) ? 0.f : log2f(a[b * 1023 + t - 1]);
    sh[t] = v;
    __syncthreads();
    for (int off = 1; off < 1024; off <<= 1) {
      float add = (t >= off) ? sh[t - off] : 0.f;
      __syncthreads();
      sh[t] += add;
      __syncthreads();
    }
    logL[b * 1024 + t] = sh[t];
  } else {
    int idx = (blockIdx.x - 4) * 1024 + threadIdx.x;   // 0..32767
    int s = idx >> 5, i = idx & 31;
    float freq = expf(-(float)i * (9.210340371976184f / 32.f));  // 10000^(-i/32)
    float ang = (float)s * freq;
    ctab[idx] = cosf(ang);
    stab[idx] = sinf(ang);
  }
}

// ---------------- MFMA NT GEMM v2: BK=64, XOR-swizzled LDS (T2, rule #21) ----
// LDS dest linear (gl_lds requirement); global SOURCE block pre-swizzled
// (srcblk = blk ^ (row&7)); reads apply same XOR -> 2-way banks (free, m136).
// Barrier pairs: K/64 = 16 (was 32).
template<int EPI>
__global__ __launch_bounds__(256) void gemm_nt(
    const u16* __restrict__ A, const u16* __restrict__ Bw,
    const float* __restrict__ bias, float* __restrict__ outF,
    u16* __restrict__ q1t, u16* __restrict__ q2t,
    u16* __restrict__ k1t, u16* __restrict__ k2t, u16* __restrict__ vtT,
    const float* __restrict__ ctab, const float* __restrict__ stab,
    int N)
{
  const int K = 1024;
  __shared__ u16 As[128 * 64];   // 16KB, rows of 128B, 8 16B-blocks/row
  __shared__ u16 Bs[128 * 64];
  int tid  = threadIdx.x;
  int lane = tid & 63, wave = tid >> 6;
  int wm = wave >> 1, wn = wave & 1;
  int m0 = blockIdx.y * 128, n0 = blockIdx.x * 128;
  int fr = lane & 15, hi = lane >> 4;

  // staging: 1024 chunks (16B) per matrix; wave w phase p covers chunks
  // [p*256+w*64, +64). LDS linear; global col-block = (c&7) ^ ((c>>3)&7).
  int ac_r[4], ac_sb[4], cb_[4];
#pragma unroll
  for (int p = 0; p < 4; ++p) {
    int c = p * 256 + wave * 64 + lane;
    ac_r[p]  = c >> 3;
    ac_sb[p] = (c & 7) ^ (ac_r[p] & 7);
    cb_[p]   = (p * 256 + wave * 64) * 8;   // wave-uniform LDS u16 index
  }

  f32x4 acc[4][4];
#pragma unroll
  for (int i = 0; i < 4; ++i)
#pragma unroll
    for (int j = 0; j < 4; ++j) acc[i][j] = 0.0f;

  for (int kk0 = 0; kk0 < K; kk0 += 64) {
    __syncthreads();
#pragma unroll
    for (int p = 0; p < 4; ++p) {
      gl_lds16(A  + (size_t)(m0 + ac_r[p]) * K + kk0 + ac_sb[p] * 8, &As[cb_[p]]);
      gl_lds16(Bw + (size_t)(n0 + ac_r[p]) * K + kk0 + ac_sb[p] * 8, &Bs[cb_[p]]);
    }
    __syncthreads();
#pragma unroll
    for (int ks = 0; ks < 2; ++ks) {
      bf16x8 af[4], bfv[4];
#pragma unroll
      for (int f = 0; f < 4; ++f) {
        int ra = wm * 64 + f * 16 + fr;
        int rb = wn * 64 + f * 16 + fr;
        int cba = (ks * 4 + hi) ^ (ra & 7);
        int cbb = (ks * 4 + hi) ^ (rb & 7);
        af[f]  = *(const bf16x8*)&As[ra * 64 + (cba << 3)];
        bfv[f] = *(const bf16x8*)&Bs[rb * 64 + (cbb << 3)];
      }
#pragma unroll
      for (int i = 0; i < 4; ++i)
#pragma unroll
        for (int j = 0; j < 4; ++j)
          acc[i][j] = __builtin_amdgcn_mfma_f32_16x16x32_bf16(af[i], bfv[j], acc[i][j], 0, 0, 0);
    }
  }

  int rg = lane >> 4;
  if (EPI == 0) {
    if (n0 < 4096) {
      u16* dst; int base;
      if (n0 < 1024)      { dst = q1t; base = 0; }
      else if (n0 < 2048) { dst = q2t; base = 1024; }
      else if (n0 < 3072) { dst = k1t; base = 2048; }
      else                { dst = k2t; base = 3072; }
      float qs = (n0 < 2048) ? 0.18033688011112042f : 1.0f;   // 0.125*log2e
#pragma unroll
      for (int i = 0; i < 4; ++i) {
#pragma unroll
        for (int e = 0; e < 4; ++e) {
          int m = m0 + wm * 64 + i * 16 + rg * 4 + e;
          int b = m >> 10, s = m & 1023;
#pragma unroll
          for (int j = 0; j < 2; ++j) {
            int n_lo = n0 + wn * 64 + j * 16 + fr;
            int feat = n_lo - base;
            int h = feat >> 6, dh = feat & 63;   // dh < 32
            float a1 = acc[i][j][e]     + bias[n_lo];
            float a2 = acc[i][j + 2][e] + bias[n_lo + 32];
            float cs = ctab[s * 32 + dh], sn = stab[s * 32 + dh];
            size_t rowb = ((size_t)(b * 16 + h) * 1024 + s) * 64;
            dst[rowb + dh]      = f2b((a1 * cs - a2 * sn) * qs);
            dst[rowb + dh + 32] = f2b((a1 * sn + a2 * cs) * qs);
          }
        }
      }
    } else {
      // v tensor: TRANSPOSED store [bh][dh][s]
#pragma unroll
      for (int i = 0; i < 4; ++i) {
        int mbase = m0 + wm * 64 + i * 16 + rg * 4;
        int b = mbase >> 10, s0 = mbase & 1023;
#pragma unroll
        for (int j = 0; j < 4; ++j) {
          int n = n0 + wn * 64 + j * 16 + fr;
          int feat = n - 4096;
          int h = feat >> 6, dh = feat & 63;
          float bv = bias[n];
          union { u16 hh[4]; uint2 u2; } p;
#pragma unroll
          for (int e = 0; e < 4; ++e) p.hh[e] = f2b(acc[i][j][e] + bv);
          *(uint2*)&vtT[((size_t)(b * 16 + h) * 64 + dh) * 1024 + s0] = p.u2;
        }
      }
    }
  } else {
#pragma unroll
    for (int i = 0; i < 4; ++i)
#pragma unroll
      for (int j = 0; j < 4; ++j)
#pragma unroll
        for (int e = 0; e < 4; ++e) {
          int m = m0 + wm * 64 + i * 16 + rg * 4 + e;
          int n = n0 + wn * 64 + j * 16 + fr;
          outF[(size_t)m * N + n] = acc[i][j][e] + bias[n];
        }
  }
}

// ---------------- fused MFMA attention v9 (unchanged from r14, 88.8us) ----------------
__global__ __launch_bounds__(256) void attn_fused(
    const u16* __restrict__ q1t, const u16* __restrict__ q2t,
    const u16* __restrict__ k1t, const u16* __restrict__ k2t,
    const u16* __restrict__ vtT,
    const float* __restrict__ logL, const float* __restrict__ lamp,
    float* __restrict__ ctx, float2* __restrict__ partials)
{
  __shared__ u16 K1s[64][72];   // K1 during QK^T, P1 during PV
  __shared__ u16 K2s[64][72];   // K2 during QK^T, P2 during PV
  __shared__ u16 Vts[64][72];   // V^T [dh][k], k-blocks XOR-swizzled by (dh>>3)&7
  __shared__ float lred1[2][2][32];
  __shared__ float lred2[2][2][32];
  __shared__ float pred[4][2];

  int tid  = threadIdx.x;
  int lane = tid & 63, wave = tid >> 6;
  int wm = wave >> 1, wn = wave & 1;
  int id = blockIdx.x;
  int bh = (id & 7) * 8 + (id >> 7);        // XCD-grouped: 8 bh per XCD (L2-fit)
  int q0 = ((id >> 3) & 15) * 64;
  int b = bh >> 4;
  int fr = lane & 15, hi = lane >> 4;

  bf16x8 qf1[2][2], qf2[2][2];
#pragma unroll
  for (int i = 0; i < 2; ++i)
#pragma unroll
    for (int ks = 0; ks < 2; ++ks) {
      size_t off = ((size_t)bh * 1024 + q0 + wm * 32 + i * 16 + fr) * 64 + ks * 32 + hi * 8;
      qf1[i][ks] = *(const bf16x8*)(q1t + off);
      qf2[i][ks] = *(const bf16x8*)(q2t + off);
    }
  float Lq[2][4];
#pragma unroll
  for (int i = 0; i < 2; ++i)
#pragma unroll
    for (int r = 0; r < 4; ++r)
      Lq[i][r] = logL[b * 1024 + q0 + wm * 32 + i * 16 + hi * 4 + r];

  float lacc1[2][4], lacc2[2][4];
  f32x4 U1[2][2], U2[2][2];
#pragma unroll
  for (int i = 0; i < 2; ++i)
#pragma unroll
    for (int r = 0; r < 4; ++r) { lacc1[i][r] = 0.f; lacc2[i][r] = 0.f; }
#pragma unroll
  for (int i = 0; i < 2; ++i)
#pragma unroll
    for (int j = 0; j < 2; ++j) { U1[i][j] = 0.f; U2[i][j] = 0.f; }

  int sr = tid >> 2, sc0 = (tid & 3) * 16;
  int swz = (sr >> 3) & 7;
  int blk0 = ((sc0 >> 3) ^ swz) << 3;
  int blk1 = (((sc0 >> 3) + 1) ^ swz) << 3;

  unsigned a1base = (unsigned)(size_t)&K1s[wm * 32 + hi * 4][wn * 32 + fr];
  unsigned a2base = (unsigned)(size_t)&K2s[wm * 32 + hi * 4][wn * 32 + fr];

  for (int kt = 0; kt < 16; ++kt) {
    __syncthreads();   // (1) prev PV reads done
    size_t gb = ((size_t)bh * 1024 + kt * 64 + sr) * 64 + sc0;
    size_t gv = (size_t)bh * 65536 + (size_t)sr * 1024 + kt * 64 + sc0;
    bf16x8 a0 = *(const bf16x8*)(k1t + gb), a1 = *(const bf16x8*)(k1t + gb + 8);
    bf16x8 b0 = *(const bf16x8*)(k2t + gb), b1 = *(const bf16x8*)(k2t + gb + 8);
    bf16x8 v0 = *(const bf16x8*)(vtT + gv), v1 = *(const bf16x8*)(vtT + gv + 8);
    *(bf16x8*)&K1s[sr][sc0]     = a0;  *(bf16x8*)&K1s[sr][sc0 + 8] = a1;
    *(bf16x8*)&K2s[sr][sc0]     = b0;  *(bf16x8*)&K2s[sr][sc0 + 8] = b1;
    *(bf16x8*)&Vts[sr][blk0]    = v0;  *(bf16x8*)&Vts[sr][blk1]    = v1;
    float Ltl[2];
#pragma unroll
    for (int j = 0; j < 2; ++j) Ltl[j] = logL[b * 1024 + kt * 64 + wn * 32 + j * 16 + fr];
    __syncthreads();   // (2) stage complete

    // ---- QK^T ----
    f32x4 S1[2][2], S2[2][2];
#pragma unroll
    for (int i = 0; i < 2; ++i)
#pragma unroll
      for (int j = 0; j < 2; ++j) { S1[i][j] = 0.f; S2[i][j] = 0.f; }
    __builtin_amdgcn_s_setprio(1);
#pragma unroll
    for (int ks = 0; ks < 2; ++ks) {
      bf16x8 kf1[2], kf2[2];
#pragma unroll
      for (int j = 0; j < 2; ++j) {
        kf1[j] = *(const bf16x8*)&K1s[wn * 32 + j * 16 + fr][ks * 32 + hi * 8];
        kf2[j] = *(const bf16x8*)&K2s[wn * 32 + j * 16 + fr][ks * 32 + hi * 8];
      }
#pragma unroll
      for (int i = 0; i < 2; ++i)
#pragma unroll
        for (int j = 0; j < 2; ++j) {
          S1[i][j] = __builtin_amdgcn_mfma_f32_16x16x32_bf16(qf1[i][ks], kf1[j], S1[i][j], 0, 0, 0);
          S2[i][j] = __builtin_amdgcn_mfma_f32_16x16x32_bf16(qf2[i][ks], kf2[j], S2[i][j], 0, 0, 0);
        }
    }
    __builtin_amdgcn_s_setprio(0);
    __syncthreads();   // (3) all K reads done -> K-space reusable as P

    // ---- exponentials (log2 domain) + packed P write ----
#pragma unroll
    for (int i = 0; i < 2; ++i) {
#pragma unroll
      for (int r = 0; r < 4; ++r) {
        float lq = Lq[i][r];
        float e1j[2], e2j[2], p1j[2], p2j[2];
#pragma unroll
        for (int j = 0; j < 2; ++j) {
          float nd = -fabsf(Ltl[j] - lq);
          float t1, t2, ec;
          asm("v_exp_f32 %0, %1" : "=v"(t1) : "v"(S1[i][j][r]));
          asm("v_exp_f32 %0, %1" : "=v"(t2) : "v"(S2[i][j][r]));
          asm("v_exp_f32 %0, %1" : "=v"(ec) : "v"(nd));
          e1j[j] = t1; e2j[j] = t2;
          p1j[j] = t1 * ec; p2j[j] = t2 * ec;
        }
        lacc1[i][r] += e1j[0] + e1j[1];
        lacc2[i][r] += e2j[0] + e2j[1];
        unsigned off = (unsigned)((i * 16 + r) * 144);
        unsigned ad1 = a1base + off, ad2 = a2base + off;
        unsigned pk1, pk2;
        asm("v_cvt_pk_bf16_f32 %0, %1, %2" : "=v"(pk1) : "v"(p1j[0]), "v"(p1j[1]));
        asm("v_cvt_pk_bf16_f32 %0, %1, %2" : "=v"(pk2) : "v"(p2j[0]), "v"(p2j[1]));
        asm volatile("ds_write_b16 %0, %1\n\tds_write_b16_d16_hi %0, %1 offset:32"
                     :: "v"(ad1), "v"(pk1) : "memory");
        asm volatile("ds_write_b16 %0, %1\n\tds_write_b16_d16_hi %0, %1 offset:32"
                     :: "v"(ad2), "v"(pk2) : "memory");
      }
    }
    __syncthreads();   // (4) P complete

    // ---- PV: U += P * V (P in K1s/K2s, V^T in Vts) ----
    __builtin_amdgcn_s_setprio(1);
#pragma unroll
    for (int ks = 0; ks < 2; ++ks) {
      bf16x8 pa1[2], pa2[2], vb[2];
#pragma unroll
      for (int i = 0; i < 2; ++i) {
        pa1[i] = *(const bf16x8*)&K1s[wm * 32 + i * 16 + fr][ks * 32 + hi * 8];
        pa2[i] = *(const bf16x8*)&K2s[wm * 32 + i * 16 + fr][ks * 32 + hi * 8];
      }
#pragma unroll
      for (int j = 0; j < 2; ++j) {
        int row = wn * 32 + j * 16 + fr;
        int kbb = (ks * 4 + hi) ^ ((row >> 3) & 7);
        vb[j] = *(const bf16x8*)&Vts[row][kbb << 3];
      }
#pragma unroll
      for (int i = 0; i < 2; ++i)
#pragma unroll
        for (int j = 0; j < 2; ++j) {
          U1[i][j] = __builtin_amdgcn_mfma_f32_16x16x32_bf16(pa1[i], vb[j], U1[i][j], 0, 0, 0);
          U2[i][j] = __builtin_amdgcn_mfma_f32_16x16x32_bf16(pa2[i], vb[j], U2[i][j], 0, 0, 0);
        }
    }
    __builtin_amdgcn_s_setprio(0);
  }

  // ---- denominator: intra-wave reduce over fr, then cross-wave over wn ----
#pragma unroll
  for (int i = 0; i < 2; ++i)
#pragma unroll
    for (int r = 0; r < 4; ++r) {
#pragma unroll
      for (int m = 1; m < 16; m <<= 1) {
        lacc1[i][r] += __shfl_xor(lacc1[i][r], m);
        lacc2[i][r] += __shfl_xor(lacc2[i][r], m);
      }
    }
  if (fr == 0) {
#pragma unroll
    for (int i = 0; i < 2; ++i)
#pragma unroll
      for (int r = 0; r < 4; ++r) {
        int rl = i * 16 + hi * 4 + r;
        lred1[wn][wm][rl] = lacc1[i][r];
        lred2[wn][wm][rl] = lacc2[i][r];
      }
  }
  __syncthreads();
  float lam = lamp[0];

  // ---- epilogue: ctx = U1/l1 - lam*U2/l2, plus block partial Sum/SumSq ----
  float psum = 0.f, psq = 0.f;
#pragma unroll
  for (int i = 0; i < 2; ++i) {
#pragma unroll
    for (int r = 0; r < 4; ++r) {
      int rl = i * 16 + hi * 4 + r;
      float l1 = lred1[0][wm][rl] + lred1[1][wm][rl];
      float l2 = lred2[0][wm][rl] + lred2[1][wm][rl];
      float inv1 = 1.f / l1;
      float inv2 = lam / l2;
      int qg = q0 + wm * 32 + i * 16 + hi * 4 + r;
#pragma unroll
      for (int j = 0; j < 2; ++j) {
        int dh = wn * 32 + j * 16 + fr;
        float o = U1[i][j][r] * inv1 - U2[i][j][r] * inv2;
        ctx[((size_t)bh * 1024 + qg) * 64 + dh] = o;
        psum += o; psq += o * o;
      }
    }
  }
#pragma unroll
  for (int m = 1; m < 64; m <<= 1) {
    psum += __shfl_xor(psum, m);
    psq  += __shfl_xor(psq, m);
  }
  if (lane == 0) { pred[wave][0] = psum; pred[wave][1] = psq; }
  __syncthreads();
  if (tid == 0)
    partials[id] = make_float2(pred[0][0] + pred[1][0] + pred[2][0] + pred[3][0],
                               pred[0][1] + pred[1][1] + pred[2][1] + pred[3][1]);
}

// ---------------- combine partials -> mean/rsqrt per (b,h) ----------------
__global__ __launch_bounds__(64) void gn_combine(
    const float2* __restrict__ partials, float2* __restrict__ mv)
{
  int bh = blockIdx.x;
  int m = threadIdx.x;
  float s = 0.f, ss = 0.f;
  if (m < 16) {
    float2 p = partials[(bh & 7) * 128 + m * 8 + (bh >> 3)];
    s = p.x; ss = p.y;
  }
#pragma unroll
  for (int o = 1; o < 16; o <<= 1) { s += __shfl_xor(s, o); ss += __shfl_xor(ss, o); }
  if (m == 0) {
    float mean = s / 65536.f;
    float var = ss / 65536.f - mean * mean;
    mv[bh] = make_float2(mean, rsqrtf(var + 1e-5f));
  }
}

__global__ __launch_bounds__(256) void gn_apply(
    const float* __restrict__ ctx, const float2* __restrict__ mv,
    const float* __restrict__ gw, const float* __restrict__ gb,
    u16* __restrict__ normed)
{
  unsigned idx = blockIdx.x * 256u + threadIdx.x;
  unsigned i = idx * 4;
  unsigned d = i & 1023u;
  unsigned srow = i >> 10;
  unsigned b = srow >> 10;
  unsigned h = d >> 6, dh = d & 63u;
  float2 m = mv[b * 16 + h];
  float4 x = *(const float4*)&ctx[(((size_t)(b * 16 + h)) * 1024 + (srow & 1023u)) * 64 + dh];
  float4 g = *(const float4*)&gw[d];
  float4 be = *(const float4*)&gb[d];
  union { u16 hh[4]; uint2 u2; } p;
  p.hh[0] = f2b(((x.x - m.x) * m.y * g.x + be.x) * 0.8f);
  p.hh[1] = f2b(((x.y - m.x) * m.y * g.y + be.y) * 0.8f);
  p.hh[2] = f2b(((x.z - m.x) * m.y * g.z + be.z) * 0.8f);
  p.hh[3] = f2b(((x.w - m.x) * m.y * g.w + be.w) * 0.8f);
  *(uint2*)(normed + i) = p.u2;
}

// ---------------- launch ----------------
extern "C" void kernel_launch(void* const* d_in, const int* in_sizes, int n_in,
                              void* d_out, int out_size, void* d_ws, size_t ws_size,
                              hipStream_t stream) {
  (void)in_sizes; (void)n_in; (void)out_size; (void)ws_size;
  const float* x   = (const float*)d_in[0];
  const float* aff = (const float*)d_in[1];
  const float* Wq  = (const float*)d_in[2];
  const float* bq  = (const float*)d_in[3];
  const float* Wk  = (const float*)d_in[4];
  const float* bk  = (const float*)d_in[5];
  const float* Wv  = (const float*)d_in[6];
  const float* bv  = (const float*)d_in[7];
  const float* Wo  = (const float*)d_in[8];
  const float* bo  = (const float*)d_in[9];
  const float* gw  = (const float*)d_in[10];
  const float* gb  = (const float*)d_in[11];
  const float* lam = (const float*)d_in[12];
  float* out = (float*)d_out;

  char* w = (char*)d_ws;
  u16*    xb    = (u16*)(w);
  u16*    Wcat  = (u16*)(w + 8388608);
  u16*    Wob   = (u16*)(w + 18874368);
  float*  bcat  = (float*)(w + 20971520);
  u16*    q1t   = (u16*)(w + 20992000);
  u16*    q2t   = (u16*)(w + 29380608);
  u16*    k1t   = (u16*)(w + 37769216);
  u16*    k2t   = (u16*)(w + 46157824);
  u16*    vtT   = (u16*)(w + 54546432);   // [bh][dh][s] transposed
  float*  logL  = (float*)(w + 62935040);
  float*  ctab  = (float*)(w + 62951424);
  float*  stab  = (float*)(w + 63082496);
  float2* parts = (float2*)(w + 63213568); // 1024 float2 (gap before ctx)
  float*  ctx   = (float*)(w + 63475712);
  float2* mv    = (float2*)(w + 80252928);
  u16*    normed= (u16*)(w + 80253440);

  convert_kernel<<<10245, 256, 0, stream>>>(x, Wq, Wk, Wv, Wo, bq, bk, bv, xb, Wcat, Wob, bcat);
  prep_kernel<<<36, 1024, 0, stream>>>(aff, logL, ctab, stab);
  gemm_nt<0><<<dim3(40, 32), 256, 0, stream>>>(xb, Wcat, bcat, nullptr, q1t, q2t, k1t, k2t, vtT, ctab, stab, 5120);
  attn_fused<<<1024, 256, 0, stream>>>(q1t, q2t, k1t, k2t, vtT, logL, lam, ctx, parts);
  gn_combine<<<64, 64, 0, stream>>>(parts, mv);
  gn_apply<<<4096, 256, 0, stream>>>(ctx, mv, gw, gb, normed);
  gemm_nt<1><<<dim3(8, 32), 256, 0, stream>>>(normed, Wob, bo, out, nullptr, nullptr, nullptr, nullptr, nullptr, ctab, stab, 1024);
}

// Round 16
// 187.156 us; speedup vs baseline: 1.2005x; 1.0131x over previous
//
#include <hip/hip_runtime.h>
#include <math.h>

typedef float  f32x4  __attribute__((ext_vector_type(4)));
typedef short  bf16x8 __attribute__((ext_vector_type(8)));
typedef unsigned short u16;

__device__ __forceinline__ u16 f2b(float f) {
  union { float f; unsigned u; } v; v.f = f;
  unsigned r = v.u + 0x7FFFu + ((v.u >> 16) & 1u);
  return (u16)(r >> 16);
}
__device__ __forceinline__ float b2f(u16 h) {
  union { unsigned u; float f; } v; v.u = ((unsigned)h) << 16;
  return v.f;
}

// async global->LDS, 16B per lane; dest = wave-uniform base + lane*16
__device__ __forceinline__ void gl_lds16(const u16* g, u16* l) {
  __builtin_amdgcn_global_load_lds(
      (const __attribute__((address_space(1))) unsigned*)g,
      (__attribute__((address_space(3))) unsigned*)l, 16, 0, 0);
}

// ---------------- fp32 -> bf16 conversion / packing ----------------
__global__ __launch_bounds__(256) void convert_kernel(
    const float* __restrict__ x,  const float* __restrict__ Wq,
    const float* __restrict__ Wk, const float* __restrict__ Wv,
    const float* __restrict__ Wo, const float* __restrict__ bq,
    const float* __restrict__ bk, const float* __restrict__ bv,
    u16* __restrict__ xb, u16* __restrict__ Wcat, u16* __restrict__ Wob,
    float* __restrict__ bcat)
{
  long i = ((long)blockIdx.x * 256 + threadIdx.x) * 4;
  if (i < 10485760L) {
    const float* src; u16* dst; long o;
    if (i < 4194304L)      { src = x;  dst = xb;             o = i; }
    else if (i < 6291456L) { src = Wq; dst = Wcat;           o = i - 4194304L; }
    else if (i < 8388608L) { src = Wk; dst = Wcat + 2097152; o = i - 6291456L; }
    else if (i < 9437184L) { src = Wv; dst = Wcat + 4194304; o = i - 8388608L; }
    else                   { src = Wo; dst = Wob;            o = i - 9437184L; }
    float4 v = *(const float4*)(src + o);
    union { u16 h[4]; uint2 u2; } p;
    p.h[0] = f2b(v.x); p.h[1] = f2b(v.y); p.h[2] = f2b(v.z); p.h[3] = f2b(v.w);
    *(uint2*)(dst + o) = p.u2;
  } else if (i < 10490880L) {
    long j = i - 10485760L;
    const float* src; long o;
    if (j < 2048)      { src = bq; o = j; }
    else if (j < 4096) { src = bk; o = j - 2048; }
    else               { src = bv; o = j - 4096; }
    *(float4*)(bcat + j) = *(const float4*)(src + o);
  }
}

// ---------------- prep: logL scan (blocks 0-3) + RoPE table (blocks 4-35) ----------------
__global__ __launch_bounds__(1024) void prep_kernel(
    const float* __restrict__ a, float* __restrict__ logL,
    float* __restrict__ ctab, float* __restrict__ stab)
{
  if (blockIdx.x < 4) {
    __shared__ float sh[1024];
    int b = blockIdx.x, t = threadIdx.x;
    float v = (t == 0) ? 0.f : log2f(a[b * 1023 + t - 1]);
    sh[t] = v;
    __syncthreads();
    for (int off = 1; off < 1024; off <<= 1) {
      float add = (t >= off) ? sh[t - off] : 0.f;
      __syncthreads();
      sh[t] += add;
      __syncthreads();
    }
    logL[b * 1024 + t] = sh[t];
  } else {
    int idx = (blockIdx.x - 4) * 1024 + threadIdx.x;   // 0..32767
    int s = idx >> 5, i = idx & 31;
    float freq = expf(-(float)i * (9.210340371976184f / 32.f));  // 10000^(-i/32)
    float ang = (float)s * freq;
    ctab[idx] = cosf(ang);
    stab[idx] = sinf(ang);
  }
}

// ---------------- MFMA NT GEMM v2: BK=64, XOR-swizzled LDS (unchanged r15) ----
template<int EPI>
__global__ __launch_bounds__(256) void gemm_nt(
    const u16* __restrict__ A, const u16* __restrict__ Bw,
    const float* __restrict__ bias, float* __restrict__ outF,
    u16* __restrict__ q1t, u16* __restrict__ q2t,
    u16* __restrict__ k1t, u16* __restrict__ k2t, u16* __restrict__ vtT,
    const float* __restrict__ ctab, const float* __restrict__ stab,
    int N)
{
  const int K = 1024;
  __shared__ u16 As[128 * 64];
  __shared__ u16 Bs[128 * 64];
  int tid  = threadIdx.x;
  int lane = tid & 63, wave = tid >> 6;
  int wm = wave >> 1, wn = wave & 1;
  int m0 = blockIdx.y * 128, n0 = blockIdx.x * 128;
  int fr = lane & 15, hi = lane >> 4;

  int ac_r[4], ac_sb[4], cb_[4];
#pragma unroll
  for (int p = 0; p < 4; ++p) {
    int c = p * 256 + wave * 64 + lane;
    ac_r[p]  = c >> 3;
    ac_sb[p] = (c & 7) ^ (ac_r[p] & 7);
    cb_[p]   = (p * 256 + wave * 64) * 8;
  }

  f32x4 acc[4][4];
#pragma unroll
  for (int i = 0; i < 4; ++i)
#pragma unroll
    for (int j = 0; j < 4; ++j) acc[i][j] = 0.0f;

  for (int kk0 = 0; kk0 < K; kk0 += 64) {
    __syncthreads();
#pragma unroll
    for (int p = 0; p < 4; ++p) {
      gl_lds16(A  + (size_t)(m0 + ac_r[p]) * K + kk0 + ac_sb[p] * 8, &As[cb_[p]]);
      gl_lds16(Bw + (size_t)(n0 + ac_r[p]) * K + kk0 + ac_sb[p] * 8, &Bs[cb_[p]]);
    }
    __syncthreads();
#pragma unroll
    for (int ks = 0; ks < 2; ++ks) {
      bf16x8 af[4], bfv[4];
#pragma unroll
      for (int f = 0; f < 4; ++f) {
        int ra = wm * 64 + f * 16 + fr;
        int rb = wn * 64 + f * 16 + fr;
        int cba = (ks * 4 + hi) ^ (ra & 7);
        int cbb = (ks * 4 + hi) ^ (rb & 7);
        af[f]  = *(const bf16x8*)&As[ra * 64 + (cba << 3)];
        bfv[f] = *(const bf16x8*)&Bs[rb * 64 + (cbb << 3)];
      }
#pragma unroll
      for (int i = 0; i < 4; ++i)
#pragma unroll
        for (int j = 0; j < 4; ++j)
          acc[i][j] = __builtin_amdgcn_mfma_f32_16x16x32_bf16(af[i], bfv[j], acc[i][j], 0, 0, 0);
    }
  }

  int rg = lane >> 4;
  if (EPI == 0) {
    if (n0 < 4096) {
      u16* dst; int base;
      if (n0 < 1024)      { dst = q1t; base = 0; }
      else if (n0 < 2048) { dst = q2t; base = 1024; }
      else if (n0 < 3072) { dst = k1t; base = 2048; }
      else                { dst = k2t; base = 3072; }
      float qs = (n0 < 2048) ? 0.18033688011112042f : 1.0f;   // 0.125*log2e
#pragma unroll
      for (int i = 0; i < 4; ++i) {
#pragma unroll
        for (int e = 0; e < 4; ++e) {
          int m = m0 + wm * 64 + i * 16 + rg * 4 + e;
          int b = m >> 10, s = m & 1023;
#pragma unroll
          for (int j = 0; j < 2; ++j) {
            int n_lo = n0 + wn * 64 + j * 16 + fr;
            int feat = n_lo - base;
            int h = feat >> 6, dh = feat & 63;   // dh < 32
            float a1 = acc[i][j][e]     + bias[n_lo];
            float a2 = acc[i][j + 2][e] + bias[n_lo + 32];
            float cs = ctab[s * 32 + dh], sn = stab[s * 32 + dh];
            size_t rowb = ((size_t)(b * 16 + h) * 1024 + s) * 64;
            dst[rowb + dh]      = f2b((a1 * cs - a2 * sn) * qs);
            dst[rowb + dh + 32] = f2b((a1 * sn + a2 * cs) * qs);
          }
        }
      }
    } else {
      // v tensor: TRANSPOSED store [bh][dh][s]
#pragma unroll
      for (int i = 0; i < 4; ++i) {
        int mbase = m0 + wm * 64 + i * 16 + rg * 4;
        int b = mbase >> 10, s0 = mbase & 1023;
#pragma unroll
        for (int j = 0; j < 4; ++j) {
          int n = n0 + wn * 64 + j * 16 + fr;
          int feat = n - 4096;
          int h = feat >> 6, dh = feat & 63;
          float bv = bias[n];
          union { u16 hh[4]; uint2 u2; } p;
#pragma unroll
          for (int e = 0; e < 4; ++e) p.hh[e] = f2b(acc[i][j][e] + bv);
          *(uint2*)&vtT[((size_t)(b * 16 + h) * 64 + dh) * 1024 + s0] = p.u2;
        }
      }
    }
  } else {
#pragma unroll
    for (int i = 0; i < 4; ++i)
#pragma unroll
      for (int j = 0; j < 4; ++j)
#pragma unroll
        for (int e = 0; e < 4; ++e) {
          int m = m0 + wm * 64 + i * 16 + rg * 4 + e;
          int n = n0 + wn * 64 + j * 16 + fr;
          outF[(size_t)m * N + n] = acc[i][j][e] + bias[n];
        }
  }
}

// ---------------- fused MFMA attention v10 ----------------
// = r14 structure; ONE change: ctx stored bf16 (halves GN re-read + attn write;
// partials still accumulated from exact f32 values pre-rounding).
__global__ __launch_bounds__(256) void attn_fused(
    const u16* __restrict__ q1t, const u16* __restrict__ q2t,
    const u16* __restrict__ k1t, const u16* __restrict__ k2t,
    const u16* __restrict__ vtT,
    const float* __restrict__ logL, const float* __restrict__ lamp,
    u16* __restrict__ ctxb, float2* __restrict__ partials)
{
  __shared__ u16 K1s[64][72];   // K1 during QK^T, P1 during PV
  __shared__ u16 K2s[64][72];   // K2 during QK^T, P2 during PV
  __shared__ u16 Vts[64][72];   // V^T [dh][k], k-blocks XOR-swizzled by (dh>>3)&7
  __shared__ float lred1[2][2][32];
  __shared__ float lred2[2][2][32];
  __shared__ float pred[4][2];

  int tid  = threadIdx.x;
  int lane = tid & 63, wave = tid >> 6;
  int wm = wave >> 1, wn = wave & 1;
  int id = blockIdx.x;
  int bh = (id & 7) * 8 + (id >> 7);        // XCD-grouped: 8 bh per XCD (L2-fit)
  int q0 = ((id >> 3) & 15) * 64;
  int b = bh >> 4;
  int fr = lane & 15, hi = lane >> 4;

  bf16x8 qf1[2][2], qf2[2][2];
#pragma unroll
  for (int i = 0; i < 2; ++i)
#pragma unroll
    for (int ks = 0; ks < 2; ++ks) {
      size_t off = ((size_t)bh * 1024 + q0 + wm * 32 + i * 16 + fr) * 64 + ks * 32 + hi * 8;
      qf1[i][ks] = *(const bf16x8*)(q1t + off);
      qf2[i][ks] = *(const bf16x8*)(q2t + off);
    }
  float Lq[2][4];
#pragma unroll
  for (int i = 0; i < 2; ++i)
#pragma unroll
    for (int r = 0; r < 4; ++r)
      Lq[i][r] = logL[b * 1024 + q0 + wm * 32 + i * 16 + hi * 4 + r];

  float lacc1[2][4], lacc2[2][4];
  f32x4 U1[2][2], U2[2][2];
#pragma unroll
  for (int i = 0; i < 2; ++i)
#pragma unroll
    for (int r = 0; r < 4; ++r) { lacc1[i][r] = 0.f; lacc2[i][r] = 0.f; }
#pragma unroll
  for (int i = 0; i < 2; ++i)
#pragma unroll
    for (int j = 0; j < 2; ++j) { U1[i][j] = 0.f; U2[i][j] = 0.f; }

  int sr = tid >> 2, sc0 = (tid & 3) * 16;
  int swz = (sr >> 3) & 7;
  int blk0 = ((sc0 >> 3) ^ swz) << 3;
  int blk1 = (((sc0 >> 3) + 1) ^ swz) << 3;

  unsigned a1base = (unsigned)(size_t)&K1s[wm * 32 + hi * 4][wn * 32 + fr];
  unsigned a2base = (unsigned)(size_t)&K2s[wm * 32 + hi * 4][wn * 32 + fr];

  for (int kt = 0; kt < 16; ++kt) {
    __syncthreads();   // (1) prev PV reads done
    size_t gb = ((size_t)bh * 1024 + kt * 64 + sr) * 64 + sc0;
    size_t gv = (size_t)bh * 65536 + (size_t)sr * 1024 + kt * 64 + sc0;
    bf16x8 a0 = *(const bf16x8*)(k1t + gb), a1 = *(const bf16x8*)(k1t + gb + 8);
    bf16x8 b0 = *(const bf16x8*)(k2t + gb), b1 = *(const bf16x8*)(k2t + gb + 8);
    bf16x8 v0 = *(const bf16x8*)(vtT + gv), v1 = *(const bf16x8*)(vtT + gv + 8);
    *(bf16x8*)&K1s[sr][sc0]     = a0;  *(bf16x8*)&K1s[sr][sc0 + 8] = a1;
    *(bf16x8*)&K2s[sr][sc0]     = b0;  *(bf16x8*)&K2s[sr][sc0 + 8] = b1;
    *(bf16x8*)&Vts[sr][blk0]    = v0;  *(bf16x8*)&Vts[sr][blk1]    = v1;
    float Ltl[2];
#pragma unroll
    for (int j = 0; j < 2; ++j) Ltl[j] = logL[b * 1024 + kt * 64 + wn * 32 + j * 16 + fr];
    __syncthreads();   // (2) stage complete

    // ---- QK^T ----
    f32x4 S1[2][2], S2[2][2];
#pragma unroll
    for (int i = 0; i < 2; ++i)
#pragma unroll
      for (int j = 0; j < 2; ++j) { S1[i][j] = 0.f; S2[i][j] = 0.f; }
    __builtin_amdgcn_s_setprio(1);
#pragma unroll
    for (int ks = 0; ks < 2; ++ks) {
      bf16x8 kf1[2], kf2[2];
#pragma unroll
      for (int j = 0; j < 2; ++j) {
        kf1[j] = *(const bf16x8*)&K1s[wn * 32 + j * 16 + fr][ks * 32 + hi * 8];
        kf2[j] = *(const bf16x8*)&K2s[wn * 32 + j * 16 + fr][ks * 32 + hi * 8];
      }
#pragma unroll
      for (int i = 0; i < 2; ++i)
#pragma unroll
        for (int j = 0; j < 2; ++j) {
          S1[i][j] = __builtin_amdgcn_mfma_f32_16x16x32_bf16(qf1[i][ks], kf1[j], S1[i][j], 0, 0, 0);
          S2[i][j] = __builtin_amdgcn_mfma_f32_16x16x32_bf16(qf2[i][ks], kf2[j], S2[i][j], 0, 0, 0);
        }
    }
    __builtin_amdgcn_s_setprio(0);
    __syncthreads();   // (3) all K reads done -> K-space reusable as P

    // ---- exponentials (log2 domain) + packed P write ----
#pragma unroll
    for (int i = 0; i < 2; ++i) {
#pragma unroll
      for (int r = 0; r < 4; ++r) {
        float lq = Lq[i][r];
        float e1j[2], e2j[2], p1j[2], p2j[2];
#pragma unroll
        for (int j = 0; j < 2; ++j) {
          float nd = -fabsf(Ltl[j] - lq);
          float t1, t2, ec;
          asm("v_exp_f32 %0, %1" : "=v"(t1) : "v"(S1[i][j][r]));
          asm("v_exp_f32 %0, %1" : "=v"(t2) : "v"(S2[i][j][r]));
          asm("v_exp_f32 %0, %1" : "=v"(ec) : "v"(nd));
          e1j[j] = t1; e2j[j] = t2;
          p1j[j] = t1 * ec; p2j[j] = t2 * ec;
        }
        lacc1[i][r] += e1j[0] + e1j[1];
        lacc2[i][r] += e2j[0] + e2j[1];
        unsigned off = (unsigned)((i * 16 + r) * 144);
        unsigned ad1 = a1base + off, ad2 = a2base + off;
        unsigned pk1, pk2;
        asm("v_cvt_pk_bf16_f32 %0, %1, %2" : "=v"(pk1) : "v"(p1j[0]), "v"(p1j[1]));
        asm("v_cvt_pk_bf16_f32 %0, %1, %2" : "=v"(pk2) : "v"(p2j[0]), "v"(p2j[1]));
        asm volatile("ds_write_b16 %0, %1\n\tds_write_b16_d16_hi %0, %1 offset:32"
                     :: "v"(ad1), "v"(pk1) : "memory");
        asm volatile("ds_write_b16 %0, %1\n\tds_write_b16_d16_hi %0, %1 offset:32"
                     :: "v"(ad2), "v"(pk2) : "memory");
      }
    }
    __syncthreads();   // (4) P complete

    // ---- PV: U += P * V (P in K1s/K2s, V^T in Vts) ----
    __builtin_amdgcn_s_setprio(1);
#pragma unroll
    for (int ks = 0; ks < 2; ++ks) {
      bf16x8 pa1[2], pa2[2], vb[2];
#pragma unroll
      for (int i = 0; i < 2; ++i) {
        pa1[i] = *(const bf16x8*)&K1s[wm * 32 + i * 16 + fr][ks * 32 + hi * 8];
        pa2[i] = *(const bf16x8*)&K2s[wm * 32 + i * 16 + fr][ks * 32 + hi * 8];
      }
#pragma unroll
      for (int j = 0; j < 2; ++j) {
        int row = wn * 32 + j * 16 + fr;
        int kbb = (ks * 4 + hi) ^ ((row >> 3) & 7);
        vb[j] = *(const bf16x8*)&Vts[row][kbb << 3];
      }
#pragma unroll
      for (int i = 0; i < 2; ++i)
#pragma unroll
        for (int j = 0; j < 2; ++j) {
          U1[i][j] = __builtin_amdgcn_mfma_f32_16x16x32_bf16(pa1[i], vb[j], U1[i][j], 0, 0, 0);
          U2[i][j] = __builtin_amdgcn_mfma_f32_16x16x32_bf16(pa2[i], vb[j], U2[i][j], 0, 0, 0);
        }
    }
    __builtin_amdgcn_s_setprio(0);
  }

  // ---- denominator: intra-wave reduce over fr, then cross-wave over wn ----
#pragma unroll
  for (int i = 0; i < 2; ++i)
#pragma unroll
    for (int r = 0; r < 4; ++r) {
#pragma unroll
      for (int m = 1; m < 16; m <<= 1) {
        lacc1[i][r] += __shfl_xor(lacc1[i][r], m);
        lacc2[i][r] += __shfl_xor(lacc2[i][r], m);
      }
    }
  if (fr == 0) {
#pragma unroll
    for (int i = 0; i < 2; ++i)
#pragma unroll
      for (int r = 0; r < 4; ++r) {
        int rl = i * 16 + hi * 4 + r;
        lred1[wn][wm][rl] = lacc1[i][r];
        lred2[wn][wm][rl] = lacc2[i][r];
      }
  }
  __syncthreads();
  float lam = lamp[0];

  // ---- epilogue: ctx(bf16) = U1/l1 - lam*U2/l2, plus block partial Sum/SumSq ----
  float psum = 0.f, psq = 0.f;
#pragma unroll
  for (int i = 0; i < 2; ++i) {
#pragma unroll
    for (int r = 0; r < 4; ++r) {
      int rl = i * 16 + hi * 4 + r;
      float l1 = lred1[0][wm][rl] + lred1[1][wm][rl];
      float l2 = lred2[0][wm][rl] + lred2[1][wm][rl];
      float inv1 = 1.f / l1;
      float inv2 = lam / l2;
      int qg = q0 + wm * 32 + i * 16 + hi * 4 + r;
#pragma unroll
      for (int j = 0; j < 2; ++j) {
        int dh = wn * 32 + j * 16 + fr;
        float o = U1[i][j][r] * inv1 - U2[i][j][r] * inv2;
        ctxb[((size_t)bh * 1024 + qg) * 64 + dh] = f2b(o);
        psum += o; psq += o * o;
      }
    }
  }
#pragma unroll
  for (int m = 1; m < 64; m <<= 1) {
    psum += __shfl_xor(psum, m);
    psq  += __shfl_xor(psq, m);
  }
  if (lane == 0) { pred[wave][0] = psum; pred[wave][1] = psq; }
  __syncthreads();
  if (tid == 0)
    partials[id] = make_float2(pred[0][0] + pred[1][0] + pred[2][0] + pred[3][0],
                               pred[0][1] + pred[1][1] + pred[2][1] + pred[3][1]);
}

// ---------------- gn_apply v2: inline combine (one (b,s) row per block) ----------------
// Thread tid: h = tid>>4, qi = tid&15. Loads partial (bh=b*16+h, qi); 16-lane
// xor-butterfly gives every lane its h's full (Sum,SumSq). Deterministic.
__global__ __launch_bounds__(256) void gn_apply(
    const u16* __restrict__ ctxb, const float2* __restrict__ partials,
    const float* __restrict__ gw, const float* __restrict__ gb,
    u16* __restrict__ normed)
{
  int tid = threadIdx.x;
  int srow = blockIdx.x;            // b*1024 + s
  int b = srow >> 10;
  int h = tid >> 4, qi = tid & 15;
  int bh = b * 16 + h;
  float2 pp = partials[(bh & 7) * 128 + qi * 8 + (bh >> 3)];
  float s = pp.x, ss = pp.y;
#pragma unroll
  for (int o = 1; o < 16; o <<= 1) { s += __shfl_xor(s, o); ss += __shfl_xor(ss, o); }
  float mean = s * (1.f / 65536.f);
  float vinv = rsqrtf(ss * (1.f / 65536.f) - mean * mean + 1e-5f);

  unsigned d  = (unsigned)tid * 4u;     // 0..1020, h == d>>6
  unsigned dh = d & 63u;
  uint2 raw = *(const uint2*)&ctxb[(((size_t)bh) * 1024 + (srow & 1023)) * 64 + dh];
  const u16* rp = (const u16*)&raw;
  float4 g  = *(const float4*)&gw[d];
  float4 be = *(const float4*)&gb[d];
  union { u16 hh[4]; uint2 u2; } p;
  p.hh[0] = f2b(((b2f(rp[0]) - mean) * vinv * g.x + be.x) * 0.8f);
  p.hh[1] = f2b(((b2f(rp[1]) - mean) * vinv * g.y + be.y) * 0.8f);
  p.hh[2] = f2b(((b2f(rp[2]) - mean) * vinv * g.z + be.z) * 0.8f);
  p.hh[3] = f2b(((b2f(rp[3]) - mean) * vinv * g.w + be.w) * 0.8f);
  *(uint2*)&normed[(size_t)srow * 1024 + d] = p.u2;
}

// ---------------- launch ----------------
extern "C" void kernel_launch(void* const* d_in, const int* in_sizes, int n_in,
                              void* d_out, int out_size, void* d_ws, size_t ws_size,
                              hipStream_t stream) {
  (void)in_sizes; (void)n_in; (void)out_size; (void)ws_size;
  const float* x   = (const float*)d_in[0];
  const float* aff = (const float*)d_in[1];
  const float* Wq  = (const float*)d_in[2];
  const float* bq  = (const float*)d_in[3];
  const float* Wk  = (const float*)d_in[4];
  const float* bk  = (const float*)d_in[5];
  const float* Wv  = (const float*)d_in[6];
  const float* bv  = (const float*)d_in[7];
  const float* Wo  = (const float*)d_in[8];
  const float* bo  = (const float*)d_in[9];
  const float* gw  = (const float*)d_in[10];
  const float* gb  = (const float*)d_in[11];
  const float* lam = (const float*)d_in[12];
  float* out = (float*)d_out;

  char* w = (char*)d_ws;
  u16*    xb    = (u16*)(w);
  u16*    Wcat  = (u16*)(w + 8388608);
  u16*    Wob   = (u16*)(w + 18874368);
  float*  bcat  = (float*)(w + 20971520);
  u16*    q1t   = (u16*)(w + 20992000);
  u16*    q2t   = (u16*)(w + 29380608);
  u16*    k1t   = (u16*)(w + 37769216);
  u16*    k2t   = (u16*)(w + 46157824);
  u16*    vtT   = (u16*)(w + 54546432);   // [bh][dh][s] transposed
  float*  logL  = (float*)(w + 62935040);
  float*  ctab  = (float*)(w + 62951424);
  float*  stab  = (float*)(w + 63082496);
  float2* parts = (float2*)(w + 63213568); // 1024 float2
  u16*    ctxb  = (u16*)(w + 63475712);    // bf16 ctx (8.4MB)
  u16*    normed= (u16*)(w + 80253440);

  convert_kernel<<<10245, 256, 0, stream>>>(x, Wq, Wk, Wv, Wo, bq, bk, bv, xb, Wcat, Wob, bcat);
  prep_kernel<<<36, 1024, 0, stream>>>(aff, logL, ctab, stab);
  gemm_nt<0><<<dim3(40, 32), 256, 0, stream>>>(xb, Wcat, bcat, nullptr, q1t, q2t, k1t, k2t, vtT, ctab, stab, 5120);
  attn_fused<<<1024, 256, 0, stream>>>(q1t, q2t, k1t, k2t, vtT, logL, lam, ctxb, parts);
  gn_apply<<<4096, 256, 0, stream>>>(ctxb, parts, gw, gb, normed);
  gemm_nt<1><<<dim3(8, 32), 256, 0, stream>>>(normed, Wob, bo, out, nullptr, nullptr, nullptr, nullptr, nullptr, ctab, stab, 1024);
}

// Round 17
// 167.485 us; speedup vs baseline: 1.3416x; 1.1174x over previous
//
#include <hip/hip_runtime.h>
#include <math.h>

typedef float  f32x4  __attribute__((ext_vector_type(4)));
typedef short  bf16x8 __attribute__((ext_vector_type(8)));
typedef unsigned short u16;

__device__ __forceinline__ u16 f2b(float f) {
  union { float f; unsigned u; } v; v.f = f;
  unsigned r = v.u + 0x7FFFu + ((v.u >> 16) & 1u);
  return (u16)(r >> 16);
}
__device__ __forceinline__ float b2f(u16 h) {
  union { unsigned u; float f; } v; v.u = ((unsigned)h) << 16;
  return v.f;
}

// async global->LDS, 16B per lane; dest = wave-uniform base + lane*16
__device__ __forceinline__ void gl_lds16(const u16* g, u16* l) {
  __builtin_amdgcn_global_load_lds(
      (const __attribute__((address_space(1))) unsigned*)g,
      (__attribute__((address_space(3))) unsigned*)l, 16, 0, 0);
}

// ---------------- fp32 -> bf16 conversion / packing ----------------
__global__ __launch_bounds__(256) void convert_kernel(
    const float* __restrict__ x,  const float* __restrict__ Wq,
    const float* __restrict__ Wk, const float* __restrict__ Wv,
    const float* __restrict__ Wo, const float* __restrict__ bq,
    const float* __restrict__ bk, const float* __restrict__ bv,
    u16* __restrict__ xb, u16* __restrict__ Wcat, u16* __restrict__ Wob,
    float* __restrict__ bcat)
{
  long i = ((long)blockIdx.x * 256 + threadIdx.x) * 4;
  if (i < 10485760L) {
    const float* src; u16* dst; long o;
    if (i < 4194304L)      { src = x;  dst = xb;             o = i; }
    else if (i < 6291456L) { src = Wq; dst = Wcat;           o = i - 4194304L; }
    else if (i < 8388608L) { src = Wk; dst = Wcat + 2097152; o = i - 6291456L; }
    else if (i < 9437184L) { src = Wv; dst = Wcat + 4194304; o = i - 8388608L; }
    else                   { src = Wo; dst = Wob;            o = i - 9437184L; }
    float4 v = *(const float4*)(src + o);
    union { u16 h[4]; uint2 u2; } p;
    p.h[0] = f2b(v.x); p.h[1] = f2b(v.y); p.h[2] = f2b(v.z); p.h[3] = f2b(v.w);
    *(uint2*)(dst + o) = p.u2;
  } else if (i < 10490880L) {
    long j = i - 10485760L;
    const float* src; long o;
    if (j < 2048)      { src = bq; o = j; }
    else if (j < 4096) { src = bk; o = j - 2048; }
    else               { src = bv; o = j - 4096; }
    *(float4*)(bcat + j) = *(const float4*)(src + o);
  }
}

// ---------------- prep: logL scan (blocks 0-3) + RoPE table (blocks 4-35) ----------------
__global__ __launch_bounds__(1024) void prep_kernel(
    const float* __restrict__ a, float* __restrict__ logL,
    float* __restrict__ ctab, float* __restrict__ stab)
{
  if (blockIdx.x < 4) {
    __shared__ float sh[1024];
    int b = blockIdx.x, t = threadIdx.x;
    float v = (t == 0) ? 0.f : log2f(a[b * 1023 + t - 1]);
    sh[t] = v;
    __syncthreads();
    for (int off = 1; off < 1024; off <<= 1) {
      float add = (t >= off) ? sh[t - off] : 0.f;
      __syncthreads();
      sh[t] += add;
      __syncthreads();
    }
    logL[b * 1024 + t] = sh[t];
  } else {
    int idx = (blockIdx.x - 4) * 1024 + threadIdx.x;   // 0..32767
    int s = idx >> 5, i = idx & 31;
    float freq = expf(-(float)i * (9.210340371976184f / 32.f));  // 10000^(-i/32)
    float ang = (float)s * freq;
    ctab[idx] = cosf(ang);
    stab[idx] = sinf(ang);
  }
}

// ---------------- MFMA NT GEMM v2: BK=64, XOR-swizzled LDS (unchanged r15) ----
template<int EPI>
__global__ __launch_bounds__(256) void gemm_nt(
    const u16* __restrict__ A, const u16* __restrict__ Bw,
    const float* __restrict__ bias, float* __restrict__ outF,
    u16* __restrict__ q1t, u16* __restrict__ q2t,
    u16* __restrict__ k1t, u16* __restrict__ k2t, u16* __restrict__ vtT,
    const float* __restrict__ ctab, const float* __restrict__ stab,
    int N)
{
  const int K = 1024;
  __shared__ u16 As[128 * 64];
  __shared__ u16 Bs[128 * 64];
  int tid  = threadIdx.x;
  int lane = tid & 63, wave = tid >> 6;
  int wm = wave >> 1, wn = wave & 1;
  int m0 = blockIdx.y * 128, n0 = blockIdx.x * 128;
  int fr = lane & 15, hi = lane >> 4;

  int ac_r[4], ac_sb[4], cb_[4];
#pragma unroll
  for (int p = 0; p < 4; ++p) {
    int c = p * 256 + wave * 64 + lane;
    ac_r[p]  = c >> 3;
    ac_sb[p] = (c & 7) ^ (ac_r[p] & 7);
    cb_[p]   = (p * 256 + wave * 64) * 8;
  }

  f32x4 acc[4][4];
#pragma unroll
  for (int i = 0; i < 4; ++i)
#pragma unroll
    for (int j = 0; j < 4; ++j) acc[i][j] = 0.0f;

  for (int kk0 = 0; kk0 < K; kk0 += 64) {
    __syncthreads();
#pragma unroll
    for (int p = 0; p < 4; ++p) {
      gl_lds16(A  + (size_t)(m0 + ac_r[p]) * K + kk0 + ac_sb[p] * 8, &As[cb_[p]]);
      gl_lds16(Bw + (size_t)(n0 + ac_r[p]) * K + kk0 + ac_sb[p] * 8, &Bs[cb_[p]]);
    }
    __syncthreads();
#pragma unroll
    for (int ks = 0; ks < 2; ++ks) {
      bf16x8 af[4], bfv[4];
#pragma unroll
      for (int f = 0; f < 4; ++f) {
        int ra = wm * 64 + f * 16 + fr;
        int rb = wn * 64 + f * 16 + fr;
        int cba = (ks * 4 + hi) ^ (ra & 7);
        int cbb = (ks * 4 + hi) ^ (rb & 7);
        af[f]  = *(const bf16x8*)&As[ra * 64 + (cba << 3)];
        bfv[f] = *(const bf16x8*)&Bs[rb * 64 + (cbb << 3)];
      }
#pragma unroll
      for (int i = 0; i < 4; ++i)
#pragma unroll
        for (int j = 0; j < 4; ++j)
          acc[i][j] = __builtin_amdgcn_mfma_f32_16x16x32_bf16(af[i], bfv[j], acc[i][j], 0, 0, 0);
    }
  }

  int rg = lane >> 4;
  if (EPI == 0) {
    if (n0 < 4096) {
      u16* dst; int base;
      if (n0 < 1024)      { dst = q1t; base = 0; }
      else if (n0 < 2048) { dst = q2t; base = 1024; }
      else if (n0 < 3072) { dst = k1t; base = 2048; }
      else                { dst = k2t; base = 3072; }
      float qs = (n0 < 2048) ? 0.18033688011112042f : 1.0f;   // 0.125*log2e
#pragma unroll
      for (int i = 0; i < 4; ++i) {
#pragma unroll
        for (int e = 0; e < 4; ++e) {
          int m = m0 + wm * 64 + i * 16 + rg * 4 + e;
          int b = m >> 10, s = m & 1023;
#pragma unroll
          for (int j = 0; j < 2; ++j) {
            int n_lo = n0 + wn * 64 + j * 16 + fr;
            int feat = n_lo - base;
            int h = feat >> 6, dh = feat & 63;   // dh < 32
            float a1 = acc[i][j][e]     + bias[n_lo];
            float a2 = acc[i][j + 2][e] + bias[n_lo + 32];
            float cs = ctab[s * 32 + dh], sn = stab[s * 32 + dh];
            size_t rowb = ((size_t)(b * 16 + h) * 1024 + s) * 64;
            dst[rowb + dh]      = f2b((a1 * cs - a2 * sn) * qs);
            dst[rowb + dh + 32] = f2b((a1 * sn + a2 * cs) * qs);
          }
        }
      }
    } else {
      // v tensor: TRANSPOSED store [bh][dh][s]
#pragma unroll
      for (int i = 0; i < 4; ++i) {
        int mbase = m0 + wm * 64 + i * 16 + rg * 4;
        int b = mbase >> 10, s0 = mbase & 1023;
#pragma unroll
        for (int j = 0; j < 4; ++j) {
          int n = n0 + wn * 64 + j * 16 + fr;
          int feat = n - 4096;
          int h = feat >> 6, dh = feat & 63;
          float bv = bias[n];
          union { u16 hh[4]; uint2 u2; } p;
#pragma unroll
          for (int e = 0; e < 4; ++e) p.hh[e] = f2b(acc[i][j][e] + bv);
          *(uint2*)&vtT[((size_t)(b * 16 + h) * 64 + dh) * 1024 + s0] = p.u2;
        }
      }
    }
  } else {
#pragma unroll
    for (int i = 0; i < 4; ++i)
#pragma unroll
      for (int j = 0; j < 4; ++j)
#pragma unroll
        for (int e = 0; e < 4; ++e) {
          int m = m0 + wm * 64 + i * 16 + rg * 4 + e;
          int n = n0 + wn * 64 + j * 16 + fr;
          outF[(size_t)m * N + n] = acc[i][j][e] + bias[n];
        }
  }
}

// ---------------- fused MFMA attention v11 ----------------
// = r16 structure + FAR-TILE SKIP: mask factor ec = 2^c with c = -|logL_j-logL_i|
// and logL monotone non-increasing. Per (q-tile,k-tile) the exact bound
// maxc = nearest-endpoint difference; if maxc < -40, every masked numerator
// term is < 2^-35 relative -> invisible in output. Denominators are UNMASKED,
// so QK^T + e1/e2 + lacc still run for all tiles; far tiles skip the 3rd exp,
// P pack/write, both inner barriers, V staging, and all PV MFMAs.
// Branch is block-uniform (q0, kt, logL endpoints). Degrades to no-skip for
// data without decay (a ~= 1).
__global__ __launch_bounds__(256) void attn_fused(
    const u16* __restrict__ q1t, const u16* __restrict__ q2t,
    const u16* __restrict__ k1t, const u16* __restrict__ k2t,
    const u16* __restrict__ vtT,
    const float* __restrict__ logL, const float* __restrict__ lamp,
    u16* __restrict__ ctxb, float2* __restrict__ partials)
{
  __shared__ u16 K1s[64][72];   // K1 during QK^T, P1 during PV
  __shared__ u16 K2s[64][72];   // K2 during QK^T, P2 during PV
  __shared__ u16 Vts[64][72];   // V^T [dh][k], k-blocks XOR-swizzled by (dh>>3)&7
  __shared__ float lred1[2][2][32];
  __shared__ float lred2[2][2][32];
  __shared__ float pred[4][2];

  int tid  = threadIdx.x;
  int lane = tid & 63, wave = tid >> 6;
  int wm = wave >> 1, wn = wave & 1;
  int id = blockIdx.x;
  int bh = (id & 7) * 8 + (id >> 7);        // XCD-grouped: 8 bh per XCD (L2-fit)
  int q0 = ((id >> 3) & 15) * 64;
  int b = bh >> 4;
  int fr = lane & 15, hi = lane >> 4;

  bf16x8 qf1[2][2], qf2[2][2];
#pragma unroll
  for (int i = 0; i < 2; ++i)
#pragma unroll
    for (int ks = 0; ks < 2; ++ks) {
      size_t off = ((size_t)bh * 1024 + q0 + wm * 32 + i * 16 + fr) * 64 + ks * 32 + hi * 8;
      qf1[i][ks] = *(const bf16x8*)(q1t + off);
      qf2[i][ks] = *(const bf16x8*)(q2t + off);
    }
  float Lq[2][4];
#pragma unroll
  for (int i = 0; i < 2; ++i)
#pragma unroll
    for (int r = 0; r < 4; ++r)
      Lq[i][r] = logL[b * 1024 + q0 + wm * 32 + i * 16 + hi * 4 + r];

  float Lq_top = logL[b * 1024 + q0];
  float Lq_bot = logL[b * 1024 + q0 + 63];

  float lacc1[2][4], lacc2[2][4];
  f32x4 U1[2][2], U2[2][2];
#pragma unroll
  for (int i = 0; i < 2; ++i)
#pragma unroll
    for (int r = 0; r < 4; ++r) { lacc1[i][r] = 0.f; lacc2[i][r] = 0.f; }
#pragma unroll
  for (int i = 0; i < 2; ++i)
#pragma unroll
    for (int j = 0; j < 2; ++j) { U1[i][j] = 0.f; U2[i][j] = 0.f; }

  int sr = tid >> 2, sc0 = (tid & 3) * 16;
  int swz = (sr >> 3) & 7;
  int blk0 = ((sc0 >> 3) ^ swz) << 3;
  int blk1 = (((sc0 >> 3) + 1) ^ swz) << 3;

  unsigned a1base = (unsigned)(size_t)&K1s[wm * 32 + hi * 4][wn * 32 + fr];
  unsigned a2base = (unsigned)(size_t)&K2s[wm * 32 + hi * 4][wn * 32 + fr];

  for (int kt = 0; kt < 16; ++kt) {
    // exact tile-pair mask bound (block-uniform)
    int ktop = kt * 64;
    float maxc;
    if (ktop > q0 + 63)      maxc = logL[b * 1024 + ktop] - Lq_bot;
    else if (ktop + 63 < q0) maxc = Lq_top - logL[b * 1024 + ktop + 63];
    else                     maxc = 0.f;
    bool far = (maxc < -40.f);

    __syncthreads();   // (1) prev tile's LDS reads done
    size_t gb = ((size_t)bh * 1024 + kt * 64 + sr) * 64 + sc0;
    bf16x8 a0 = *(const bf16x8*)(k1t + gb), a1 = *(const bf16x8*)(k1t + gb + 8);
    bf16x8 b0 = *(const bf16x8*)(k2t + gb), b1 = *(const bf16x8*)(k2t + gb + 8);
    *(bf16x8*)&K1s[sr][sc0] = a0;  *(bf16x8*)&K1s[sr][sc0 + 8] = a1;
    *(bf16x8*)&K2s[sr][sc0] = b0;  *(bf16x8*)&K2s[sr][sc0 + 8] = b1;
    if (!far) {
      size_t gv = (size_t)bh * 65536 + (size_t)sr * 1024 + kt * 64 + sc0;
      bf16x8 v0 = *(const bf16x8*)(vtT + gv), v1 = *(const bf16x8*)(vtT + gv + 8);
      *(bf16x8*)&Vts[sr][blk0] = v0;  *(bf16x8*)&Vts[sr][blk1] = v1;
    }
    __syncthreads();   // (2) stage complete

    // ---- QK^T (always: denominators are unmasked) ----
    f32x4 S1[2][2], S2[2][2];
#pragma unroll
    for (int i = 0; i < 2; ++i)
#pragma unroll
      for (int j = 0; j < 2; ++j) { S1[i][j] = 0.f; S2[i][j] = 0.f; }
    __builtin_amdgcn_s_setprio(1);
#pragma unroll
    for (int ks = 0; ks < 2; ++ks) {
      bf16x8 kf1[2], kf2[2];
#pragma unroll
      for (int j = 0; j < 2; ++j) {
        kf1[j] = *(const bf16x8*)&K1s[wn * 32 + j * 16 + fr][ks * 32 + hi * 8];
        kf2[j] = *(const bf16x8*)&K2s[wn * 32 + j * 16 + fr][ks * 32 + hi * 8];
      }
#pragma unroll
      for (int i = 0; i < 2; ++i)
#pragma unroll
        for (int j = 0; j < 2; ++j) {
          S1[i][j] = __builtin_amdgcn_mfma_f32_16x16x32_bf16(qf1[i][ks], kf1[j], S1[i][j], 0, 0, 0);
          S2[i][j] = __builtin_amdgcn_mfma_f32_16x16x32_bf16(qf2[i][ks], kf2[j], S2[i][j], 0, 0, 0);
        }
    }
    __builtin_amdgcn_s_setprio(0);

    if (!far) {
      float Ltl[2];
#pragma unroll
      for (int j = 0; j < 2; ++j) Ltl[j] = logL[b * 1024 + kt * 64 + wn * 32 + j * 16 + fr];
      __syncthreads();   // (3) all K reads done -> K-space reusable as P

      // ---- exponentials (log2 domain) + packed P write ----
#pragma unroll
      for (int i = 0; i < 2; ++i) {
#pragma unroll
        for (int r = 0; r < 4; ++r) {
          float lq = Lq[i][r];
          float e1j[2], e2j[2], p1j[2], p2j[2];
#pragma unroll
          for (int j = 0; j < 2; ++j) {
            float nd = -fabsf(Ltl[j] - lq);
            float t1, t2, ec;
            asm("v_exp_f32 %0, %1" : "=v"(t1) : "v"(S1[i][j][r]));
            asm("v_exp_f32 %0, %1" : "=v"(t2) : "v"(S2[i][j][r]));
            asm("v_exp_f32 %0, %1" : "=v"(ec) : "v"(nd));
            e1j[j] = t1; e2j[j] = t2;
            p1j[j] = t1 * ec; p2j[j] = t2 * ec;
          }
          lacc1[i][r] += e1j[0] + e1j[1];
          lacc2[i][r] += e2j[0] + e2j[1];
          unsigned off = (unsigned)((i * 16 + r) * 144);
          unsigned ad1 = a1base + off, ad2 = a2base + off;
          unsigned pk1, pk2;
          asm("v_cvt_pk_bf16_f32 %0, %1, %2" : "=v"(pk1) : "v"(p1j[0]), "v"(p1j[1]));
          asm("v_cvt_pk_bf16_f32 %0, %1, %2" : "=v"(pk2) : "v"(p2j[0]), "v"(p2j[1]));
          asm volatile("ds_write_b16 %0, %1\n\tds_write_b16_d16_hi %0, %1 offset:32"
                       :: "v"(ad1), "v"(pk1) : "memory");
          asm volatile("ds_write_b16 %0, %1\n\tds_write_b16_d16_hi %0, %1 offset:32"
                       :: "v"(ad2), "v"(pk2) : "memory");
        }
      }
      __syncthreads();   // (4) P complete

      // ---- PV: U += P * V (P in K1s/K2s, V^T in Vts) ----
      __builtin_amdgcn_s_setprio(1);
#pragma unroll
      for (int ks = 0; ks < 2; ++ks) {
        bf16x8 pa1[2], pa2[2], vb[2];
#pragma unroll
        for (int i = 0; i < 2; ++i) {
          pa1[i] = *(const bf16x8*)&K1s[wm * 32 + i * 16 + fr][ks * 32 + hi * 8];
          pa2[i] = *(const bf16x8*)&K2s[wm * 32 + i * 16 + fr][ks * 32 + hi * 8];
        }
#pragma unroll
        for (int j = 0; j < 2; ++j) {
          int row = wn * 32 + j * 16 + fr;
          int kbb = (ks * 4 + hi) ^ ((row >> 3) & 7);
          vb[j] = *(const bf16x8*)&Vts[row][kbb << 3];
        }
#pragma unroll
        for (int i = 0; i < 2; ++i)
#pragma unroll
          for (int j = 0; j < 2; ++j) {
            U1[i][j] = __builtin_amdgcn_mfma_f32_16x16x32_bf16(pa1[i], vb[j], U1[i][j], 0, 0, 0);
            U2[i][j] = __builtin_amdgcn_mfma_f32_16x16x32_bf16(pa2[i], vb[j], U2[i][j], 0, 0, 0);
          }
      }
      __builtin_amdgcn_s_setprio(0);
    } else {
      // far tile: denominators only (2 exps, no mask, no P, no PV, no barriers)
#pragma unroll
      for (int i = 0; i < 2; ++i) {
#pragma unroll
        for (int r = 0; r < 4; ++r) {
          float t1a, t1b, t2a, t2b;
          asm("v_exp_f32 %0, %1" : "=v"(t1a) : "v"(S1[i][0][r]));
          asm("v_exp_f32 %0, %1" : "=v"(t1b) : "v"(S1[i][1][r]));
          asm("v_exp_f32 %0, %1" : "=v"(t2a) : "v"(S2[i][0][r]));
          asm("v_exp_f32 %0, %1" : "=v"(t2b) : "v"(S2[i][1][r]));
          lacc1[i][r] += t1a + t1b;
          lacc2[i][r] += t2a + t2b;
        }
      }
    }
  }

  // ---- denominator: intra-wave reduce over fr, then cross-wave over wn ----
#pragma unroll
  for (int i = 0; i < 2; ++i)
#pragma unroll
    for (int r = 0; r < 4; ++r) {
#pragma unroll
      for (int m = 1; m < 16; m <<= 1) {
        lacc1[i][r] += __shfl_xor(lacc1[i][r], m);
        lacc2[i][r] += __shfl_xor(lacc2[i][r], m);
      }
    }
  if (fr == 0) {
#pragma unroll
    for (int i = 0; i < 2; ++i)
#pragma unroll
      for (int r = 0; r < 4; ++r) {
        int rl = i * 16 + hi * 4 + r;
        lred1[wn][wm][rl] = lacc1[i][r];
        lred2[wn][wm][rl] = lacc2[i][r];
      }
  }
  __syncthreads();
  float lam = lamp[0];

  // ---- epilogue: ctx(bf16) = U1/l1 - lam*U2/l2, plus block partial Sum/SumSq ----
  float psum = 0.f, psq = 0.f;
#pragma unroll
  for (int i = 0; i < 2; ++i) {
#pragma unroll
    for (int r = 0; r < 4; ++r) {
      int rl = i * 16 + hi * 4 + r;
      float l1 = lred1[0][wm][rl] + lred1[1][wm][rl];
      float l2 = lred2[0][wm][rl] + lred2[1][wm][rl];
      float inv1 = 1.f / l1;
      float inv2 = lam / l2;
      int qg = q0 + wm * 32 + i * 16 + hi * 4 + r;
#pragma unroll
      for (int j = 0; j < 2; ++j) {
        int dh = wn * 32 + j * 16 + fr;
        float o = U1[i][j][r] * inv1 - U2[i][j][r] * inv2;
        ctxb[((size_t)bh * 1024 + qg) * 64 + dh] = f2b(o);
        psum += o; psq += o * o;
      }
    }
  }
#pragma unroll
  for (int m = 1; m < 64; m <<= 1) {
    psum += __shfl_xor(psum, m);
    psq  += __shfl_xor(psq, m);
  }
  if (lane == 0) { pred[wave][0] = psum; pred[wave][1] = psq; }
  __syncthreads();
  if (tid == 0)
    partials[id] = make_float2(pred[0][0] + pred[1][0] + pred[2][0] + pred[3][0],
                               pred[0][1] + pred[1][1] + pred[2][1] + pred[3][1]);
}

// ---------------- gn_apply v2: inline combine (one (b,s) row per block) ----------------
__global__ __launch_bounds__(256) void gn_apply(
    const u16* __restrict__ ctxb, const float2* __restrict__ partials,
    const float* __restrict__ gw, const float* __restrict__ gb,
    u16* __restrict__ normed)
{
  int tid = threadIdx.x;
  int srow = blockIdx.x;            // b*1024 + s
  int b = srow >> 10;
  int h = tid >> 4, qi = tid & 15;
  int bh = b * 16 + h;
  float2 pp = partials[(bh & 7) * 128 + qi * 8 + (bh >> 3)];
  float s = pp.x, ss = pp.y;
#pragma unroll
  for (int o = 1; o < 16; o <<= 1) { s += __shfl_xor(s, o); ss += __shfl_xor(ss, o); }
  float mean = s * (1.f / 65536.f);
  float vinv = rsqrtf(ss * (1.f / 65536.f) - mean * mean + 1e-5f);

  unsigned d  = (unsigned)tid * 4u;     // 0..1020, h == d>>6
  unsigned dh = d & 63u;
  uint2 raw = *(const uint2*)&ctxb[(((size_t)bh) * 1024 + (srow & 1023)) * 64 + dh];
  const u16* rp = (const u16*)&raw;
  float4 g  = *(const float4*)&gw[d];
  float4 be = *(const float4*)&gb[d];
  union { u16 hh[4]; uint2 u2; } p;
  p.hh[0] = f2b(((b2f(rp[0]) - mean) * vinv * g.x + be.x) * 0.8f);
  p.hh[1] = f2b(((b2f(rp[1]) - mean) * vinv * g.y + be.y) * 0.8f);
  p.hh[2] = f2b(((b2f(rp[2]) - mean) * vinv * g.z + be.z) * 0.8f);
  p.hh[3] = f2b(((b2f(rp[3]) - mean) * vinv * g.w + be.w) * 0.8f);
  *(uint2*)&normed[(size_t)srow * 1024 + d] = p.u2;
}

// ---------------- launch ----------------
extern "C" void kernel_launch(void* const* d_in, const int* in_sizes, int n_in,
                              void* d_out, int out_size, void* d_ws, size_t ws_size,
                              hipStream_t stream) {
  (void)in_sizes; (void)n_in; (void)out_size; (void)ws_size;
  const float* x   = (const float*)d_in[0];
  const float* aff = (const float*)d_in[1];
  const float* Wq  = (const float*)d_in[2];
  const float* bq  = (const float*)d_in[3];
  const float* Wk  = (const float*)d_in[4];
  const float* bk  = (const float*)d_in[5];
  const float* Wv  = (const float*)d_in[6];
  const float* bv  = (const float*)d_in[7];
  const float* Wo  = (const float*)d_in[8];
  const float* bo  = (const float*)d_in[9];
  const float* gw  = (const float*)d_in[10];
  const float* gb  = (const float*)d_in[11];
  const float* lam = (const float*)d_in[12];
  float* out = (float*)d_out;

  char* w = (char*)d_ws;
  u16*    xb    = (u16*)(w);
  u16*    Wcat  = (u16*)(w + 8388608);
  u16*    Wob   = (u16*)(w + 18874368);
  float*  bcat  = (float*)(w + 20971520);
  u16*    q1t   = (u16*)(w + 20992000);
  u16*    q2t   = (u16*)(w + 29380608);
  u16*    k1t   = (u16*)(w + 37769216);
  u16*    k2t   = (u16*)(w + 46157824);
  u16*    vtT   = (u16*)(w + 54546432);   // [bh][dh][s] transposed
  float*  logL  = (float*)(w + 62935040);
  float*  ctab  = (float*)(w + 62951424);
  float*  stab  = (float*)(w + 63082496);
  float2* parts = (float2*)(w + 63213568); // 1024 float2
  u16*    ctxb  = (u16*)(w + 63475712);    // bf16 ctx (8.4MB)
  u16*    normed= (u16*)(w + 80253440);

  convert_kernel<<<10245, 256, 0, stream>>>(x, Wq, Wk, Wv, Wo, bq, bk, bv, xb, Wcat, Wob, bcat);
  prep_kernel<<<36, 1024, 0, stream>>>(aff, logL, ctab, stab);
  gemm_nt<0><<<dim3(40, 32), 256, 0, stream>>>(xb, Wcat, bcat, nullptr, q1t, q2t, k1t, k2t, vtT, ctab, stab, 5120);
  attn_fused<<<1024, 256, 0, stream>>>(q1t, q2t, k1t, k2t, vtT, logL, lam, ctxb, parts);
  gn_apply<<<4096, 256, 0, stream>>>(ctxb, parts, gw, gb, normed);
  gemm_nt<1><<<dim3(8, 32), 256, 0, stream>>>(normed, Wob, bo, out, nullptr, nullptr, nullptr, nullptr, nullptr, ctab, stab, 1024);
}

// Round 18
// 166.387 us; speedup vs baseline: 1.3504x; 1.0066x over previous
//
#include <hip/hip_runtime.h>
#include <math.h>

typedef float  f32x4  __attribute__((ext_vector_type(4)));
typedef short  bf16x8 __attribute__((ext_vector_type(8)));
typedef unsigned short u16;

__device__ __forceinline__ u16 f2b(float f) {
  union { float f; unsigned u; } v; v.f = f;
  unsigned r = v.u + 0x7FFFu + ((v.u >> 16) & 1u);
  return (u16)(r >> 16);
}
__device__ __forceinline__ float b2f(u16 h) {
  union { unsigned u; float f; } v; v.u = ((unsigned)h) << 16;
  return v.f;
}

// async global->LDS, 16B per lane; dest = wave-uniform base + lane*16
__device__ __forceinline__ void gl_lds16(const u16* g, u16* l) {
  __builtin_amdgcn_global_load_lds(
      (const __attribute__((address_space(1))) unsigned*)g,
      (__attribute__((address_space(3))) unsigned*)l, 16, 0, 0);
}

// ---------------- fp32 -> bf16 conversion / packing ----------------
__global__ __launch_bounds__(256) void convert_kernel(
    const float* __restrict__ x,  const float* __restrict__ Wq,
    const float* __restrict__ Wk, const float* __restrict__ Wv,
    const float* __restrict__ Wo, const float* __restrict__ bq,
    const float* __restrict__ bk, const float* __restrict__ bv,
    u16* __restrict__ xb, u16* __restrict__ Wcat, u16* __restrict__ Wob,
    float* __restrict__ bcat)
{
  long i = ((long)blockIdx.x * 256 + threadIdx.x) * 4;
  if (i < 10485760L) {
    const float* src; u16* dst; long o;
    if (i < 4194304L)      { src = x;  dst = xb;             o = i; }
    else if (i < 6291456L) { src = Wq; dst = Wcat;           o = i - 4194304L; }
    else if (i < 8388608L) { src = Wk; dst = Wcat + 2097152; o = i - 6291456L; }
    else if (i < 9437184L) { src = Wv; dst = Wcat + 4194304; o = i - 8388608L; }
    else                   { src = Wo; dst = Wob;            o = i - 9437184L; }
    float4 v = *(const float4*)(src + o);
    union { u16 h[4]; uint2 u2; } p;
    p.h[0] = f2b(v.x); p.h[1] = f2b(v.y); p.h[2] = f2b(v.z); p.h[3] = f2b(v.w);
    *(uint2*)(dst + o) = p.u2;
  } else if (i < 10490880L) {
    long j = i - 10485760L;
    const float* src; long o;
    if (j < 2048)      { src = bq; o = j; }
    else if (j < 4096) { src = bk; o = j - 2048; }
    else               { src = bv; o = j - 4096; }
    *(float4*)(bcat + j) = *(const float4*)(src + o);
  }
}

// ---------------- prep: logL scan (blocks 0-3) + RoPE table (blocks 4-35) ----------------
__global__ __launch_bounds__(1024) void prep_kernel(
    const float* __restrict__ a, float* __restrict__ logL,
    float* __restrict__ ctab, float* __restrict__ stab)
{
  if (blockIdx.x < 4) {
    __shared__ float sh[1024];
    int b = blockIdx.x, t = threadIdx.x;
    float v = (t == 0) ? 0.f : log2f(a[b * 1023 + t - 1]);
    sh[t] = v;
    __syncthreads();
    for (int off = 1; off < 1024; off <<= 1) {
      float add = (t >= off) ? sh[t - off] : 0.f;
      __syncthreads();
      sh[t] += add;
      __syncthreads();
    }
    logL[b * 1024 + t] = sh[t];
  } else {
    int idx = (blockIdx.x - 4) * 1024 + threadIdx.x;   // 0..32767
    int s = idx >> 5, i = idx & 31;
    float freq = expf(-(float)i * (9.210340371976184f / 32.f));  // 10000^(-i/32)
    float ang = (float)s * freq;
    ctab[idx] = cosf(ang);
    stab[idx] = sinf(ang);
  }
}

// ---------------- MFMA NT GEMM v3: BK=64, XOR-swizzled LDS ----------------
// EPI=0 q/k epilogue: dh-PERMUTED storage (rotated pair (dh,dh+32) -> (2dh,2dh+1)).
// QK^T is invariant under shared head-dim permutation of q and k, so the
// attention kernel is unchanged. Pack via v_cvt_pk_bf16_f32 + one 4B store
// (coalesced 64B per 16-lane group) instead of 2 f2b + 2 scattered 2B stores.
template<int EPI>
__global__ __launch_bounds__(256) void gemm_nt(
    const u16* __restrict__ A, const u16* __restrict__ Bw,
    const float* __restrict__ bias, float* __restrict__ outF,
    u16* __restrict__ q1t, u16* __restrict__ q2t,
    u16* __restrict__ k1t, u16* __restrict__ k2t, u16* __restrict__ vtT,
    const float* __restrict__ ctab, const float* __restrict__ stab,
    int N)
{
  const int K = 1024;
  __shared__ u16 As[128 * 64];
  __shared__ u16 Bs[128 * 64];
  int tid  = threadIdx.x;
  int lane = tid & 63, wave = tid >> 6;
  int wm = wave >> 1, wn = wave & 1;
  int m0 = blockIdx.y * 128, n0 = blockIdx.x * 128;
  int fr = lane & 15, hi = lane >> 4;

  int ac_r[4], ac_sb[4], cb_[4];
#pragma unroll
  for (int p = 0; p < 4; ++p) {
    int c = p * 256 + wave * 64 + lane;
    ac_r[p]  = c >> 3;
    ac_sb[p] = (c & 7) ^ (ac_r[p] & 7);
    cb_[p]   = (p * 256 + wave * 64) * 8;
  }

  f32x4 acc[4][4];
#pragma unroll
  for (int i = 0; i < 4; ++i)
#pragma unroll
    for (int j = 0; j < 4; ++j) acc[i][j] = 0.0f;

  for (int kk0 = 0; kk0 < K; kk0 += 64) {
    __syncthreads();
#pragma unroll
    for (int p = 0; p < 4; ++p) {
      gl_lds16(A  + (size_t)(m0 + ac_r[p]) * K + kk0 + ac_sb[p] * 8, &As[cb_[p]]);
      gl_lds16(Bw + (size_t)(n0 + ac_r[p]) * K + kk0 + ac_sb[p] * 8, &Bs[cb_[p]]);
    }
    __syncthreads();
#pragma unroll
    for (int ks = 0; ks < 2; ++ks) {
      bf16x8 af[4], bfv[4];
#pragma unroll
      for (int f = 0; f < 4; ++f) {
        int ra = wm * 64 + f * 16 + fr;
        int rb = wn * 64 + f * 16 + fr;
        int cba = (ks * 4 + hi) ^ (ra & 7);
        int cbb = (ks * 4 + hi) ^ (rb & 7);
        af[f]  = *(const bf16x8*)&As[ra * 64 + (cba << 3)];
        bfv[f] = *(const bf16x8*)&Bs[rb * 64 + (cbb << 3)];
      }
#pragma unroll
      for (int i = 0; i < 4; ++i)
#pragma unroll
        for (int j = 0; j < 4; ++j)
          acc[i][j] = __builtin_amdgcn_mfma_f32_16x16x32_bf16(af[i], bfv[j], acc[i][j], 0, 0, 0);
    }
  }

  int rg = lane >> 4;
  if (EPI == 0) {
    if (n0 < 4096) {
      u16* dst; int base;
      if (n0 < 1024)      { dst = q1t; base = 0; }
      else if (n0 < 2048) { dst = q2t; base = 1024; }
      else if (n0 < 3072) { dst = k1t; base = 2048; }
      else                { dst = k2t; base = 3072; }
      float qs = (n0 < 2048) ? 0.18033688011112042f : 1.0f;   // 0.125*log2e
#pragma unroll
      for (int i = 0; i < 4; ++i) {
#pragma unroll
        for (int e = 0; e < 4; ++e) {
          int m = m0 + wm * 64 + i * 16 + rg * 4 + e;
          int b = m >> 10, s = m & 1023;
#pragma unroll
          for (int j = 0; j < 2; ++j) {
            int n_lo = n0 + wn * 64 + j * 16 + fr;
            int feat = n_lo - base;
            int h = feat >> 6, dh = feat & 63;   // dh < 32
            float a1 = acc[i][j][e]     + bias[n_lo];
            float a2 = acc[i][j + 2][e] + bias[n_lo + 32];
            float cs = ctab[s * 32 + dh], sn = stab[s * 32 + dh];
            float r0 = (a1 * cs - a2 * sn) * qs;
            float r1 = (a1 * sn + a2 * cs) * qs;
            unsigned pk;
            asm("v_cvt_pk_bf16_f32 %0, %1, %2" : "=v"(pk) : "v"(r0), "v"(r1));
            size_t rowb = ((size_t)(b * 16 + h) * 1024 + s) * 64;
            *(unsigned*)&dst[rowb + 2 * dh] = pk;   // permuted: (dh,dh+32)->(2dh,2dh+1)
          }
        }
      }
    } else {
      // v tensor: TRANSPOSED store [bh][dh][s] (unpermuted)
#pragma unroll
      for (int i = 0; i < 4; ++i) {
        int mbase = m0 + wm * 64 + i * 16 + rg * 4;
        int b = mbase >> 10, s0 = mbase & 1023;
#pragma unroll
        for (int j = 0; j < 4; ++j) {
          int n = n0 + wn * 64 + j * 16 + fr;
          int feat = n - 4096;
          int h = feat >> 6, dh = feat & 63;
          float bv = bias[n];
          union { u16 hh[4]; uint2 u2; } p;
#pragma unroll
          for (int e = 0; e < 4; ++e) p.hh[e] = f2b(acc[i][j][e] + bv);
          *(uint2*)&vtT[((size_t)(b * 16 + h) * 64 + dh) * 1024 + s0] = p.u2;
        }
      }
    }
  } else {
#pragma unroll
    for (int i = 0; i < 4; ++i)
#pragma unroll
      for (int j = 0; j < 4; ++j)
#pragma unroll
        for (int e = 0; e < 4; ++e) {
          int m = m0 + wm * 64 + i * 16 + rg * 4 + e;
          int n = n0 + wn * 64 + j * 16 + fr;
          outF[(size_t)m * N + n] = acc[i][j][e] + bias[n];
        }
  }
}

// ---------------- fused MFMA attention v11 (unchanged r17; q/k dh-permutation
// is transparent: identical contiguous fragment indexing on both operands) ----
__global__ __launch_bounds__(256) void attn_fused(
    const u16* __restrict__ q1t, const u16* __restrict__ q2t,
    const u16* __restrict__ k1t, const u16* __restrict__ k2t,
    const u16* __restrict__ vtT,
    const float* __restrict__ logL, const float* __restrict__ lamp,
    u16* __restrict__ ctxb, float2* __restrict__ partials)
{
  __shared__ u16 K1s[64][72];   // K1 during QK^T, P1 during PV
  __shared__ u16 K2s[64][72];   // K2 during QK^T, P2 during PV
  __shared__ u16 Vts[64][72];   // V^T [dh][k], k-blocks XOR-swizzled by (dh>>3)&7
  __shared__ float lred1[2][2][32];
  __shared__ float lred2[2][2][32];
  __shared__ float pred[4][2];

  int tid  = threadIdx.x;
  int lane = tid & 63, wave = tid >> 6;
  int wm = wave >> 1, wn = wave & 1;
  int id = blockIdx.x;
  int bh = (id & 7) * 8 + (id >> 7);        // XCD-grouped: 8 bh per XCD (L2-fit)
  int q0 = ((id >> 3) & 15) * 64;
  int b = bh >> 4;
  int fr = lane & 15, hi = lane >> 4;

  bf16x8 qf1[2][2], qf2[2][2];
#pragma unroll
  for (int i = 0; i < 2; ++i)
#pragma unroll
    for (int ks = 0; ks < 2; ++ks) {
      size_t off = ((size_t)bh * 1024 + q0 + wm * 32 + i * 16 + fr) * 64 + ks * 32 + hi * 8;
      qf1[i][ks] = *(const bf16x8*)(q1t + off);
      qf2[i][ks] = *(const bf16x8*)(q2t + off);
    }
  float Lq[2][4];
#pragma unroll
  for (int i = 0; i < 2; ++i)
#pragma unroll
    for (int r = 0; r < 4; ++r)
      Lq[i][r] = logL[b * 1024 + q0 + wm * 32 + i * 16 + hi * 4 + r];

  float Lq_top = logL[b * 1024 + q0];
  float Lq_bot = logL[b * 1024 + q0 + 63];

  float lacc1[2][4], lacc2[2][4];
  f32x4 U1[2][2], U2[2][2];
#pragma unroll
  for (int i = 0; i < 2; ++i)
#pragma unroll
    for (int r = 0; r < 4; ++r) { lacc1[i][r] = 0.f; lacc2[i][r] = 0.f; }
#pragma unroll
  for (int i = 0; i < 2; ++i)
#pragma unroll
    for (int j = 0; j < 2; ++j) { U1[i][j] = 0.f; U2[i][j] = 0.f; }

  int sr = tid >> 2, sc0 = (tid & 3) * 16;
  int swz = (sr >> 3) & 7;
  int blk0 = ((sc0 >> 3) ^ swz) << 3;
  int blk1 = (((sc0 >> 3) + 1) ^ swz) << 3;

  unsigned a1base = (unsigned)(size_t)&K1s[wm * 32 + hi * 4][wn * 32 + fr];
  unsigned a2base = (unsigned)(size_t)&K2s[wm * 32 + hi * 4][wn * 32 + fr];

  for (int kt = 0; kt < 16; ++kt) {
    // exact tile-pair mask bound (block-uniform)
    int ktop = kt * 64;
    float maxc;
    if (ktop > q0 + 63)      maxc = logL[b * 1024 + ktop] - Lq_bot;
    else if (ktop + 63 < q0) maxc = Lq_top - logL[b * 1024 + ktop + 63];
    else                     maxc = 0.f;
    bool far = (maxc < -40.f);

    __syncthreads();   // (1) prev tile's LDS reads done
    size_t gb = ((size_t)bh * 1024 + kt * 64 + sr) * 64 + sc0;
    bf16x8 a0 = *(const bf16x8*)(k1t + gb), a1 = *(const bf16x8*)(k1t + gb + 8);
    bf16x8 b0 = *(const bf16x8*)(k2t + gb), b1 = *(const bf16x8*)(k2t + gb + 8);
    *(bf16x8*)&K1s[sr][sc0] = a0;  *(bf16x8*)&K1s[sr][sc0 + 8] = a1;
    *(bf16x8*)&K2s[sr][sc0] = b0;  *(bf16x8*)&K2s[sr][sc0 + 8] = b1;
    if (!far) {
      size_t gv = (size_t)bh * 65536 + (size_t)sr * 1024 + kt * 64 + sc0;
      bf16x8 v0 = *(const bf16x8*)(vtT + gv), v1 = *(const bf16x8*)(vtT + gv + 8);
      *(bf16x8*)&Vts[sr][blk0] = v0;  *(bf16x8*)&Vts[sr][blk1] = v1;
    }
    __syncthreads();   // (2) stage complete

    // ---- QK^T (always: denominators are unmasked) ----
    f32x4 S1[2][2], S2[2][2];
#pragma unroll
    for (int i = 0; i < 2; ++i)
#pragma unroll
      for (int j = 0; j < 2; ++j) { S1[i][j] = 0.f; S2[i][j] = 0.f; }
    __builtin_amdgcn_s_setprio(1);
#pragma unroll
    for (int ks = 0; ks < 2; ++ks) {
      bf16x8 kf1[2], kf2[2];
#pragma unroll
      for (int j = 0; j < 2; ++j) {
        kf1[j] = *(const bf16x8*)&K1s[wn * 32 + j * 16 + fr][ks * 32 + hi * 8];
        kf2[j] = *(const bf16x8*)&K2s[wn * 32 + j * 16 + fr][ks * 32 + hi * 8];
      }
#pragma unroll
      for (int i = 0; i < 2; ++i)
#pragma unroll
        for (int j = 0; j < 2; ++j) {
          S1[i][j] = __builtin_amdgcn_mfma_f32_16x16x32_bf16(qf1[i][ks], kf1[j], S1[i][j], 0, 0, 0);
          S2[i][j] = __builtin_amdgcn_mfma_f32_16x16x32_bf16(qf2[i][ks], kf2[j], S2[i][j], 0, 0, 0);
        }
    }
    __builtin_amdgcn_s_setprio(0);

    if (!far) {
      float Ltl[2];
#pragma unroll
      for (int j = 0; j < 2; ++j) Ltl[j] = logL[b * 1024 + kt * 64 + wn * 32 + j * 16 + fr];
      __syncthreads();   // (3) all K reads done -> K-space reusable as P

      // ---- exponentials (log2 domain) + packed P write ----
#pragma unroll
      for (int i = 0; i < 2; ++i) {
#pragma unroll
        for (int r = 0; r < 4; ++r) {
          float lq = Lq[i][r];
          float e1j[2], e2j[2], p1j[2], p2j[2];
#pragma unroll
          for (int j = 0; j < 2; ++j) {
            float nd = -fabsf(Ltl[j] - lq);
            float t1, t2, ec;
            asm("v_exp_f32 %0, %1" : "=v"(t1) : "v"(S1[i][j][r]));
            asm("v_exp_f32 %0, %1" : "=v"(t2) : "v"(S2[i][j][r]));
            asm("v_exp_f32 %0, %1" : "=v"(ec) : "v"(nd));
            e1j[j] = t1; e2j[j] = t2;
            p1j[j] = t1 * ec; p2j[j] = t2 * ec;
          }
          lacc1[i][r] += e1j[0] + e1j[1];
          lacc2[i][r] += e2j[0] + e2j[1];
          unsigned off = (unsigned)((i * 16 + r) * 144);
          unsigned ad1 = a1base + off, ad2 = a2base + off;
          unsigned pk1, pk2;
          asm("v_cvt_pk_bf16_f32 %0, %1, %2" : "=v"(pk1) : "v"(p1j[0]), "v"(p1j[1]));
          asm("v_cvt_pk_bf16_f32 %0, %1, %2" : "=v"(pk2) : "v"(p2j[0]), "v"(p2j[1]));
          asm volatile("ds_write_b16 %0, %1\n\tds_write_b16_d16_hi %0, %1 offset:32"
                       :: "v"(ad1), "v"(pk1) : "memory");
          asm volatile("ds_write_b16 %0, %1\n\tds_write_b16_d16_hi %0, %1 offset:32"
                       :: "v"(ad2), "v"(pk2) : "memory");
        }
      }
      __syncthreads();   // (4) P complete

      // ---- PV: U += P * V (P in K1s/K2s, V^T in Vts) ----
      __builtin_amdgcn_s_setprio(1);
#pragma unroll
      for (int ks = 0; ks < 2; ++ks) {
        bf16x8 pa1[2], pa2[2], vb[2];
#pragma unroll
        for (int i = 0; i < 2; ++i) {
          pa1[i] = *(const bf16x8*)&K1s[wm * 32 + i * 16 + fr][ks * 32 + hi * 8];
          pa2[i] = *(const bf16x8*)&K2s[wm * 32 + i * 16 + fr][ks * 32 + hi * 8];
        }
#pragma unroll
        for (int j = 0; j < 2; ++j) {
          int row = wn * 32 + j * 16 + fr;
          int kbb = (ks * 4 + hi) ^ ((row >> 3) & 7);
          vb[j] = *(const bf16x8*)&Vts[row][kbb << 3];
        }
#pragma unroll
        for (int i = 0; i < 2; ++i)
#pragma unroll
          for (int j = 0; j < 2; ++j) {
            U1[i][j] = __builtin_amdgcn_mfma_f32_16x16x32_bf16(pa1[i], vb[j], U1[i][j], 0, 0, 0);
            U2[i][j] = __builtin_amdgcn_mfma_f32_16x16x32_bf16(pa2[i], vb[j], U2[i][j], 0, 0, 0);
          }
      }
      __builtin_amdgcn_s_setprio(0);
    } else {
      // far tile: denominators only (2 exps, no mask, no P, no PV, no barriers)
#pragma unroll
      for (int i = 0; i < 2; ++i) {
#pragma unroll
        for (int r = 0; r < 4; ++r) {
          float t1a, t1b, t2a, t2b;
          asm("v_exp_f32 %0, %1" : "=v"(t1a) : "v"(S1[i][0][r]));
          asm("v_exp_f32 %0, %1" : "=v"(t1b) : "v"(S1[i][1][r]));
          asm("v_exp_f32 %0, %1" : "=v"(t2a) : "v"(S2[i][0][r]));
          asm("v_exp_f32 %0, %1" : "=v"(t2b) : "v"(S2[i][1][r]));
          lacc1[i][r] += t1a + t1b;
          lacc2[i][r] += t2a + t2b;
        }
      }
    }
  }

  // ---- denominator: intra-wave reduce over fr, then cross-wave over wn ----
#pragma unroll
  for (int i = 0; i < 2; ++i)
#pragma unroll
    for (int r = 0; r < 4; ++r) {
#pragma unroll
      for (int m = 1; m < 16; m <<= 1) {
        lacc1[i][r] += __shfl_xor(lacc1[i][r], m);
        lacc2[i][r] += __shfl_xor(lacc2[i][r], m);
      }
    }
  if (fr == 0) {
#pragma unroll
    for (int i = 0; i < 2; ++i)
#pragma unroll
      for (int r = 0; r < 4; ++r) {
        int rl = i * 16 + hi * 4 + r;
        lred1[wn][wm][rl] = lacc1[i][r];
        lred2[wn][wm][rl] = lacc2[i][r];
      }
  }
  __syncthreads();
  float lam = lamp[0];

  // ---- epilogue: ctx(bf16) = U1/l1 - lam*U2/l2, plus block partial Sum/SumSq ----
  float psum = 0.f, psq = 0.f;
#pragma unroll
  for (int i = 0; i < 2; ++i) {
#pragma unroll
    for (int r = 0; r < 4; ++r) {
      int rl = i * 16 + hi * 4 + r;
      float l1 = lred1[0][wm][rl] + lred1[1][wm][rl];
      float l2 = lred2[0][wm][rl] + lred2[1][wm][rl];
      float inv1 = 1.f / l1;
      float inv2 = lam / l2;
      int qg = q0 + wm * 32 + i * 16 + hi * 4 + r;
#pragma unroll
      for (int j = 0; j < 2; ++j) {
        int dh = wn * 32 + j * 16 + fr;
        float o = U1[i][j][r] * inv1 - U2[i][j][r] * inv2;
        ctxb[((size_t)bh * 1024 + qg) * 64 + dh] = f2b(o);
        psum += o; psq += o * o;
      }
    }
  }
#pragma unroll
  for (int m = 1; m < 64; m <<= 1) {
    psum += __shfl_xor(psum, m);
    psq  += __shfl_xor(psq, m);
  }
  if (lane == 0) { pred[wave][0] = psum; pred[wave][1] = psq; }
  __syncthreads();
  if (tid == 0)
    partials[id] = make_float2(pred[0][0] + pred[1][0] + pred[2][0] + pred[3][0],
                               pred[0][1] + pred[1][1] + pred[2][1] + pred[3][1]);
}

// ---------------- gn_apply v2: inline combine (one (b,s) row per block) ----------------
__global__ __launch_bounds__(256) void gn_apply(
    const u16* __restrict__ ctxb, const float2* __restrict__ partials,
    const float* __restrict__ gw, const float* __restrict__ gb,
    u16* __restrict__ normed)
{
  int tid = threadIdx.x;
  int srow = blockIdx.x;            // b*1024 + s
  int b = srow >> 10;
  int h = tid >> 4, qi = tid & 15;
  int bh = b * 16 + h;
  float2 pp = partials[(bh & 7) * 128 + qi * 8 + (bh >> 3)];
  float s = pp.x, ss = pp.y;
#pragma unroll
  for (int o = 1; o < 16; o <<= 1) { s += __shfl_xor(s, o); ss += __shfl_xor(ss, o); }
  float mean = s * (1.f / 65536.f);
  float vinv = rsqrtf(ss * (1.f / 65536.f) - mean * mean + 1e-5f);

  unsigned d  = (unsigned)tid * 4u;     // 0..1020, h == d>>6
  unsigned dh = d & 63u;
  uint2 raw = *(const uint2*)&ctxb[(((size_t)bh) * 1024 + (srow & 1023)) * 64 + dh];
  const u16* rp = (const u16*)&raw;
  float4 g  = *(const float4*)&gw[d];
  float4 be = *(const float4*)&gb[d];
  union { u16 hh[4]; uint2 u2; } p;
  p.hh[0] = f2b(((b2f(rp[0]) - mean) * vinv * g.x + be.x) * 0.8f);
  p.hh[1] = f2b(((b2f(rp[1]) - mean) * vinv * g.y + be.y) * 0.8f);
  p.hh[2] = f2b(((b2f(rp[2]) - mean) * vinv * g.z + be.z) * 0.8f);
  p.hh[3] = f2b(((b2f(rp[3]) - mean) * vinv * g.w + be.w) * 0.8f);
  *(uint2*)&normed[(size_t)srow * 1024 + d] = p.u2;
}

// ---------------- launch ----------------
extern "C" void kernel_launch(void* const* d_in, const int* in_sizes, int n_in,
                              void* d_out, int out_size, void* d_ws, size_t ws_size,
                              hipStream_t stream) {
  (void)in_sizes; (void)n_in; (void)out_size; (void)ws_size;
  const float* x   = (const float*)d_in[0];
  const float* aff = (const float*)d_in[1];
  const float* Wq  = (const float*)d_in[2];
  const float* bq  = (const float*)d_in[3];
  const float* Wk  = (const float*)d_in[4];
  const float* bk  = (const float*)d_in[5];
  const float* Wv  = (const float*)d_in[6];
  const float* bv  = (const float*)d_in[7];
  const float* Wo  = (const float*)d_in[8];
  const float* bo  = (const float*)d_in[9];
  const float* gw  = (const float*)d_in[10];
  const float* gb  = (const float*)d_in[11];
  const float* lam = (const float*)d_in[12];
  float* out = (float*)d_out;

  char* w = (char*)d_ws;
  u16*    xb    = (u16*)(w);
  u16*    Wcat  = (u16*)(w + 8388608);
  u16*    Wob   = (u16*)(w + 18874368);
  float*  bcat  = (float*)(w + 20971520);
  u16*    q1t   = (u16*)(w + 20992000);
  u16*    q2t   = (u16*)(w + 29380608);
  u16*    k1t   = (u16*)(w + 37769216);
  u16*    k2t   = (u16*)(w + 46157824);
  u16*    vtT   = (u16*)(w + 54546432);   // [bh][dh][s] transposed
  float*  logL  = (float*)(w + 62935040);
  float*  ctab  = (float*)(w + 62951424);
  float*  stab  = (float*)(w + 63082496);
  float2* parts = (float2*)(w + 63213568); // 1024 float2
  u16*    ctxb  = (u16*)(w + 63475712);    // bf16 ctx (8.4MB)
  u16*    normed= (u16*)(w + 80253440);

  convert_kernel<<<10245, 256, 0, stream>>>(x, Wq, Wk, Wv, Wo, bq, bk, bv, xb, Wcat, Wob, bcat);
  prep_kernel<<<36, 1024, 0, stream>>>(aff, logL, ctab, stab);
  gemm_nt<0><<<dim3(40, 32), 256, 0, stream>>>(xb, Wcat, bcat, nullptr, q1t, q2t, k1t, k2t, vtT, ctab, stab, 5120);
  attn_fused<<<1024, 256, 0, stream>>>(q1t, q2t, k1t, k2t, vtT, logL, lam, ctxb, parts);
  gn_apply<<<4096, 256, 0, stream>>>(ctxb, parts, gw, gb, normed);
  gemm_nt<1><<<dim3(8, 32), 256, 0, stream>>>(normed, Wob, bo, out, nullptr, nullptr, nullptr, nullptr, nullptr, ctab, stab, 1024);
}

// Round 19
// 159.891 us; speedup vs baseline: 1.4053x; 1.0406x over previous
//
#include <hip/hip_runtime.h>
#include <math.h>

typedef float  f32x4  __attribute__((ext_vector_type(4)));
typedef short  bf16x8 __attribute__((ext_vector_type(8)));
typedef unsigned short u16;

__device__ __forceinline__ u16 f2b(float f) {
  union { float f; unsigned u; } v; v.f = f;
  unsigned r = v.u + 0x7FFFu + ((v.u >> 16) & 1u);
  return (u16)(r >> 16);
}
__device__ __forceinline__ float b2f(u16 h) {
  union { unsigned u; float f; } v; v.u = ((unsigned)h) << 16;
  return v.f;
}

// async global->LDS, 16B per lane; dest = wave-uniform base + lane*16
__device__ __forceinline__ void gl_lds16(const u16* g, u16* l) {
  __builtin_amdgcn_global_load_lds(
      (const __attribute__((address_space(1))) unsigned*)g,
      (__attribute__((address_space(3))) unsigned*)l, 16, 0, 0);
}

// ---------------- fp32 -> bf16 conversion / packing + logL scan + RoPE table --
// blocks [0,10245): convert; [10245,10249): logL scan (b = bid-10245);
// [10249,10377): cos/sin table.
__global__ __launch_bounds__(256) void convert_kernel(
    const float* __restrict__ x,  const float* __restrict__ Wq,
    const float* __restrict__ Wk, const float* __restrict__ Wv,
    const float* __restrict__ Wo, const float* __restrict__ bq,
    const float* __restrict__ bk, const float* __restrict__ bv,
    const float* __restrict__ aff,
    u16* __restrict__ xb, u16* __restrict__ Wcat, u16* __restrict__ Wob,
    float* __restrict__ bcat, float* __restrict__ logL,
    float* __restrict__ ctab, float* __restrict__ stab)
{
  int bid = blockIdx.x;
  if (bid < 10245) {
    long i = ((long)bid * 256 + threadIdx.x) * 4;
    if (i < 10485760L) {
      const float* src; u16* dst; long o;
      if (i < 4194304L)      { src = x;  dst = xb;             o = i; }
      else if (i < 6291456L) { src = Wq; dst = Wcat;           o = i - 4194304L; }
      else if (i < 8388608L) { src = Wk; dst = Wcat + 2097152; o = i - 6291456L; }
      else if (i < 9437184L) { src = Wv; dst = Wcat + 4194304; o = i - 8388608L; }
      else                   { src = Wo; dst = Wob;            o = i - 9437184L; }
      float4 v = *(const float4*)(src + o);
      union { u16 h[4]; uint2 u2; } p;
      p.h[0] = f2b(v.x); p.h[1] = f2b(v.y); p.h[2] = f2b(v.z); p.h[3] = f2b(v.w);
      *(uint2*)(dst + o) = p.u2;
    } else if (i < 10490880L) {
      long j = i - 10485760L;
      const float* src; long o;
      if (j < 2048)      { src = bq; o = j; }
      else if (j < 4096) { src = bk; o = j - 2048; }
      else               { src = bv; o = j - 4096; }
      *(float4*)(bcat + j) = *(const float4*)(src + o);
    }
  } else if (bid < 10249) {
    // 256-thread scan of 1024 elems: 4 per thread + Hillis-Steele over totals
    __shared__ float sh[256];
    int b = bid - 10245, t = threadIdx.x;
    float c0, c1, c2, c3;
    {
      int i0 = 4 * t;
      float l0 = (i0 == 0) ? 0.f : log2f(aff[b * 1023 + i0 - 1]);
      float l1 = log2f(aff[b * 1023 + i0]);
      float l2 = log2f(aff[b * 1023 + i0 + 1]);
      float l3 = log2f(aff[b * 1023 + i0 + 2]);
      c0 = l0; c1 = c0 + l1; c2 = c1 + l2; c3 = c2 + l3;
    }
    sh[t] = c3;
    __syncthreads();
    for (int off = 1; off < 256; off <<= 1) {
      float add = (t >= off) ? sh[t - off] : 0.f;
      __syncthreads();
      sh[t] += add;
      __syncthreads();
    }
    float base = sh[t] - c3;   // exclusive prefix of thread totals
    float* Lp = logL + b * 1024 + 4 * t;
    Lp[0] = base + c0; Lp[1] = base + c1; Lp[2] = base + c2; Lp[3] = base + c3;
  } else {
    int idx = (bid - 10249) * 256 + threadIdx.x;   // 0..32767
    int s = idx >> 5, i = idx & 31;
    float freq = expf(-(float)i * (9.210340371976184f / 32.f));  // 10000^(-i/32)
    float ang = (float)s * freq;
    ctab[idx] = cosf(ang);
    stab[idx] = sinf(ang);
  }
}

// ---------------- MFMA NT GEMM v3: BK=64, XOR-swizzled LDS (unchanged r18) ----
template<int EPI>
__global__ __launch_bounds__(256) void gemm_nt(
    const u16* __restrict__ A, const u16* __restrict__ Bw,
    const float* __restrict__ bias, float* __restrict__ outF,
    u16* __restrict__ q1t, u16* __restrict__ q2t,
    u16* __restrict__ k1t, u16* __restrict__ k2t, u16* __restrict__ vtT,
    const float* __restrict__ ctab, const float* __restrict__ stab,
    int N)
{
  const int K = 1024;
  __shared__ u16 As[128 * 64];
  __shared__ u16 Bs[128 * 64];
  int tid  = threadIdx.x;
  int lane = tid & 63, wave = tid >> 6;
  int wm = wave >> 1, wn = wave & 1;
  int m0 = blockIdx.y * 128, n0 = blockIdx.x * 128;
  int fr = lane & 15, hi = lane >> 4;

  int ac_r[4], ac_sb[4], cb_[4];
#pragma unroll
  for (int p = 0; p < 4; ++p) {
    int c = p * 256 + wave * 64 + lane;
    ac_r[p]  = c >> 3;
    ac_sb[p] = (c & 7) ^ (ac_r[p] & 7);
    cb_[p]   = (p * 256 + wave * 64) * 8;
  }

  f32x4 acc[4][4];
#pragma unroll
  for (int i = 0; i < 4; ++i)
#pragma unroll
    for (int j = 0; j < 4; ++j) acc[i][j] = 0.0f;

  for (int kk0 = 0; kk0 < K; kk0 += 64) {
    __syncthreads();
#pragma unroll
    for (int p = 0; p < 4; ++p) {
      gl_lds16(A  + (size_t)(m0 + ac_r[p]) * K + kk0 + ac_sb[p] * 8, &As[cb_[p]]);
      gl_lds16(Bw + (size_t)(n0 + ac_r[p]) * K + kk0 + ac_sb[p] * 8, &Bs[cb_[p]]);
    }
    __syncthreads();
#pragma unroll
    for (int ks = 0; ks < 2; ++ks) {
      bf16x8 af[4], bfv[4];
#pragma unroll
      for (int f = 0; f < 4; ++f) {
        int ra = wm * 64 + f * 16 + fr;
        int rb = wn * 64 + f * 16 + fr;
        int cba = (ks * 4 + hi) ^ (ra & 7);
        int cbb = (ks * 4 + hi) ^ (rb & 7);
        af[f]  = *(const bf16x8*)&As[ra * 64 + (cba << 3)];
        bfv[f] = *(const bf16x8*)&Bs[rb * 64 + (cbb << 3)];
      }
#pragma unroll
      for (int i = 0; i < 4; ++i)
#pragma unroll
        for (int j = 0; j < 4; ++j)
          acc[i][j] = __builtin_amdgcn_mfma_f32_16x16x32_bf16(af[i], bfv[j], acc[i][j], 0, 0, 0);
    }
  }

  int rg = lane >> 4;
  if (EPI == 0) {
    if (n0 < 4096) {
      u16* dst; int base;
      if (n0 < 1024)      { dst = q1t; base = 0; }
      else if (n0 < 2048) { dst = q2t; base = 1024; }
      else if (n0 < 3072) { dst = k1t; base = 2048; }
      else                { dst = k2t; base = 3072; }
      float qs = (n0 < 2048) ? 0.18033688011112042f : 1.0f;   // 0.125*log2e
#pragma unroll
      for (int i = 0; i < 4; ++i) {
#pragma unroll
        for (int e = 0; e < 4; ++e) {
          int m = m0 + wm * 64 + i * 16 + rg * 4 + e;
          int b = m >> 10, s = m & 1023;
#pragma unroll
          for (int j = 0; j < 2; ++j) {
            int n_lo = n0 + wn * 64 + j * 16 + fr;
            int feat = n_lo - base;
            int h = feat >> 6, dh = feat & 63;   // dh < 32
            float a1 = acc[i][j][e]     + bias[n_lo];
            float a2 = acc[i][j + 2][e] + bias[n_lo + 32];
            float cs = ctab[s * 32 + dh], sn = stab[s * 32 + dh];
            float r0 = (a1 * cs - a2 * sn) * qs;
            float r1 = (a1 * sn + a2 * cs) * qs;
            unsigned pk;
            asm("v_cvt_pk_bf16_f32 %0, %1, %2" : "=v"(pk) : "v"(r0), "v"(r1));
            size_t rowb = ((size_t)(b * 16 + h) * 1024 + s) * 64;
            *(unsigned*)&dst[rowb + 2 * dh] = pk;   // permuted: (dh,dh+32)->(2dh,2dh+1)
          }
        }
      }
    } else {
      // v tensor: TRANSPOSED store [bh][dh][s] (unpermuted)
#pragma unroll
      for (int i = 0; i < 4; ++i) {
        int mbase = m0 + wm * 64 + i * 16 + rg * 4;
        int b = mbase >> 10, s0 = mbase & 1023;
#pragma unroll
        for (int j = 0; j < 4; ++j) {
          int n = n0 + wn * 64 + j * 16 + fr;
          int feat = n - 4096;
          int h = feat >> 6, dh = feat & 63;
          float bv = bias[n];
          union { u16 hh[4]; uint2 u2; } p;
#pragma unroll
          for (int e = 0; e < 4; ++e) p.hh[e] = f2b(acc[i][j][e] + bv);
          *(uint2*)&vtT[((size_t)(b * 16 + h) * 64 + dh) * 1024 + s0] = p.u2;
        }
      }
    }
  } else {
#pragma unroll
    for (int i = 0; i < 4; ++i)
#pragma unroll
      for (int j = 0; j < 4; ++j)
#pragma unroll
        for (int e = 0; e < 4; ++e) {
          int m = m0 + wm * 64 + i * 16 + rg * 4 + e;
          int n = n0 + wn * 64 + j * 16 + fr;
          outF[(size_t)m * N + n] = acc[i][j][e] + bias[n];
        }
  }
}

// ---------------- fused MFMA attention v12 ----------------
// = r18 + skip threshold -40 -> -24 (rigorous: dropped P-mass <= 64*2^(3.3-24)
// relative ~ 1.3e-6; bound computed from actual logL endpoints, so any data
// without decay falls back to full compute).
__global__ __launch_bounds__(256) void attn_fused(
    const u16* __restrict__ q1t, const u16* __restrict__ q2t,
    const u16* __restrict__ k1t, const u16* __restrict__ k2t,
    const u16* __restrict__ vtT,
    const float* __restrict__ logL, const float* __restrict__ lamp,
    u16* __restrict__ ctxb, float2* __restrict__ partials)
{
  __shared__ u16 K1s[64][72];   // K1 during QK^T, P1 during PV
  __shared__ u16 K2s[64][72];   // K2 during QK^T, P2 during PV
  __shared__ u16 Vts[64][72];   // V^T [dh][k], k-blocks XOR-swizzled by (dh>>3)&7
  __shared__ float lred1[2][2][32];
  __shared__ float lred2[2][2][32];
  __shared__ float pred[4][2];

  int tid  = threadIdx.x;
  int lane = tid & 63, wave = tid >> 6;
  int wm = wave >> 1, wn = wave & 1;
  int id = blockIdx.x;
  int bh = (id & 7) * 8 + (id >> 7);        // XCD-grouped: 8 bh per XCD (L2-fit)
  int q0 = ((id >> 3) & 15) * 64;
  int b = bh >> 4;
  int fr = lane & 15, hi = lane >> 4;

  bf16x8 qf1[2][2], qf2[2][2];
#pragma unroll
  for (int i = 0; i < 2; ++i)
#pragma unroll
    for (int ks = 0; ks < 2; ++ks) {
      size_t off = ((size_t)bh * 1024 + q0 + wm * 32 + i * 16 + fr) * 64 + ks * 32 + hi * 8;
      qf1[i][ks] = *(const bf16x8*)(q1t + off);
      qf2[i][ks] = *(const bf16x8*)(q2t + off);
    }
  float Lq[2][4];
#pragma unroll
  for (int i = 0; i < 2; ++i)
#pragma unroll
    for (int r = 0; r < 4; ++r)
      Lq[i][r] = logL[b * 1024 + q0 + wm * 32 + i * 16 + hi * 4 + r];

  float Lq_top = logL[b * 1024 + q0];
  float Lq_bot = logL[b * 1024 + q0 + 63];

  float lacc1[2][4], lacc2[2][4];
  f32x4 U1[2][2], U2[2][2];
#pragma unroll
  for (int i = 0; i < 2; ++i)
#pragma unroll
    for (int r = 0; r < 4; ++r) { lacc1[i][r] = 0.f; lacc2[i][r] = 0.f; }
#pragma unroll
  for (int i = 0; i < 2; ++i)
#pragma unroll
    for (int j = 0; j < 2; ++j) { U1[i][j] = 0.f; U2[i][j] = 0.f; }

  int sr = tid >> 2, sc0 = (tid & 3) * 16;
  int swz = (sr >> 3) & 7;
  int blk0 = ((sc0 >> 3) ^ swz) << 3;
  int blk1 = (((sc0 >> 3) + 1) ^ swz) << 3;

  unsigned a1base = (unsigned)(size_t)&K1s[wm * 32 + hi * 4][wn * 32 + fr];
  unsigned a2base = (unsigned)(size_t)&K2s[wm * 32 + hi * 4][wn * 32 + fr];

  for (int kt = 0; kt < 16; ++kt) {
    // exact tile-pair mask bound (block-uniform)
    int ktop = kt * 64;
    float maxc;
    if (ktop > q0 + 63)      maxc = logL[b * 1024 + ktop] - Lq_bot;
    else if (ktop + 63 < q0) maxc = Lq_top - logL[b * 1024 + ktop + 63];
    else                     maxc = 0.f;
    bool far = (maxc < -24.f);

    __syncthreads();   // (1) prev tile's LDS reads done
    size_t gb = ((size_t)bh * 1024 + kt * 64 + sr) * 64 + sc0;
    bf16x8 a0 = *(const bf16x8*)(k1t + gb), a1 = *(const bf16x8*)(k1t + gb + 8);
    bf16x8 b0 = *(const bf16x8*)(k2t + gb), b1 = *(const bf16x8*)(k2t + gb + 8);
    *(bf16x8*)&K1s[sr][sc0] = a0;  *(bf16x8*)&K1s[sr][sc0 + 8] = a1;
    *(bf16x8*)&K2s[sr][sc0] = b0;  *(bf16x8*)&K2s[sr][sc0 + 8] = b1;
    if (!far) {
      size_t gv = (size_t)bh * 65536 + (size_t)sr * 1024 + kt * 64 + sc0;
      bf16x8 v0 = *(const bf16x8*)(vtT + gv), v1 = *(const bf16x8*)(vtT + gv + 8);
      *(bf16x8*)&Vts[sr][blk0] = v0;  *(bf16x8*)&Vts[sr][blk1] = v1;
    }
    __syncthreads();   // (2) stage complete

    // ---- QK^T (always: denominators are unmasked) ----
    f32x4 S1[2][2], S2[2][2];
#pragma unroll
    for (int i = 0; i < 2; ++i)
#pragma unroll
      for (int j = 0; j < 2; ++j) { S1[i][j] = 0.f; S2[i][j] = 0.f; }
    __builtin_amdgcn_s_setprio(1);
#pragma unroll
    for (int ks = 0; ks < 2; ++ks) {
      bf16x8 kf1[2], kf2[2];
#pragma unroll
      for (int j = 0; j < 2; ++j) {
        kf1[j] = *(const bf16x8*)&K1s[wn * 32 + j * 16 + fr][ks * 32 + hi * 8];
        kf2[j] = *(const bf16x8*)&K2s[wn * 32 + j * 16 + fr][ks * 32 + hi * 8];
      }
#pragma unroll
      for (int i = 0; i < 2; ++i)
#pragma unroll
        for (int j = 0; j < 2; ++j) {
          S1[i][j] = __builtin_amdgcn_mfma_f32_16x16x32_bf16(qf1[i][ks], kf1[j], S1[i][j], 0, 0, 0);
          S2[i][j] = __builtin_amdgcn_mfma_f32_16x16x32_bf16(qf2[i][ks], kf2[j], S2[i][j], 0, 0, 0);
        }
    }
    __builtin_amdgcn_s_setprio(0);

    if (!far) {
      float Ltl[2];
#pragma unroll
      for (int j = 0; j < 2; ++j) Ltl[j] = logL[b * 1024 + kt * 64 + wn * 32 + j * 16 + fr];
      __syncthreads();   // (3) all K reads done -> K-space reusable as P

      // ---- exponentials (log2 domain) + packed P write ----
#pragma unroll
      for (int i = 0; i < 2; ++i) {
#pragma unroll
        for (int r = 0; r < 4; ++r) {
          float lq = Lq[i][r];
          float e1j[2], e2j[2], p1j[2], p2j[2];
#pragma unroll
          for (int j = 0; j < 2; ++j) {
            float nd = -fabsf(Ltl[j] - lq);
            float t1, t2, ec;
            asm("v_exp_f32 %0, %1" : "=v"(t1) : "v"(S1[i][j][r]));
            asm("v_exp_f32 %0, %1" : "=v"(t2) : "v"(S2[i][j][r]));
            asm("v_exp_f32 %0, %1" : "=v"(ec) : "v"(nd));
            e1j[j] = t1; e2j[j] = t2;
            p1j[j] = t1 * ec; p2j[j] = t2 * ec;
          }
          lacc1[i][r] += e1j[0] + e1j[1];
          lacc2[i][r] += e2j[0] + e2j[1];
          unsigned off = (unsigned)((i * 16 + r) * 144);
          unsigned ad1 = a1base + off, ad2 = a2base + off;
          unsigned pk1, pk2;
          asm("v_cvt_pk_bf16_f32 %0, %1, %2" : "=v"(pk1) : "v"(p1j[0]), "v"(p1j[1]));
          asm("v_cvt_pk_bf16_f32 %0, %1, %2" : "=v"(pk2) : "v"(p2j[0]), "v"(p2j[1]));
          asm volatile("ds_write_b16 %0, %1\n\tds_write_b16_d16_hi %0, %1 offset:32"
                       :: "v"(ad1), "v"(pk1) : "memory");
          asm volatile("ds_write_b16 %0, %1\n\tds_write_b16_d16_hi %0, %1 offset:32"
                       :: "v"(ad2), "v"(pk2) : "memory");
        }
      }
      __syncthreads();   // (4) P complete

      // ---- PV: U += P * V (P in K1s/K2s, V^T in Vts) ----
      __builtin_amdgcn_s_setprio(1);
#pragma unroll
      for (int ks = 0; ks < 2; ++ks) {
        bf16x8 pa1[2], pa2[2], vb[2];
#pragma unroll
        for (int i = 0; i < 2; ++i) {
          pa1[i] = *(const bf16x8*)&K1s[wm * 32 + i * 16 + fr][ks * 32 + hi * 8];
          pa2[i] = *(const bf16x8*)&K2s[wm * 32 + i * 16 + fr][ks * 32 + hi * 8];
        }
#pragma unroll
        for (int j = 0; j < 2; ++j) {
          int row = wn * 32 + j * 16 + fr;
          int kbb = (ks * 4 + hi) ^ ((row >> 3) & 7);
          vb[j] = *(const bf16x8*)&Vts[row][kbb << 3];
        }
#pragma unroll
        for (int i = 0; i < 2; ++i)
#pragma unroll
          for (int j = 0; j < 2; ++j) {
            U1[i][j] = __builtin_amdgcn_mfma_f32_16x16x32_bf16(pa1[i], vb[j], U1[i][j], 0, 0, 0);
            U2[i][j] = __builtin_amdgcn_mfma_f32_16x16x32_bf16(pa2[i], vb[j], U2[i][j], 0, 0, 0);
          }
      }
      __builtin_amdgcn_s_setprio(0);
    } else {
      // far tile: denominators only (exps only, no mask, no P, no PV, no barriers)
#pragma unroll
      for (int i = 0; i < 2; ++i) {
#pragma unroll
        for (int r = 0; r < 4; ++r) {
          float t1a, t1b, t2a, t2b;
          asm("v_exp_f32 %0, %1" : "=v"(t1a) : "v"(S1[i][0][r]));
          asm("v_exp_f32 %0, %1" : "=v"(t1b) : "v"(S1[i][1][r]));
          asm("v_exp_f32 %0, %1" : "=v"(t2a) : "v"(S2[i][0][r]));
          asm("v_exp_f32 %0, %1" : "=v"(t2b) : "v"(S2[i][1][r]));
          lacc1[i][r] += t1a + t1b;
          lacc2[i][r] += t2a + t2b;
        }
      }
    }
  }

  // ---- denominator: intra-wave reduce over fr, then cross-wave over wn ----
#pragma unroll
  for (int i = 0; i < 2; ++i)
#pragma unroll
    for (int r = 0; r < 4; ++r) {
#pragma unroll
      for (int m = 1; m < 16; m <<= 1) {
        lacc1[i][r] += __shfl_xor(lacc1[i][r], m);
        lacc2[i][r] += __shfl_xor(lacc2[i][r], m);
      }
    }
  if (fr == 0) {
#pragma unroll
    for (int i = 0; i < 2; ++i)
#pragma unroll
      for (int r = 0; r < 4; ++r) {
        int rl = i * 16 + hi * 4 + r;
        lred1[wn][wm][rl] = lacc1[i][r];
        lred2[wn][wm][rl] = lacc2[i][r];
      }
  }
  __syncthreads();
  float lam = lamp[0];

  // ---- epilogue: ctx(bf16) = U1/l1 - lam*U2/l2, plus block partial Sum/SumSq ----
  float psum = 0.f, psq = 0.f;
#pragma unroll
  for (int i = 0; i < 2; ++i) {
#pragma unroll
    for (int r = 0; r < 4; ++r) {
      int rl = i * 16 + hi * 4 + r;
      float l1 = lred1[0][wm][rl] + lred1[1][wm][rl];
      float l2 = lred2[0][wm][rl] + lred2[1][wm][rl];
      float inv1 = 1.f / l1;
      float inv2 = lam / l2;
      int qg = q0 + wm * 32 + i * 16 + hi * 4 + r;
#pragma unroll
      for (int j = 0; j < 2; ++j) {
        int dh = wn * 32 + j * 16 + fr;
        float o = U1[i][j][r] * inv1 - U2[i][j][r] * inv2;
        ctxb[((size_t)bh * 1024 + qg) * 64 + dh] = f2b(o);
        psum += o; psq += o * o;
      }
    }
  }
#pragma unroll
  for (int m = 1; m < 64; m <<= 1) {
    psum += __shfl_xor(psum, m);
    psq  += __shfl_xor(psq, m);
  }
  if (lane == 0) { pred[wave][0] = psum; pred[wave][1] = psq; }
  __syncthreads();
  if (tid == 0)
    partials[id] = make_float2(pred[0][0] + pred[1][0] + pred[2][0] + pred[3][0],
                               pred[0][1] + pred[1][1] + pred[2][1] + pred[3][1]);
}

// ---------------- gn_apply v2: inline combine (one (b,s) row per block) ----------------
__global__ __launch_bounds__(256) void gn_apply(
    const u16* __restrict__ ctxb, const float2* __restrict__ partials,
    const float* __restrict__ gw, const float* __restrict__ gb,
    u16* __restrict__ normed)
{
  int tid = threadIdx.x;
  int srow = blockIdx.x;            // b*1024 + s
  int b = srow >> 10;
  int h = tid >> 4, qi = tid & 15;
  int bh = b * 16 + h;
  float2 pp = partials[(bh & 7) * 128 + qi * 8 + (bh >> 3)];
  float s = pp.x, ss = pp.y;
#pragma unroll
  for (int o = 1; o < 16; o <<= 1) { s += __shfl_xor(s, o); ss += __shfl_xor(ss, o); }
  float mean = s * (1.f / 65536.f);
  float vinv = rsqrtf(ss * (1.f / 65536.f) - mean * mean + 1e-5f);

  unsigned d  = (unsigned)tid * 4u;     // 0..1020, h == d>>6
  unsigned dh = d & 63u;
  uint2 raw = *(const uint2*)&ctxb[(((size_t)bh) * 1024 + (srow & 1023)) * 64 + dh];
  const u16* rp = (const u16*)&raw;
  float4 g  = *(const float4*)&gw[d];
  float4 be = *(const float4*)&gb[d];
  union { u16 hh[4]; uint2 u2; } p;
  p.hh[0] = f2b(((b2f(rp[0]) - mean) * vinv * g.x + be.x) * 0.8f);
  p.hh[1] = f2b(((b2f(rp[1]) - mean) * vinv * g.y + be.y) * 0.8f);
  p.hh[2] = f2b(((b2f(rp[2]) - mean) * vinv * g.z + be.z) * 0.8f);
  p.hh[3] = f2b(((b2f(rp[3]) - mean) * vinv * g.w + be.w) * 0.8f);
  *(uint2*)&normed[(size_t)srow * 1024 + d] = p.u2;
}

// ---------------- launch ----------------
extern "C" void kernel_launch(void* const* d_in, const int* in_sizes, int n_in,
                              void* d_out, int out_size, void* d_ws, size_t ws_size,
                              hipStream_t stream) {
  (void)in_sizes; (void)n_in; (void)out_size; (void)ws_size;
  const float* x   = (const float*)d_in[0];
  const float* aff = (const float*)d_in[1];
  const float* Wq  = (const float*)d_in[2];
  const float* bq  = (const float*)d_in[3];
  const float* Wk  = (const float*)d_in[4];
  const float* bk  = (const float*)d_in[5];
  const float* Wv  = (const float*)d_in[6];
  const float* bv  = (const float*)d_in[7];
  const float* Wo  = (const float*)d_in[8];
  const float* bo  = (const float*)d_in[9];
  const float* gw  = (const float*)d_in[10];
  const float* gb  = (const float*)d_in[11];
  const float* lam = (const float*)d_in[12];
  float* out = (float*)d_out;

  char* w = (char*)d_ws;
  u16*    xb    = (u16*)(w);
  u16*    Wcat  = (u16*)(w + 8388608);
  u16*    Wob   = (u16*)(w + 18874368);
  float*  bcat  = (float*)(w + 20971520);
  u16*    q1t   = (u16*)(w + 20992000);
  u16*    q2t   = (u16*)(w + 29380608);
  u16*    k1t   = (u16*)(w + 37769216);
  u16*    k2t   = (u16*)(w + 46157824);
  u16*    vtT   = (u16*)(w + 54546432);   // [bh][dh][s] transposed
  float*  logL  = (float*)(w + 62935040);
  float*  ctab  = (float*)(w + 62951424);
  float*  stab  = (float*)(w + 63082496);
  float2* parts = (float2*)(w + 63213568); // 1024 float2
  u16*    ctxb  = (u16*)(w + 63475712);    // bf16 ctx (8.4MB)
  u16*    normed= (u16*)(w + 80253440);

  convert_kernel<<<10377, 256, 0, stream>>>(x, Wq, Wk, Wv, Wo, bq, bk, bv, aff,
                                            xb, Wcat, Wob, bcat, logL, ctab, stab);
  gemm_nt<0><<<dim3(40, 32), 256, 0, stream>>>(xb, Wcat, bcat, nullptr, q1t, q2t, k1t, k2t, vtT, ctab, stab, 5120);
  attn_fused<<<1024, 256, 0, stream>>>(q1t, q2t, k1t, k2t, vtT, logL, lam, ctxb, parts);
  gn_apply<<<4096, 256, 0, stream>>>(ctxb, parts, gw, gb, normed);
  gemm_nt<1><<<dim3(8, 32), 256, 0, stream>>>(normed, Wob, bo, out, nullptr, nullptr, nullptr, nullptr, nullptr, ctab, stab, 1024);
}

// Round 20
// 158.822 us; speedup vs baseline: 1.4147x; 1.0067x over previous
//
#include <hip/hip_runtime.h>
#include <math.h>

typedef float  f32x4  __attribute__((ext_vector_type(4)));
typedef short  bf16x8 __attribute__((ext_vector_type(8)));
typedef unsigned short u16;

__device__ __forceinline__ u16 f2b(float f) {
  union { float f; unsigned u; } v; v.f = f;
  unsigned r = v.u + 0x7FFFu + ((v.u >> 16) & 1u);
  return (u16)(r >> 16);
}
__device__ __forceinline__ float b2f(u16 h) {
  union { unsigned u; float f; } v; v.u = ((unsigned)h) << 16;
  return v.f;
}

// async global->LDS, 16B per lane; dest = wave-uniform base + lane*16
__device__ __forceinline__ void gl_lds16(const u16* g, u16* l) {
  __builtin_amdgcn_global_load_lds(
      (const __attribute__((address_space(1))) unsigned*)g,
      (__attribute__((address_space(3))) unsigned*)l, 16, 0, 0);
}

// ---------------- fp32 -> bf16 conversion / packing + logL scan + RoPE table --
__global__ __launch_bounds__(256) void convert_kernel(
    const float* __restrict__ x,  const float* __restrict__ Wq,
    const float* __restrict__ Wk, const float* __restrict__ Wv,
    const float* __restrict__ Wo, const float* __restrict__ bq,
    const float* __restrict__ bk, const float* __restrict__ bv,
    const float* __restrict__ aff,
    u16* __restrict__ xb, u16* __restrict__ Wcat, u16* __restrict__ Wob,
    float* __restrict__ bcat, float* __restrict__ logL,
    float* __restrict__ ctab, float* __restrict__ stab)
{
  int bid = blockIdx.x;
  if (bid < 10245) {
    long i = ((long)bid * 256 + threadIdx.x) * 4;
    if (i < 10485760L) {
      const float* src; u16* dst; long o;
      if (i < 4194304L)      { src = x;  dst = xb;             o = i; }
      else if (i < 6291456L) { src = Wq; dst = Wcat;           o = i - 4194304L; }
      else if (i < 8388608L) { src = Wk; dst = Wcat + 2097152; o = i - 6291456L; }
      else if (i < 9437184L) { src = Wv; dst = Wcat + 4194304; o = i - 8388608L; }
      else                   { src = Wo; dst = Wob;            o = i - 9437184L; }
      float4 v = *(const float4*)(src + o);
      union { u16 h[4]; uint2 u2; } p;
      p.h[0] = f2b(v.x); p.h[1] = f2b(v.y); p.h[2] = f2b(v.z); p.h[3] = f2b(v.w);
      *(uint2*)(dst + o) = p.u2;
    } else if (i < 10490880L) {
      long j = i - 10485760L;
      const float* src; long o;
      if (j < 2048)      { src = bq; o = j; }
      else if (j < 4096) { src = bk; o = j - 2048; }
      else               { src = bv; o = j - 4096; }
      *(float4*)(bcat + j) = *(const float4*)(src + o);
    }
  } else if (bid < 10249) {
    __shared__ float sh[256];
    int b = bid - 10245, t = threadIdx.x;
    float c0, c1, c2, c3;
    {
      int i0 = 4 * t;
      float l0 = (i0 == 0) ? 0.f : log2f(aff[b * 1023 + i0 - 1]);
      float l1 = log2f(aff[b * 1023 + i0]);
      float l2 = log2f(aff[b * 1023 + i0 + 1]);
      float l3 = log2f(aff[b * 1023 + i0 + 2]);
      c0 = l0; c1 = c0 + l1; c2 = c1 + l2; c3 = c2 + l3;
    }
    sh[t] = c3;
    __syncthreads();
    for (int off = 1; off < 256; off <<= 1) {
      float add = (t >= off) ? sh[t - off] : 0.f;
      __syncthreads();
      sh[t] += add;
      __syncthreads();
    }
    float base = sh[t] - c3;
    float* Lp = logL + b * 1024 + 4 * t;
    Lp[0] = base + c0; Lp[1] = base + c1; Lp[2] = base + c2; Lp[3] = base + c3;
  } else {
    int idx = (bid - 10249) * 256 + threadIdx.x;   // 0..32767
    int s = idx >> 5, i = idx & 31;
    float freq = expf(-(float)i * (9.210340371976184f / 32.f));
    float ang = (float)s * freq;
    ctab[idx] = cosf(ang);
    stab[idx] = sinf(ang);
  }
}

// ---------------- MFMA NT GEMM (QKV, unchanged r19) ----------------
template<int EPI>
__global__ __launch_bounds__(256) void gemm_nt(
    const u16* __restrict__ A, const u16* __restrict__ Bw,
    const float* __restrict__ bias, float* __restrict__ outF,
    u16* __restrict__ q1t, u16* __restrict__ q2t,
    u16* __restrict__ k1t, u16* __restrict__ k2t, u16* __restrict__ vtT,
    const float* __restrict__ ctab, const float* __restrict__ stab,
    int N)
{
  const int K = 1024;
  __shared__ u16 As[128 * 64];
  __shared__ u16 Bs[128 * 64];
  int tid  = threadIdx.x;
  int lane = tid & 63, wave = tid >> 6;
  int wm = wave >> 1, wn = wave & 1;
  int m0 = blockIdx.y * 128, n0 = blockIdx.x * 128;
  int fr = lane & 15, hi = lane >> 4;

  int ac_r[4], ac_sb[4], cb_[4];
#pragma unroll
  for (int p = 0; p < 4; ++p) {
    int c = p * 256 + wave * 64 + lane;
    ac_r[p]  = c >> 3;
    ac_sb[p] = (c & 7) ^ (ac_r[p] & 7);
    cb_[p]   = (p * 256 + wave * 64) * 8;
  }

  f32x4 acc[4][4];
#pragma unroll
  for (int i = 0; i < 4; ++i)
#pragma unroll
    for (int j = 0; j < 4; ++j) acc[i][j] = 0.0f;

  for (int kk0 = 0; kk0 < K; kk0 += 64) {
    __syncthreads();
#pragma unroll
    for (int p = 0; p < 4; ++p) {
      gl_lds16(A  + (size_t)(m0 + ac_r[p]) * K + kk0 + ac_sb[p] * 8, &As[cb_[p]]);
      gl_lds16(Bw + (size_t)(n0 + ac_r[p]) * K + kk0 + ac_sb[p] * 8, &Bs[cb_[p]]);
    }
    __syncthreads();
#pragma unroll
    for (int ks = 0; ks < 2; ++ks) {
      bf16x8 af[4], bfv[4];
#pragma unroll
      for (int f = 0; f < 4; ++f) {
        int ra = wm * 64 + f * 16 + fr;
        int rb = wn * 64 + f * 16 + fr;
        int cba = (ks * 4 + hi) ^ (ra & 7);
        int cbb = (ks * 4 + hi) ^ (rb & 7);
        af[f]  = *(const bf16x8*)&As[ra * 64 + (cba << 3)];
        bfv[f] = *(const bf16x8*)&Bs[rb * 64 + (cbb << 3)];
      }
#pragma unroll
      for (int i = 0; i < 4; ++i)
#pragma unroll
        for (int j = 0; j < 4; ++j)
          acc[i][j] = __builtin_amdgcn_mfma_f32_16x16x32_bf16(af[i], bfv[j], acc[i][j], 0, 0, 0);
    }
  }

  int rg = lane >> 4;
  if (EPI == 0) {
    if (n0 < 4096) {
      u16* dst; int base;
      if (n0 < 1024)      { dst = q1t; base = 0; }
      else if (n0 < 2048) { dst = q2t; base = 1024; }
      else if (n0 < 3072) { dst = k1t; base = 2048; }
      else                { dst = k2t; base = 3072; }
      float qs = (n0 < 2048) ? 0.18033688011112042f : 1.0f;   // 0.125*log2e
#pragma unroll
      for (int i = 0; i < 4; ++i) {
#pragma unroll
        for (int e = 0; e < 4; ++e) {
          int m = m0 + wm * 64 + i * 16 + rg * 4 + e;
          int b = m >> 10, s = m & 1023;
#pragma unroll
          for (int j = 0; j < 2; ++j) {
            int n_lo = n0 + wn * 64 + j * 16 + fr;
            int feat = n_lo - base;
            int h = feat >> 6, dh = feat & 63;   // dh < 32
            float a1 = acc[i][j][e]     + bias[n_lo];
            float a2 = acc[i][j + 2][e] + bias[n_lo + 32];
            float cs = ctab[s * 32 + dh], sn = stab[s * 32 + dh];
            float r0 = (a1 * cs - a2 * sn) * qs;
            float r1 = (a1 * sn + a2 * cs) * qs;
            unsigned pk;
            asm("v_cvt_pk_bf16_f32 %0, %1, %2" : "=v"(pk) : "v"(r0), "v"(r1));
            size_t rowb = ((size_t)(b * 16 + h) * 1024 + s) * 64;
            *(unsigned*)&dst[rowb + 2 * dh] = pk;   // permuted: (dh,dh+32)->(2dh,2dh+1)
          }
        }
      }
    } else {
      // v tensor: TRANSPOSED store [bh][dh][s]
#pragma unroll
      for (int i = 0; i < 4; ++i) {
        int mbase = m0 + wm * 64 + i * 16 + rg * 4;
        int b = mbase >> 10, s0 = mbase & 1023;
#pragma unroll
        for (int j = 0; j < 4; ++j) {
          int n = n0 + wn * 64 + j * 16 + fr;
          int feat = n - 4096;
          int h = feat >> 6, dh = feat & 63;
          float bv = bias[n];
          union { u16 hh[4]; uint2 u2; } p;
#pragma unroll
          for (int e = 0; e < 4; ++e) p.hh[e] = f2b(acc[i][j][e] + bv);
          *(uint2*)&vtT[((size_t)(b * 16 + h) * 64 + dh) * 1024 + s0] = p.u2;
        }
      }
    }
  } else {
#pragma unroll
    for (int i = 0; i < 4; ++i)
#pragma unroll
      for (int j = 0; j < 4; ++j)
#pragma unroll
        for (int e = 0; e < 4; ++e) {
          int m = m0 + wm * 64 + i * 16 + rg * 4 + e;
          int n = n0 + wn * 64 + j * 16 + fr;
          outF[(size_t)m * N + n] = acc[i][j][e] + bias[n];
        }
  }
}

// ---------------- output GEMM with FUSED GroupNorm A-staging ----------------
// out = (GN(ctx)*gw+gb)*0.8 @ Wo^T + bo. A-tile rows lie in one batch b
// (m0 multiple of 128 < 1024-aligned) -> 16 (mean,vinv) combined in prologue.
// Per column: A = v*acol + bcol, acol = vinv*g*0.8, bcol = 0.8*be - mean*acol.
// A staged to the SAME linear-chunk XOR layout gl_lds produced; B via gl_lds.
__global__ __launch_bounds__(256) void gemm_out(
    const u16* __restrict__ ctxb, const u16* __restrict__ Bw,
    const float2* __restrict__ partials,
    const float* __restrict__ gw, const float* __restrict__ gb,
    const float* __restrict__ bias, float* __restrict__ outF)
{
  const int K = 1024, N = 1024;
  __shared__ u16 As[128 * 64];
  __shared__ u16 Bs[128 * 64];
  __shared__ float acol[1024];
  __shared__ float bcol[1024];
  __shared__ float2 mvs[16];

  int tid  = threadIdx.x;
  int lane = tid & 63, wave = tid >> 6;
  int wm = wave >> 1, wn = wave & 1;
  int m0 = blockIdx.y * 128, n0 = blockIdx.x * 128;
  int fr = lane & 15, hi = lane >> 4;
  int b = m0 >> 10;

  // ---- prologue: combine partials -> (mean, vinv) for this b's 16 heads ----
  {
    int h = tid >> 4, qi = tid & 15;
    int bh = b * 16 + h;
    float2 pp = partials[(bh & 7) * 128 + qi * 8 + (bh >> 3)];
    float s = pp.x, ss = pp.y;
#pragma unroll
    for (int o = 1; o < 16; o <<= 1) { s += __shfl_xor(s, o); ss += __shfl_xor(ss, o); }
    if (qi == 0) {
      float mean = s * (1.f / 65536.f);
      float vinv = rsqrtf(ss * (1.f / 65536.f) - mean * mean + 1e-5f);
      mvs[h] = make_float2(mean, vinv);
    }
  }
  __syncthreads();
  {
    int col = tid * 4;
    float4 g  = *(const float4*)&gw[col];
    float4 be = *(const float4*)&gb[col];
    float2 mv = mvs[col >> 6];
    float a0 = mv.y * g.x * 0.8f, a1 = mv.y * g.y * 0.8f;
    float a2 = mv.y * g.z * 0.8f, a3 = mv.y * g.w * 0.8f;
    acol[col+0] = a0; bcol[col+0] = 0.8f * be.x - mv.x * a0;
    acol[col+1] = a1; bcol[col+1] = 0.8f * be.y - mv.x * a1;
    acol[col+2] = a2; bcol[col+2] = 0.8f * be.z - mv.x * a2;
    acol[col+3] = a3; bcol[col+3] = 0.8f * be.w - mv.x * a3;
  }

  int ac_r[4], ac_sb[4], cb_[4];
#pragma unroll
  for (int p = 0; p < 4; ++p) {
    int c = p * 256 + wave * 64 + lane;
    ac_r[p]  = c >> 3;
    ac_sb[p] = (c & 7) ^ (ac_r[p] & 7);
    cb_[p]   = (p * 256 + wave * 64) * 8;
  }

  f32x4 acc[4][4];
#pragma unroll
  for (int i = 0; i < 4; ++i)
#pragma unroll
    for (int j = 0; j < 4; ++j) acc[i][j] = 0.0f;

  for (int kk0 = 0; kk0 < K; kk0 += 64) {
    __syncthreads();
#pragma unroll
    for (int p = 0; p < 4; ++p) {
      // B via gl_lds (unchanged)
      gl_lds16(Bw + (size_t)(n0 + ac_r[p]) * K + kk0 + ac_sb[p] * 8, &Bs[cb_[p]]);
      // A from ctxb with inline GN; write to the same linear chunk layout
      int row = m0 + ac_r[p];
      int s   = row & 1023;
      int c0  = kk0 + ac_sb[p] * 8;          // h = kk0>>6 (sb*8 <= 56)
      int h   = kk0 >> 6;
      uint4 raw = *(const uint4*)&ctxb[(((size_t)(b * 16 + h)) * 1024 + s) * 64 + (c0 & 63)];
      const u16* rp = (const u16*)&raw;
      float av[8];
#pragma unroll
      for (int e = 0; e < 8; ++e)
        av[e] = b2f(rp[e]) * acol[c0 + e] + bcol[c0 + e];
      unsigned pk0, pk1, pk2, pk3;
      asm("v_cvt_pk_bf16_f32 %0, %1, %2" : "=v"(pk0) : "v"(av[0]), "v"(av[1]));
      asm("v_cvt_pk_bf16_f32 %0, %1, %2" : "=v"(pk1) : "v"(av[2]), "v"(av[3]));
      asm("v_cvt_pk_bf16_f32 %0, %1, %2" : "=v"(pk2) : "v"(av[4]), "v"(av[5]));
      asm("v_cvt_pk_bf16_f32 %0, %1, %2" : "=v"(pk3) : "v"(av[6]), "v"(av[7]));
      uint4 w4; w4.x = pk0; w4.y = pk1; w4.z = pk2; w4.w = pk3;
      *(uint4*)&As[cb_[p] + lane * 8] = w4;
    }
    __syncthreads();
#pragma unroll
    for (int ks = 0; ks < 2; ++ks) {
      bf16x8 af[4], bfv[4];
#pragma unroll
      for (int f = 0; f < 4; ++f) {
        int ra = wm * 64 + f * 16 + fr;
        int rb = wn * 64 + f * 16 + fr;
        int cba = (ks * 4 + hi) ^ (ra & 7);
        int cbb = (ks * 4 + hi) ^ (rb & 7);
        af[f]  = *(const bf16x8*)&As[ra * 64 + (cba << 3)];
        bfv[f] = *(const bf16x8*)&Bs[rb * 64 + (cbb << 3)];
      }
#pragma unroll
      for (int i = 0; i < 4; ++i)
#pragma unroll
        for (int j = 0; j < 4; ++j)
          acc[i][j] = __builtin_amdgcn_mfma_f32_16x16x32_bf16(af[i], bfv[j], acc[i][j], 0, 0, 0);
    }
  }

  int rg = lane >> 4;
#pragma unroll
  for (int i = 0; i < 4; ++i)
#pragma unroll
    for (int j = 0; j < 4; ++j)
#pragma unroll
      for (int e = 0; e < 4; ++e) {
        int m = m0 + wm * 64 + i * 16 + rg * 4 + e;
        int n = n0 + wn * 64 + j * 16 + fr;
        outF[(size_t)m * N + n] = acc[i][j][e] + bias[n];
      }
}

// ---------------- fused MFMA attention v12 (unchanged r19) ----------------
__global__ __launch_bounds__(256) void attn_fused(
    const u16* __restrict__ q1t, const u16* __restrict__ q2t,
    const u16* __restrict__ k1t, const u16* __restrict__ k2t,
    const u16* __restrict__ vtT,
    const float* __restrict__ logL, const float* __restrict__ lamp,
    u16* __restrict__ ctxb, float2* __restrict__ partials)
{
  __shared__ u16 K1s[64][72];   // K1 during QK^T, P1 during PV
  __shared__ u16 K2s[64][72];   // K2 during QK^T, P2 during PV
  __shared__ u16 Vts[64][72];   // V^T [dh][k], k-blocks XOR-swizzled by (dh>>3)&7
  __shared__ float lred1[2][2][32];
  __shared__ float lred2[2][2][32];
  __shared__ float pred[4][2];

  int tid  = threadIdx.x;
  int lane = tid & 63, wave = tid >> 6;
  int wm = wave >> 1, wn = wave & 1;
  int id = blockIdx.x;
  int bh = (id & 7) * 8 + (id >> 7);        // XCD-grouped: 8 bh per XCD (L2-fit)
  int q0 = ((id >> 3) & 15) * 64;
  int b = bh >> 4;
  int fr = lane & 15, hi = lane >> 4;

  bf16x8 qf1[2][2], qf2[2][2];
#pragma unroll
  for (int i = 0; i < 2; ++i)
#pragma unroll
    for (int ks = 0; ks < 2; ++ks) {
      size_t off = ((size_t)bh * 1024 + q0 + wm * 32 + i * 16 + fr) * 64 + ks * 32 + hi * 8;
      qf1[i][ks] = *(const bf16x8*)(q1t + off);
      qf2[i][ks] = *(const bf16x8*)(q2t + off);
    }
  float Lq[2][4];
#pragma unroll
  for (int i = 0; i < 2; ++i)
#pragma unroll
    for (int r = 0; r < 4; ++r)
      Lq[i][r] = logL[b * 1024 + q0 + wm * 32 + i * 16 + hi * 4 + r];

  float Lq_top = logL[b * 1024 + q0];
  float Lq_bot = logL[b * 1024 + q0 + 63];

  float lacc1[2][4], lacc2[2][4];
  f32x4 U1[2][2], U2[2][2];
#pragma unroll
  for (int i = 0; i < 2; ++i)
#pragma unroll
    for (int r = 0; r < 4; ++r) { lacc1[i][r] = 0.f; lacc2[i][r] = 0.f; }
#pragma unroll
  for (int i = 0; i < 2; ++i)
#pragma unroll
    for (int j = 0; j < 2; ++j) { U1[i][j] = 0.f; U2[i][j] = 0.f; }

  int sr = tid >> 2, sc0 = (tid & 3) * 16;
  int swz = (sr >> 3) & 7;
  int blk0 = ((sc0 >> 3) ^ swz) << 3;
  int blk1 = (((sc0 >> 3) + 1) ^ swz) << 3;

  unsigned a1base = (unsigned)(size_t)&K1s[wm * 32 + hi * 4][wn * 32 + fr];
  unsigned a2base = (unsigned)(size_t)&K2s[wm * 32 + hi * 4][wn * 32 + fr];

  for (int kt = 0; kt < 16; ++kt) {
    int ktop = kt * 64;
    float maxc;
    if (ktop > q0 + 63)      maxc = logL[b * 1024 + ktop] - Lq_bot;
    else if (ktop + 63 < q0) maxc = Lq_top - logL[b * 1024 + ktop + 63];
    else                     maxc = 0.f;
    bool far = (maxc < -24.f);

    __syncthreads();   // (1) prev tile's LDS reads done
    size_t gb = ((size_t)bh * 1024 + kt * 64 + sr) * 64 + sc0;
    bf16x8 a0 = *(const bf16x8*)(k1t + gb), a1 = *(const bf16x8*)(k1t + gb + 8);
    bf16x8 b0 = *(const bf16x8*)(k2t + gb), b1 = *(const bf16x8*)(k2t + gb + 8);
    *(bf16x8*)&K1s[sr][sc0] = a0;  *(bf16x8*)&K1s[sr][sc0 + 8] = a1;
    *(bf16x8*)&K2s[sr][sc0] = b0;  *(bf16x8*)&K2s[sr][sc0 + 8] = b1;
    if (!far) {
      size_t gv = (size_t)bh * 65536 + (size_t)sr * 1024 + kt * 64 + sc0;
      bf16x8 v0 = *(const bf16x8*)(vtT + gv), v1 = *(const bf16x8*)(vtT + gv + 8);
      *(bf16x8*)&Vts[sr][blk0] = v0;  *(bf16x8*)&Vts[sr][blk1] = v1;
    }
    __syncthreads();   // (2) stage complete

    // ---- QK^T (always: denominators are unmasked) ----
    f32x4 S1[2][2], S2[2][2];
#pragma unroll
    for (int i = 0; i < 2; ++i)
#pragma unroll
      for (int j = 0; j < 2; ++j) { S1[i][j] = 0.f; S2[i][j] = 0.f; }
    __builtin_amdgcn_s_setprio(1);
#pragma unroll
    for (int ks = 0; ks < 2; ++ks) {
      bf16x8 kf1[2], kf2[2];
#pragma unroll
      for (int j = 0; j < 2; ++j) {
        kf1[j] = *(const bf16x8*)&K1s[wn * 32 + j * 16 + fr][ks * 32 + hi * 8];
        kf2[j] = *(const bf16x8*)&K2s[wn * 32 + j * 16 + fr][ks * 32 + hi * 8];
      }
#pragma unroll
      for (int i = 0; i < 2; ++i)
#pragma unroll
        for (int j = 0; j < 2; ++j) {
          S1[i][j] = __builtin_amdgcn_mfma_f32_16x16x32_bf16(qf1[i][ks], kf1[j], S1[i][j], 0, 0, 0);
          S2[i][j] = __builtin_amdgcn_mfma_f32_16x16x32_bf16(qf2[i][ks], kf2[j], S2[i][j], 0, 0, 0);
        }
    }
    __builtin_amdgcn_s_setprio(0);

    if (!far) {
      float Ltl[2];
#pragma unroll
      for (int j = 0; j < 2; ++j) Ltl[j] = logL[b * 1024 + kt * 64 + wn * 32 + j * 16 + fr];
      __syncthreads();   // (3) all K reads done -> K-space reusable as P

#pragma unroll
      for (int i = 0; i < 2; ++i) {
#pragma unroll
        for (int r = 0; r < 4; ++r) {
          float lq = Lq[i][r];
          float e1j[2], e2j[2], p1j[2], p2j[2];
#pragma unroll
          for (int j = 0; j < 2; ++j) {
            float nd = -fabsf(Ltl[j] - lq);
            float t1, t2, ec;
            asm("v_exp_f32 %0, %1" : "=v"(t1) : "v"(S1[i][j][r]));
            asm("v_exp_f32 %0, %1" : "=v"(t2) : "v"(S2[i][j][r]));
            asm("v_exp_f32 %0, %1" : "=v"(ec) : "v"(nd));
            e1j[j] = t1; e2j[j] = t2;
            p1j[j] = t1 * ec; p2j[j] = t2 * ec;
          }
          lacc1[i][r] += e1j[0] + e1j[1];
          lacc2[i][r] += e2j[0] + e2j[1];
          unsigned off = (unsigned)((i * 16 + r) * 144);
          unsigned ad1 = a1base + off, ad2 = a2base + off;
          unsigned pk1, pk2;
          asm("v_cvt_pk_bf16_f32 %0, %1, %2" : "=v"(pk1) : "v"(p1j[0]), "v"(p1j[1]));
          asm("v_cvt_pk_bf16_f32 %0, %1, %2" : "=v"(pk2) : "v"(p2j[0]), "v"(p2j[1]));
          asm volatile("ds_write_b16 %0, %1\n\tds_write_b16_d16_hi %0, %1 offset:32"
                       :: "v"(ad1), "v"(pk1) : "memory");
          asm volatile("ds_write_b16 %0, %1\n\tds_write_b16_d16_hi %0, %1 offset:32"
                       :: "v"(ad2), "v"(pk2) : "memory");
        }
      }
      __syncthreads();   // (4) P complete

      __builtin_amdgcn_s_setprio(1);
#pragma unroll
      for (int ks = 0; ks < 2; ++ks) {
        bf16x8 pa1[2], pa2[2], vb[2];
#pragma unroll
        for (int i = 0; i < 2; ++i) {
          pa1[i] = *(const bf16x8*)&K1s[wm * 32 + i * 16 + fr][ks * 32 + hi * 8];
          pa2[i] = *(const bf16x8*)&K2s[wm * 32 + i * 16 + fr][ks * 32 + hi * 8];
        }
#pragma unroll
        for (int j = 0; j < 2; ++j) {
          int row = wn * 32 + j * 16 + fr;
          int kbb = (ks * 4 + hi) ^ ((row >> 3) & 7);
          vb[j] = *(const bf16x8*)&Vts[row][kbb << 3];
        }
#pragma unroll
        for (int i = 0; i < 2; ++i)
#pragma unroll
          for (int j = 0; j < 2; ++j) {
            U1[i][j] = __builtin_amdgcn_mfma_f32_16x16x32_bf16(pa1[i], vb[j], U1[i][j], 0, 0, 0);
            U2[i][j] = __builtin_amdgcn_mfma_f32_16x16x32_bf16(pa2[i], vb[j], U2[i][j], 0, 0, 0);
          }
      }
      __builtin_amdgcn_s_setprio(0);
    } else {
#pragma unroll
      for (int i = 0; i < 2; ++i) {
#pragma unroll
        for (int r = 0; r < 4; ++r) {
          float t1a, t1b, t2a, t2b;
          asm("v_exp_f32 %0, %1" : "=v"(t1a) : "v"(S1[i][0][r]));
          asm("v_exp_f32 %0, %1" : "=v"(t1b) : "v"(S1[i][1][r]));
          asm("v_exp_f32 %0, %1" : "=v"(t2a) : "v"(S2[i][0][r]));
          asm("v_exp_f32 %0, %1" : "=v"(t2b) : "v"(S2[i][1][r]));
          lacc1[i][r] += t1a + t1b;
          lacc2[i][r] += t2a + t2b;
        }
      }
    }
  }

#pragma unroll
  for (int i = 0; i < 2; ++i)
#pragma unroll
    for (int r = 0; r < 4; ++r) {
#pragma unroll
      for (int m = 1; m < 16; m <<= 1) {
        lacc1[i][r] += __shfl_xor(lacc1[i][r], m);
        lacc2[i][r] += __shfl_xor(lacc2[i][r], m);
      }
    }
  if (fr == 0) {
#pragma unroll
    for (int i = 0; i < 2; ++i)
#pragma unroll
      for (int r = 0; r < 4; ++r) {
        int rl = i * 16 + hi * 4 + r;
        lred1[wn][wm][rl] = lacc1[i][r];
        lred2[wn][wm][rl] = lacc2[i][r];
      }
  }
  __syncthreads();
  float lam = lamp[0];

  float psum = 0.f, psq = 0.f;
#pragma unroll
  for (int i = 0; i < 2; ++i) {
#pragma unroll
    for (int r = 0; r < 4; ++r) {
      int rl = i * 16 + hi * 4 + r;
      float l1 = lred1[0][wm][rl] + lred1[1][wm][rl];
      float l2 = lred2[0][wm][rl] + lred2[1][wm][rl];
      float inv1 = 1.f / l1;
      float inv2 = lam / l2;
      int qg = q0 + wm * 32 + i * 16 + hi * 4 + r;
#pragma unroll
      for (int j = 0; j < 2; ++j) {
        int dh = wn * 32 + j * 16 + fr;
        float o = U1[i][j][r] * inv1 - U2[i][j][r] * inv2;
        ctxb[((size_t)bh * 1024 + qg) * 64 + dh] = f2b(o);
        psum += o; psq += o * o;
      }
    }
  }
#pragma unroll
  for (int m = 1; m < 64; m <<= 1) {
    psum += __shfl_xor(psum, m);
    psq  += __shfl_xor(psq, m);
  }
  if (lane == 0) { pred[wave][0] = psum; pred[wave][1] = psq; }
  __syncthreads();
  if (tid == 0)
    partials[id] = make_float2(pred[0][0] + pred[1][0] + pred[2][0] + pred[3][0],
                               pred[0][1] + pred[1][1] + pred[2][1] + pred[3][1]);
}

// ---------------- launch ----------------
extern "C" void kernel_launch(void* const* d_in, const int* in_sizes, int n_in,
                              void* d_out, int out_size, void* d_ws, size_t ws_size,
                              hipStream_t stream) {
  (void)in_sizes; (void)n_in; (void)out_size; (void)ws_size;
  const float* x   = (const float*)d_in[0];
  const float* aff = (const float*)d_in[1];
  const float* Wq  = (const float*)d_in[2];
  const float* bq  = (const float*)d_in[3];
  const float* Wk  = (const float*)d_in[4];
  const float* bk  = (const float*)d_in[5];
  const float* Wv  = (const float*)d_in[6];
  const float* bv  = (const float*)d_in[7];
  const float* Wo  = (const float*)d_in[8];
  const float* bo  = (const float*)d_in[9];
  const float* gw  = (const float*)d_in[10];
  const float* gb  = (const float*)d_in[11];
  const float* lam = (const float*)d_in[12];
  float* out = (float*)d_out;

  char* w = (char*)d_ws;
  u16*    xb    = (u16*)(w);
  u16*    Wcat  = (u16*)(w + 8388608);
  u16*    Wob   = (u16*)(w + 18874368);
  float*  bcat  = (float*)(w + 20971520);
  u16*    q1t   = (u16*)(w + 20992000);
  u16*    q2t   = (u16*)(w + 29380608);
  u16*    k1t   = (u16*)(w + 37769216);
  u16*    k2t   = (u16*)(w + 46157824);
  u16*    vtT   = (u16*)(w + 54546432);   // [bh][dh][s] transposed
  float*  logL  = (float*)(w + 62935040);
  float*  ctab  = (float*)(w + 62951424);
  float*  stab  = (float*)(w + 63082496);
  float2* parts = (float2*)(w + 63213568); // 1024 float2
  u16*    ctxb  = (u16*)(w + 63475712);    // bf16 ctx (8.4MB)

  convert_kernel<<<10377, 256, 0, stream>>>(x, Wq, Wk, Wv, Wo, bq, bk, bv, aff,
                                            xb, Wcat, Wob, bcat, logL, ctab, stab);
  gemm_nt<0><<<dim3(40, 32), 256, 0, stream>>>(xb, Wcat, bcat, nullptr, q1t, q2t, k1t, k2t, vtT, ctab, stab, 5120);
  attn_fused<<<1024, 256, 0, stream>>>(q1t, q2t, k1t, k2t, vtT, logL, lam, ctxb, parts);
  gemm_out<<<dim3(8, 32), 256, 0, stream>>>(ctxb, Wob, parts, gw, gb, bo, out);
}